// Round 2
// baseline (477.377 us; speedup 1.0000x reference)
//
#include <hip/hip_runtime.h>

typedef __attribute__((ext_vector_type(8))) short bf16x8;
typedef __attribute__((ext_vector_type(4))) short s16x4;
typedef __attribute__((ext_vector_type(4))) float f32x4;
typedef unsigned int u32;

#define SQ 1024
#define BB 8
#define DM 512
#define NH 8
#define HD 64
#define FF 2048
#define NROWS (SQ*BB)

static __device__ __forceinline__ float b2f(short s) {
  return __uint_as_float(((u32)(unsigned short)s) << 16);
}
static __device__ __forceinline__ short f2b(float f) {
  u32 u = __float_as_uint(f);
  return (short)((u + 0x7FFFu + ((u >> 16) & 1u)) >> 16);
}
static __device__ __forceinline__ float sigm(float x) { return 1.f / (1.f + __expf(-x)); }

static __device__ __forceinline__ f32x4 mfma16(bf16x8 a, bf16x8 b, f32x4 c) {
  return __builtin_amdgcn_mfma_f32_16x16x32_bf16(a, b, c, 0, 0, 0);
}

static __device__ __forceinline__ void gload16(const void* g, void* l) {
  __builtin_amdgcn_global_load_lds(
      (const __attribute__((address_space(1))) void*)g,
      (__attribute__((address_space(3))) void*)l, 16, 0, 0);
}

// swizzle for row-major [*][64 bf16] tiles (128 B row stride)
static __device__ __forceinline__ int swz(int r, int byteoff) {
  return (r * 128 + byteoff) ^ ((r & 7) << 4);
}

// ---------------- f32 -> bf16 convert (4-wide) ----------------
__global__ __launch_bounds__(256) void cvt_kernel(const float* __restrict__ in,
                                                  short* __restrict__ out, int n4) {
  int i = blockIdx.x * 256 + threadIdx.x;
  if (i >= n4) return;
  float4 v = ((const float4*)in)[i];
  s16x4 r = { f2b(v.x), f2b(v.y), f2b(v.z), f2b(v.w) };
  ((s16x4*)out)[i] = r;
}

// ---------------- row LayerNorm, D=512, one wave per row ----------------
// MODE 0: bf16 out; 1: f32 out; 2: bf16 out with swish
template<int MODE>
__global__ __launch_bounds__(256) void ln_kernel(const float* __restrict__ x,
                                                 const float* __restrict__ gam,
                                                 const float* __restrict__ bet,
                                                 void* __restrict__ out) {
  int w = threadIdx.x >> 6, lane = threadIdx.x & 63;
  int row = (blockIdx.x << 2) + w;
  const float* xr = x + (size_t)row * DM + lane * 8;
  float4 a = *(const float4*)xr;
  float4 c = *(const float4*)(xr + 4);
  float v[8] = {a.x, a.y, a.z, a.w, c.x, c.y, c.z, c.w};
  float s = 0.f, q = 0.f;
#pragma unroll
  for (int e = 0; e < 8; ++e) { s += v[e]; q += v[e] * v[e]; }
#pragma unroll
  for (int m = 1; m < 64; m <<= 1) { s += __shfl_xor(s, m); q += __shfl_xor(q, m); }
  float mean = s * (1.f / DM);
  float rstd = rsqrtf(q * (1.f / DM) - mean * mean + 1e-5f);
  int col = lane * 8;
  if (MODE == 1) {
    float* o = (float*)out + (size_t)row * DM + col;
    float y[8];
#pragma unroll
    for (int e = 0; e < 8; ++e) y[e] = (v[e] - mean) * rstd * gam[col + e] + bet[col + e];
    *(float4*)o = make_float4(y[0], y[1], y[2], y[3]);
    *(float4*)(o + 4) = make_float4(y[4], y[5], y[6], y[7]);
  } else {
    bf16x8 r;
#pragma unroll
    for (int e = 0; e < 8; ++e) {
      float y = (v[e] - mean) * rstd * gam[col + e] + bet[col + e];
      if (MODE == 2) y = y * sigm(y);
      r[e] = f2b(y);
    }
    *(bf16x8*)((short*)out + (size_t)row * DM + col) = r;
  }
}

// ---------------- GEMM: C = A(MxK) * W(NxK)^T, bf16 in, epilogues ----------------
// EPI 0: +bias -> bf16 ; 1: swish(+bias) -> bf16 ; 2: res + alpha*(+bias) -> f32 ; 3: plain -> bf16
template<int EPI>
__global__ __launch_bounds__(256) void gemm_bt(const short* __restrict__ A,
                                               const short* __restrict__ W,
                                               const float* __restrict__ bias,
                                               const float* __restrict__ res,
                                               float alpha, void* __restrict__ out,
                                               int M, int N, int K) {
  __shared__ __align__(16) short ldsA[128 * 32];
  __shared__ __align__(16) short ldsB[128 * 32];
  int nb = N >> 7;
  int bm = blockIdx.x / nb, bn = blockIdx.x % nb;
  int m0 = bm << 7, n0 = bn << 7;
  int tid = threadIdx.x, w = tid >> 6, lane = tid & 63;
  int wm = w >> 1, wn = w & 1;
  f32x4 acc[4][4];
#pragma unroll
  for (int i = 0; i < 4; ++i)
#pragma unroll
    for (int j = 0; j < 4; ++j) acc[i][j] = (f32x4){0.f, 0.f, 0.f, 0.f};

  for (int kt = 0; kt < K; kt += 32) {
    __syncthreads();
#pragma unroll
    for (int q = 0; q < 2; ++q) {
      int c = (q * 4 + w) * 64 + lane;
      int r = c >> 2, cc = c & 3;
      gload16(A + (size_t)(m0 + r) * K + kt + cc * 8, (char*)ldsA + (q * 4 + w) * 1024);
      gload16(W + (size_t)(n0 + r) * K + kt + cc * 8, (char*)ldsB + (q * 4 + w) * 1024);
    }
    __syncthreads();
    int rr = lane & 15, kk = (lane >> 4) << 3;
    bf16x8 af[4], bfr[4];
#pragma unroll
    for (int mt = 0; mt < 4; ++mt)
      af[mt] = *(const bf16x8*)(ldsA + (wm * 64 + mt * 16 + rr) * 32 + kk);
#pragma unroll
    for (int nt = 0; nt < 4; ++nt)
      bfr[nt] = *(const bf16x8*)(ldsB + (wn * 64 + nt * 16 + rr) * 32 + kk);
#pragma unroll
    for (int mt = 0; mt < 4; ++mt)
#pragma unroll
      for (int nt = 0; nt < 4; ++nt)
        acc[mt][nt] = mfma16(af[mt], bfr[nt], acc[mt][nt]);
  }

#pragma unroll
  for (int mt = 0; mt < 4; ++mt) {
#pragma unroll
    for (int nt = 0; nt < 4; ++nt) {
      int col = n0 + wn * 64 + nt * 16 + (lane & 15);
      float bv = (EPI == 3) ? 0.f : bias[col];
#pragma unroll
      for (int r4 = 0; r4 < 4; ++r4) {
        int row = m0 + wm * 64 + mt * 16 + (lane >> 4) * 4 + r4;
        size_t idx = (size_t)row * N + col;
        float v = acc[mt][nt][r4] + bv;
        if (EPI == 0 || EPI == 3) ((short*)out)[idx] = f2b(v);
        else if (EPI == 1) ((short*)out)[idx] = f2b(v * sigm(v));
        else ((float*)out)[idx] = res[idx] + alpha * v;
      }
    }
  }
}

// ---------------- fused rel-pos flash attention ----------------
// grid = B*H*(S/64); block = 256 (4 waves, 16 q-rows each)
__global__ __launch_bounds__(256) void attn_kernel(const short* __restrict__ qkv,
                                                   const short* __restrict__ posb,
                                                   const float* __restrict__ bias_u,
                                                   const float* __restrict__ bias_v,
                                                   short* __restrict__ obuf) {
  __shared__ __align__(16) char smem[62464];
  short* lds_qu = (short*)smem;              // [64][64] swizzled
  short* lds_qv = lds_qu + 64 * 64;          // [64][64]
  short* lds_p  = lds_qu;                    // [128][64] overlaps qu+qv after q-frag reads
  short* lds_k  = (short*)(smem + 16384);    // [64][64]
  short* lds_vt = lds_k + 64 * 64;           // [64 d][64 j]
  float* lds_e  = (float*)(smem + 32768);    // 4 waves x [16][84]
  short* lds_ps = (short*)(smem + 32768 + 21504); // 4 waves x [16][64] swizzled

  int tid = threadIdx.x, w = tid >> 6, lane = tid & 63;
  int l15 = lane & 15, l4 = lane >> 4;
  int it = blockIdx.x & 15, h = (blockIdx.x >> 4) & 7, b = blockIdx.x >> 7;
  int i0 = it << 6;

  // stage q + bias_u / q + bias_v
#pragma unroll
  for (int q = 0; q < 2; ++q) {
    int c = q * 256 + tid;
    int r = c >> 3, cc = c & 7;
    int grow = (i0 + r) * BB + b;
    bf16x8 qraw = *(const bf16x8*)(qkv + (size_t)grow * 1536 + h * 64 + cc * 8);
    bf16x8 uu, vv;
#pragma unroll
    for (int e = 0; e < 8; ++e) {
      float qf = b2f(qraw[e]);
      uu[e] = f2b(qf + bias_u[h * 64 + cc * 8 + e]);
      vv[e] = f2b(qf + bias_v[h * 64 + cc * 8 + e]);
    }
    int sa = swz(r, cc * 16);
    *(bf16x8*)((char*)lds_qu + sa) = uu;
    *(bf16x8*)((char*)lds_qv + sa) = vv;
  }
  __syncthreads();

  bf16x8 qu_f[2], qv_f[2];
  int fr = w * 16 + l15;
#pragma unroll
  for (int ks = 0; ks < 2; ++ks) {
    int sa = swz(fr, ks * 64 + l4 * 16);
    qu_f[ks] = *(const bf16x8*)((char*)lds_qu + sa);
    qv_f[ks] = *(const bf16x8*)((char*)lds_qv + sa);
  }

  float m_run[4], l_run[4];
  f32x4 o_acc[4];
#pragma unroll
  for (int r4 = 0; r4 < 4; ++r4) { m_run[r4] = -1e30f; l_run[r4] = 0.f; }
#pragma unroll
  for (int dt = 0; dt < 4; ++dt) o_acc[dt] = (f32x4){0.f, 0.f, 0.f, 0.f};

  float* ew = lds_e + w * 16 * 84;
  short* psw = lds_ps + w * 16 * 64;
  int prbase = 48 - 16 * w;

  for (int j0 = 0; j0 < SQ; j0 += 64) {
    __syncthreads();
    // stage K [j][d]
#pragma unroll
    for (int q = 0; q < 2; ++q) {
      int c = q * 256 + tid;
      int r = c >> 3, cc = c & 7;
      bf16x8 kv = *(const bf16x8*)(qkv + (size_t)((j0 + r) * BB + b) * 1536 + 512 + h * 64 + cc * 8);
      *(bf16x8*)((char*)lds_k + swz(r, cc * 16)) = kv;
    }
    // stage V transposed [d][j]
    {
      int d = tid & 63, jc = tid >> 6;
#pragma unroll
      for (int u = 0; u < 8; ++u) {
        int j = jc * 16 + u * 2;
        short v0 = qkv[(size_t)((j0 + j) * BB + b) * 1536 + 1024 + h * 64 + d];
        short v1 = qkv[(size_t)((j0 + j + 1) * BB + b) * 1536 + 1024 + h * 64 + d];
        u32 pk = (u32)(unsigned short)v0 | ((u32)(unsigned short)v1 << 16);
        *(u32*)((char*)lds_vt + swz(d, j * 2)) = pk;
      }
    }
    // stage P band [128][64]: rows nmin .. nmin+127
    int nmin = SQ - 64 - i0 + j0;
#pragma unroll
    for (int q = 0; q < 4; ++q) {
      int c = q * 256 + tid;
      int r = c >> 3, cc = c & 7;
      bf16x8 pv = *(const bf16x8*)(posb + (size_t)(nmin + r) * DM + h * 64 + cc * 8);
      *(bf16x8*)((char*)lds_p + swz(r, cc * 16)) = pv;
    }
    __syncthreads();

    // ac = (q+u) @ k^T : 4 col-tiles
    f32x4 ac[4];
#pragma unroll
    for (int ct = 0; ct < 4; ++ct) {
      f32x4 z = (f32x4){0.f, 0.f, 0.f, 0.f};
      bf16x8 kb0 = *(const bf16x8*)((char*)lds_k + swz(ct * 16 + l15, l4 * 16));
      bf16x8 kb1 = *(const bf16x8*)((char*)lds_k + swz(ct * 16 + l15, 64 + l4 * 16));
      z = mfma16(qu_f[0], kb0, z);
      z = mfma16(qu_f[1], kb1, z);
      ac[ct] = z;
    }
    // e band = (q+v) @ p^T : 5 col-tiles -> per-wave LDS
#pragma unroll
    for (int et = 0; et < 5; ++et) {
      f32x4 z = (f32x4){0.f, 0.f, 0.f, 0.f};
      int pr = prbase + et * 16 + l15;
      bf16x8 pb0 = *(const bf16x8*)((char*)lds_p + swz(pr, l4 * 16));
      bf16x8 pb1 = *(const bf16x8*)((char*)lds_p + swz(pr, 64 + l4 * 16));
      z = mfma16(qv_f[0], pb0, z);
      z = mfma16(qv_f[1], pb1, z);
#pragma unroll
      for (int r4 = 0; r4 < 4; ++r4)
        ew[(l4 * 4 + r4) * 84 + et * 16 + l15] = z[r4];
    }
    __syncthreads();

    // gather band + online softmax
    float pst[4][4];
#pragma unroll
    for (int r4 = 0; r4 < 4; ++r4) {
      int iloc = l4 * 4 + r4;
      float sv[4];
      float mt = -1e30f;
#pragma unroll
      for (int ct = 0; ct < 4; ++ct) {
        int jj = ct * 16 + l15;
        float sc = (ac[ct][r4] + ew[iloc * 84 + (15 - iloc + jj)]) * 0.125f;
        sv[ct] = sc;
        mt = fmaxf(mt, sc);
      }
#pragma unroll
      for (int msk = 1; msk < 16; msk <<= 1) mt = fmaxf(mt, __shfl_xor(mt, msk));
      float mn = fmaxf(m_run[r4], mt);
      float fac = __expf(m_run[r4] - mn);
      float ls = 0.f;
#pragma unroll
      for (int ct = 0; ct < 4; ++ct) {
        float pp = __expf(sv[ct] - mn);
        pst[ct][r4] = pp;
        ls += pp;
      }
#pragma unroll
      for (int msk = 1; msk < 16; msk <<= 1) ls += __shfl_xor(ls, msk);
      l_run[r4] = l_run[r4] * fac + ls;
      m_run[r4] = mn;
#pragma unroll
      for (int dt = 0; dt < 4; ++dt) o_acc[dt][r4] *= fac;
    }
    // write P tile (bf16) to per-wave LDS
#pragma unroll
    for (int r4 = 0; r4 < 4; ++r4) {
      int iloc = l4 * 4 + r4;
#pragma unroll
      for (int ct = 0; ct < 4; ++ct) {
        int jj = ct * 16 + l15;
        *(short*)((char*)psw + swz(iloc, jj * 2)) = f2b(pst[ct][r4]);
      }
    }
    __syncthreads();

    // PV
    bf16x8 pa[2];
#pragma unroll
    for (int ks = 0; ks < 2; ++ks)
      pa[ks] = *(const bf16x8*)((char*)psw + swz(l15, ks * 64 + l4 * 16));
#pragma unroll
    for (int dt = 0; dt < 4; ++dt) {
      bf16x8 vb0 = *(const bf16x8*)((char*)lds_vt + swz(dt * 16 + l15, l4 * 16));
      bf16x8 vb1 = *(const bf16x8*)((char*)lds_vt + swz(dt * 16 + l15, 64 + l4 * 16));
      o_acc[dt] = mfma16(pa[0], vb0, o_acc[dt]);
      o_acc[dt] = mfma16(pa[1], vb1, o_acc[dt]);
    }
  }

  // write O
#pragma unroll
  for (int dt = 0; dt < 4; ++dt) {
#pragma unroll
    for (int r4 = 0; r4 < 4; ++r4) {
      int i = i0 + w * 16 + l4 * 4 + r4;
      int d = dt * 16 + l15;
      float val = o_acc[dt][r4] / l_run[r4];
      obuf[(size_t)(i * BB + b) * DM + h * 64 + d] = f2b(val);
    }
  }
}

// ---------------- GLU + depthwise conv (K=31, pad 15) ----------------
// grid = (S/8)*B ; block computes 8 output rows for one b
__global__ __launch_bounds__(256) void glu_dwconv_kernel(const short* __restrict__ pw1,
                                                         const float* __restrict__ dww,
                                                         const float* __restrict__ dwb,
                                                         float* __restrict__ out) {
  __shared__ short glu[38 * 512];
  int tid = threadIdx.x;
  int b = blockIdx.x & 7;
  int s0 = (blockIdx.x >> 3) << 3;
  for (int idx = tid; idx < 38 * 512; idx += 256) {
    int r = idx >> 9, d = idx & 511;
    int s = s0 - 15 + r;
    float v = 0.f;
    if (s >= 0 && s < SQ) {
      const short* row = pw1 + (size_t)(s * BB + b) * 1024;
      float a = b2f(row[d]);
      float g = b2f(row[512 + d]);
      v = a * sigm(g);
    }
    glu[idx] = f2b(v);
  }
  __syncthreads();
#pragma unroll
  for (int c = 0; c < 2; ++c) {
    int d = tid + c * 256;
    float wreg[31];
#pragma unroll
    for (int k = 0; k < 31; ++k) wreg[k] = dww[d * 31 + k];
    float bb = dwb[d];
    for (int ri = 0; ri < 8; ++ri) {
      float acc = bb;
#pragma unroll
      for (int k = 0; k < 31; ++k)
        acc += wreg[k] * b2f(glu[(ri + k) * 512 + d]);
      out[(size_t)((s0 + ri) * BB + b) * 512 + d] = acc;
    }
  }
}

// ---------------- host ----------------
extern "C" void kernel_launch(void* const* d_in, const int* in_sizes, int n_in,
                              void* d_out, int out_size, void* d_ws, size_t ws_size,
                              hipStream_t stream) {
  const float* src    = (const float*)d_in[0];
  const float* pose   = (const float*)d_in[1];
  const float* ffm_w1 = (const float*)d_in[2];
  const float* ffm_b1 = (const float*)d_in[3];
  const float* ffm_w2 = (const float*)d_in[4];
  const float* ffm_b2 = (const float*)d_in[5];
  const float* in_w   = (const float*)d_in[6];
  const float* in_b   = (const float*)d_in[7];
  const float* out_w  = (const float*)d_in[8];
  const float* out_b  = (const float*)d_in[9];
  const float* pos_w  = (const float*)d_in[10];
  const float* bias_u = (const float*)d_in[11];
  const float* bias_v = (const float*)d_in[12];
  const float* pw1_w  = (const float*)d_in[13];
  const float* pw1_b  = (const float*)d_in[14];
  const float* dw_w   = (const float*)d_in[15];
  const float* dw_b   = (const float*)d_in[16];
  const float* cng    = (const float*)d_in[17];
  const float* cnb    = (const float*)d_in[18];
  const float* pw2_w  = (const float*)d_in[19];
  const float* pw2_b  = (const float*)d_in[20];
  const float* ff_w1  = (const float*)d_in[21];
  const float* ff_b1  = (const float*)d_in[22];
  const float* ff_w2  = (const float*)d_in[23];
  const float* ff_b2  = (const float*)d_in[24];
  const float* g_ffm  = (const float*)d_in[25];
  const float* b_ffm  = (const float*)d_in[26];
  const float* g_mha  = (const float*)d_in[27];
  const float* b_mha  = (const float*)d_in[28];
  const float* g_conv = (const float*)d_in[29];
  const float* b_conv = (const float*)d_in[30];
  const float* g_ff   = (const float*)d_in[31];
  const float* b_ff   = (const float*)d_in[32];
  const float* g_fin  = (const float*)d_in[33];
  const float* b_fin  = (const float*)d_in[34];

  char* ws = (char*)d_ws;
  size_t off = 0;
  auto alloc = [&](size_t bytes) -> void* {
    void* p = ws + off;
    off += (bytes + 255) & ~(size_t)255;
    return p;
  };
  short* wb_ffm1 = (short*)alloc((size_t)FF * DM * 2);
  short* wb_ffm2 = (short*)alloc((size_t)DM * FF * 2);
  short* wb_in   = (short*)alloc((size_t)3 * DM * DM * 2);
  short* wb_out  = (short*)alloc((size_t)DM * DM * 2);
  short* wb_pos  = (short*)alloc((size_t)DM * DM * 2);
  short* wb_pw1  = (short*)alloc((size_t)2 * DM * DM * 2);
  short* wb_pw2  = (short*)alloc((size_t)DM * DM * 2);
  short* wb_ff1  = (short*)alloc((size_t)FF * DM * 2);
  short* wb_ff2  = (short*)alloc((size_t)DM * FF * 2);
  short* pos_src = (short*)alloc((size_t)2048 * DM * 2);
  short* pos_bf  = (short*)alloc((size_t)2048 * DM * 2);
  short* lnb     = (short*)alloc((size_t)NROWS * DM * 2);
  short* hbig    = (short*)alloc((size_t)NROWS * FF * 2);   // also pw1 raw (8192x1024)
  short* qkvb    = (short*)alloc((size_t)NROWS * 3 * DM * 2); // also dwout f32
  short* obuf    = (short*)alloc((size_t)NROWS * DM * 2);   // also conv_y
  float* x1      = (float*)alloc((size_t)NROWS * DM * 4);   // also x3
  float* x2      = (float*)alloc((size_t)NROWS * DM * 4);   // also x4
  float* dwout   = (float*)qkvb;
  short* pw1raw  = hbig;
  short* convy   = obuf;
  float* x3 = x1;
  float* x4 = x2;

  auto cvt = [&](const float* s, short* d, size_t n) {
    int n4 = (int)(n >> 2);
    cvt_kernel<<<dim3((n4 + 255) / 256), dim3(256), 0, stream>>>(s, d, n4);
  };
  cvt(ffm_w1, wb_ffm1, (size_t)FF * DM);
  cvt(ffm_w2, wb_ffm2, (size_t)DM * FF);
  cvt(in_w,   wb_in,   (size_t)3 * DM * DM);
  cvt(out_w,  wb_out,  (size_t)DM * DM);
  cvt(pos_w,  wb_pos,  (size_t)DM * DM);
  cvt(pw1_w,  wb_pw1,  (size_t)2 * DM * DM);
  cvt(pw2_w,  wb_pw2,  (size_t)DM * DM);
  cvt(ff_w1,  wb_ff1,  (size_t)FF * DM);
  cvt(ff_w2,  wb_ff2,  (size_t)DM * FF);
  cvt(pose,   pos_src, (size_t)2047 * DM);

  auto gemm = [&](int EPI, const short* A, const short* W, const float* bias,
                  const float* res, float alpha, void* out, int M, int N, int K) {
    dim3 g((M / 128) * (N / 128)), blk(256);
    switch (EPI) {
      case 0: gemm_bt<0><<<g, blk, 0, stream>>>(A, W, bias, res, alpha, out, M, N, K); break;
      case 1: gemm_bt<1><<<g, blk, 0, stream>>>(A, W, bias, res, alpha, out, M, N, K); break;
      case 2: gemm_bt<2><<<g, blk, 0, stream>>>(A, W, bias, res, alpha, out, M, N, K); break;
      default: gemm_bt<3><<<g, blk, 0, stream>>>(A, W, bias, res, alpha, out, M, N, K); break;
    }
  };
  auto ln = [&](int MODE, const float* x, const float* g, const float* b, void* o) {
    dim3 grid(NROWS / 4), blk(256);
    if (MODE == 0)      ln_kernel<0><<<grid, blk, 0, stream>>>(x, g, b, o);
    else if (MODE == 1) ln_kernel<1><<<grid, blk, 0, stream>>>(x, g, b, o);
    else                ln_kernel<2><<<grid, blk, 0, stream>>>(x, g, b, o);
  };

  // positional projection: (2048 x 512) @ pos_w^T -> bf16 (row 2047 garbage, never used)
  gemm(3, pos_src, wb_pos, nullptr, nullptr, 0.f, pos_bf, 2048, DM, DM);

  // macaron FFN: x1 = src + 0.5*ffn(ln(src))
  ln(0, src, g_ffm, b_ffm, lnb);
  gemm(1, lnb, wb_ffm1, ffm_b1, nullptr, 0.f, hbig, NROWS, FF, DM);
  gemm(2, hbig, wb_ffm2, ffm_b2, src, 0.5f, x1, NROWS, DM, FF);

  // MHA: x2 = x1 + out_proj(attn(ln(x1)))
  ln(0, x1, g_mha, b_mha, lnb);
  gemm(0, lnb, wb_in, in_b, nullptr, 0.f, qkvb, NROWS, 3 * DM, DM);
  attn_kernel<<<dim3(1024), dim3(256), 0, stream>>>(qkvb, pos_bf, bias_u, bias_v, obuf);
  gemm(2, obuf, wb_out, out_b, x1, 1.f, x2, NROWS, DM, DM);

  // conv module: x3 = x2 + pw2(swish(ln(dwconv(glu(pw1(ln(x2)))))))
  ln(0, x2, g_conv, b_conv, lnb);
  gemm(0, lnb, wb_pw1, pw1_b, nullptr, 0.f, pw1raw, NROWS, 2 * DM, DM);
  glu_dwconv_kernel<<<dim3(1024), dim3(256), 0, stream>>>(pw1raw, dw_w, dw_b, dwout);
  ln(2, dwout, cng, cnb, convy);
  gemm(2, convy, wb_pw2, pw2_b, x2, 1.f, x3, NROWS, DM, DM);

  // final FFN: x4 = x3 + ffn(ln(x3))
  ln(0, x3, g_ff, b_ff, lnb);
  gemm(1, lnb, wb_ff1, ff_b1, nullptr, 0.f, hbig, NROWS, FF, DM);
  gemm(2, hbig, wb_ff2, ff_b2, x3, 1.f, x4, NROWS, DM, FF);

  // final LN -> f32 output
  ln(1, x4, g_fin, b_fin, d_out);

  (void)in_sizes; (void)n_in; (void)out_size; (void)ws_size;
}

// Round 3
// 448.275 us; speedup vs baseline: 1.0649x; 1.0649x over previous
//
#include <hip/hip_runtime.h>

typedef __attribute__((ext_vector_type(8))) short bf16x8;
typedef __attribute__((ext_vector_type(4))) short s16x4;
typedef __attribute__((ext_vector_type(4))) float f32x4;
typedef unsigned int u32;

#define SQ 1024
#define BB 8
#define DM 512
#define NH 8
#define HD 64
#define FF 2048
#define NROWS (SQ*BB)

static __device__ __forceinline__ float b2f(short s) {
  return __uint_as_float(((u32)(unsigned short)s) << 16);
}
static __device__ __forceinline__ short f2b(float f) {
  u32 u = __float_as_uint(f);
  return (short)((u + 0x7FFFu + ((u >> 16) & 1u)) >> 16);
}
static __device__ __forceinline__ float sigm(float x) { return 1.f / (1.f + __expf(-x)); }

static __device__ __forceinline__ f32x4 mfma16(bf16x8 a, bf16x8 b, f32x4 c) {
  return __builtin_amdgcn_mfma_f32_16x16x32_bf16(a, b, c, 0, 0, 0);
}

static __device__ __forceinline__ void gload16(const void* g, void* l) {
  __builtin_amdgcn_global_load_lds(
      (const __attribute__((address_space(1))) void*)g,
      (__attribute__((address_space(3))) void*)l, 16, 0, 0);
}

// XOR swizzle for row-major [*][64 bf16] tiles (128 B row stride)
static __device__ __forceinline__ int swzp(int r, int byteoff) {
  return (r * 128 + byteoff) ^ ((r & 7) << 4);
}

#define WAIT_LGKM() do { \
    asm volatile("s_waitcnt lgkmcnt(0)" ::: "memory"); \
    __builtin_amdgcn_sched_barrier(0); } while (0)

// ---------------- f32 -> bf16 convert (4-wide) ----------------
__global__ __launch_bounds__(256) void cvt_kernel(const float* __restrict__ in,
                                                  short* __restrict__ out, int n4) {
  int i = blockIdx.x * 256 + threadIdx.x;
  if (i >= n4) return;
  float4 v = ((const float4*)in)[i];
  s16x4 r = { f2b(v.x), f2b(v.y), f2b(v.z), f2b(v.w) };
  ((s16x4*)out)[i] = r;
}

// ---------------- row LayerNorm, D=512, one wave per row ----------------
// MODE 0: bf16 out; 1: f32 out; 2: bf16 out with swish
template<int MODE>
__global__ __launch_bounds__(256) void ln_kernel(const float* __restrict__ x,
                                                 const float* __restrict__ gam,
                                                 const float* __restrict__ bet,
                                                 void* __restrict__ out) {
  int w = threadIdx.x >> 6, lane = threadIdx.x & 63;
  int row = (blockIdx.x << 2) + w;
  const float* xr = x + (size_t)row * DM + lane * 8;
  float4 a = *(const float4*)xr;
  float4 c = *(const float4*)(xr + 4);
  float v[8] = {a.x, a.y, a.z, a.w, c.x, c.y, c.z, c.w};
  float s = 0.f, q = 0.f;
#pragma unroll
  for (int e = 0; e < 8; ++e) { s += v[e]; q += v[e] * v[e]; }
#pragma unroll
  for (int m = 1; m < 64; m <<= 1) { s += __shfl_xor(s, m); q += __shfl_xor(q, m); }
  float mean = s * (1.f / DM);
  float rstd = rsqrtf(q * (1.f / DM) - mean * mean + 1e-5f);
  int col = lane * 8;
  if (MODE == 1) {
    float* o = (float*)out + (size_t)row * DM + col;
    float y[8];
#pragma unroll
    for (int e = 0; e < 8; ++e) y[e] = (v[e] - mean) * rstd * gam[col + e] + bet[col + e];
    *(float4*)o = make_float4(y[0], y[1], y[2], y[3]);
    *(float4*)(o + 4) = make_float4(y[4], y[5], y[6], y[7]);
  } else {
    bf16x8 r;
#pragma unroll
    for (int e = 0; e < 8; ++e) {
      float y = (v[e] - mean) * rstd * gam[col + e] + bet[col + e];
      if (MODE == 2) y = y * sigm(y);
      r[e] = f2b(y);
    }
    *(bf16x8*)((short*)out + (size_t)row * DM + col) = r;
  }
}

// ---------------- GEMM: C = A(MxK) * W(NxK)^T, 2-phase prefetch ----------------
// EPI 0: +bias -> bf16 ; 1: swish(+bias) -> bf16 ; 2: res + alpha*(+bias) -> f32 ; 3: plain -> bf16
template<int EPI>
__global__ __launch_bounds__(256) void gemm_bt(const short* __restrict__ A,
                                               const short* __restrict__ W,
                                               const float* __restrict__ bias,
                                               const float* __restrict__ res,
                                               float alpha, void* __restrict__ out,
                                               int M, int N, int K) {
  __shared__ __align__(16) short ldsA[2 * 128 * 32];
  __shared__ __align__(16) short ldsB[2 * 128 * 32];
  int nb = N >> 7;
  int bm = blockIdx.x / nb, bn = blockIdx.x % nb;
  int m0 = bm << 7, n0 = bn << 7;
  int tid = threadIdx.x, w = tid >> 6, lane = tid & 63;
  int wm = w >> 1, wn = w & 1;
  f32x4 acc[4][4];
#pragma unroll
  for (int i = 0; i < 4; ++i)
#pragma unroll
    for (int j = 0; j < 4; ++j) acc[i][j] = (f32x4){0.f, 0.f, 0.f, 0.f};

  auto stage = [&](int bufsel, int kt) {
#pragma unroll
    for (int q = 0; q < 2; ++q) {
      int c = (q * 4 + w) * 64 + lane;
      int r = c >> 2, cc = c & 3;
      gload16(A + (size_t)(m0 + r) * K + kt + cc * 8,
              (char*)ldsA + bufsel * 8192 + (q * 4 + w) * 1024);
      gload16(W + (size_t)(n0 + r) * K + kt + cc * 8,
              (char*)ldsB + bufsel * 8192 + (q * 4 + w) * 1024);
    }
  };

  stage(0, 0);
  asm volatile("s_waitcnt vmcnt(0)" ::: "memory");
  __syncthreads();
  int cur = 0;
  for (int kt = 0; kt < K; kt += 32) {
    if (kt + 32 < K) stage(cur ^ 1, kt + 32);
    int rr = lane & 15, kk = (lane >> 4) << 3;
    bf16x8 af[4], bfr[4];
#pragma unroll
    for (int mt = 0; mt < 4; ++mt)
      af[mt] = *(const bf16x8*)(ldsA + cur * 4096 + (wm * 64 + mt * 16 + rr) * 32 + kk);
#pragma unroll
    for (int nt = 0; nt < 4; ++nt)
      bfr[nt] = *(const bf16x8*)(ldsB + cur * 4096 + (wn * 64 + nt * 16 + rr) * 32 + kk);
#pragma unroll
    for (int mt = 0; mt < 4; ++mt)
#pragma unroll
      for (int nt = 0; nt < 4; ++nt)
        acc[mt][nt] = mfma16(af[mt], bfr[nt], acc[mt][nt]);
    asm volatile("s_waitcnt vmcnt(0)" ::: "memory");
    __syncthreads();
    cur ^= 1;
  }

#pragma unroll
  for (int mt = 0; mt < 4; ++mt) {
#pragma unroll
    for (int nt = 0; nt < 4; ++nt) {
      int col = n0 + wn * 64 + nt * 16 + (lane & 15);
      float bv = (EPI == 3) ? 0.f : bias[col];
#pragma unroll
      for (int r4 = 0; r4 < 4; ++r4) {
        int row = m0 + wm * 64 + mt * 16 + (lane >> 4) * 4 + r4;
        size_t idx = (size_t)row * N + col;
        float v = acc[mt][nt][r4] + bv;
        if (EPI == 0 || EPI == 3) ((short*)out)[idx] = f2b(v);
        else if (EPI == 1) ((short*)out)[idx] = f2b(v * sigm(v));
        else ((float*)out)[idx] = res[idx] + alpha * v;
      }
    }
  }
}

// ---------------- QKV prep: per-head contiguous QU/QV/K and transposed V ----------------
// grid = 64(bh) * 16(s-tiles of 64); block 256
__global__ __launch_bounds__(256) void prep_kernel(const short* __restrict__ qkv,
                                                   const float* __restrict__ bias_u,
                                                   const float* __restrict__ bias_v,
                                                   short* __restrict__ QU,
                                                   short* __restrict__ QV,
                                                   short* __restrict__ Kp,
                                                   short* __restrict__ VTp) {
  __shared__ short ldsv[64 * 66];
  int tid = threadIdx.x;
  int st = blockIdx.x & 15, bh = blockIdx.x >> 4;
  int b = bh >> 3, h = bh & 7;
  int s0 = st << 6;
#pragma unroll
  for (int pass = 0; pass < 2; ++pass) {
    int r = pass * 32 + (tid >> 3), c = tid & 7;
    int s = s0 + r;
    size_t grow = (size_t)(s * BB + b) * 1536 + h * 64 + c * 8;
    bf16x8 q8 = *(const bf16x8*)(qkv + grow);
    bf16x8 k8 = *(const bf16x8*)(qkv + grow + 512);
    bf16x8 v8 = *(const bf16x8*)(qkv + grow + 1024);
    bf16x8 u8, w8;
#pragma unroll
    for (int e = 0; e < 8; ++e) {
      float qf = b2f(q8[e]);
      u8[e] = f2b(qf + bias_u[h * 64 + c * 8 + e]);
      w8[e] = f2b(qf + bias_v[h * 64 + c * 8 + e]);
    }
    size_t dst = ((size_t)bh * SQ + s) * 64 + c * 8;
    *(bf16x8*)(QU + dst) = u8;
    *(bf16x8*)(QV + dst) = w8;
    *(bf16x8*)(Kp + dst) = k8;
    *(bf16x8*)(ldsv + r * 66 + c * 8) = v8;
  }
  __syncthreads();
#pragma unroll
  for (int pass = 0; pass < 2; ++pass) {
    int d = pass * 32 + (tid >> 3), sc = tid & 7;
    bf16x8 o;
#pragma unroll
    for (int u = 0; u < 8; ++u) o[u] = ldsv[(sc * 8 + u) * 66 + d];
    *(bf16x8*)(VTp + ((size_t)bh * 64 + d) * SQ + s0 + sc * 8) = o;
  }
}

// ---------------- fused rel-pos flash attention ----------------
// grid = 64(bh) * 8(i-tiles of 128); block 512 (8 waves, 16 q-rows each)
__global__ __launch_bounds__(512, 4) void attn_kernel(const short* __restrict__ QU,
                                                      const short* __restrict__ QV,
                                                      const short* __restrict__ Kp,
                                                      const short* __restrict__ VTp,
                                                      const short* __restrict__ posb,
                                                      short* __restrict__ obuf) {
  __shared__ __align__(16) char smem[62464];
  char* lds_k   = smem;            // [64][64] bf16, swizzled, 8KB
  char* lds_vt  = smem + 8192;     // [64 d][64 j] bf16, swizzled, 8KB
  char* lds_pos = smem + 16384;    // [192][64] bf16, swizzled, 24KB
  char* lds_ew  = smem + 40960;    // 8 waves x 2688B: e band [16][84] bf16, P overlaps

  int tid = threadIdx.x, w = tid >> 6, lane = tid & 63;
  int l15 = lane & 15, l4 = lane >> 4;
  int it = blockIdx.x & 7, bh = blockIdx.x >> 3;
  int b = bh >> 3, h = bh & 7;
  int i0 = it << 7;
  char* ewb = lds_ew + w * 2688;

  const size_t hoff = (size_t)bh * SQ * 64;       // elements
  const size_t hoffB = (size_t)bh * SQ * 128;     // bytes

  // Q fragments straight from global
  int fr = i0 + w * 16 + l15;
  bf16x8 qu_f[2], qv_f[2];
  qu_f[0] = *(const bf16x8*)(QU + hoff + (size_t)fr * 64 + l4 * 8);
  qu_f[1] = *(const bf16x8*)(QU + hoff + (size_t)fr * 64 + 32 + l4 * 8);
  qv_f[0] = *(const bf16x8*)(QV + hoff + (size_t)fr * 64 + l4 * 8);
  qv_f[1] = *(const bf16x8*)(QV + hoff + (size_t)fr * 64 + 32 + l4 * 8);

  float m_run[4], l_run[4];
  f32x4 o_acc[4];
#pragma unroll
  for (int r4 = 0; r4 < 4; ++r4) { m_run[r4] = -1e30f; l_run[r4] = 0.f; }
#pragma unroll
  for (int dt = 0; dt < 4; ++dt) o_acc[dt] = (f32x4){0.f, 0.f, 0.f, 0.f};

  int prbase = 112 - 16 * w;
  int lnq = lane >> 3, lnr = lane & 7;   // lane -> (row-in-chunk, 16B slot)

  for (int j0 = 0; j0 < SQ; j0 += 64) {
    __syncthreads();
    // ---- stage K (1KB/wave), VT (1KB/wave), pos band (3KB/wave) via global_load_lds,
    //      linear LDS dest + inverse-swizzled global source ----
    {
      int r = w * 8 + lnq;
      int byt = (lnr * 16) ^ ((r & 7) << 4);
      gload16((const char*)Kp + hoffB + (size_t)(j0 + r) * 128 + byt, lds_k + w * 1024);
      gload16((const char*)VTp + hoffB + (size_t)r * 2048 + (size_t)j0 * 2 + byt,
              lds_vt + w * 1024);
    }
    int nmin2 = 896 - i0 + j0;
#pragma unroll
    for (int q = 0; q < 3; ++q) {
      int ch = w * 3 + q;
      int r = ch * 8 + lnq;
      int byt = (lnr * 16) ^ ((r & 7) << 4);
      gload16((const char*)posb + (size_t)(nmin2 + r) * 1024 + h * 128 + byt,
              lds_pos + ch * 1024);
    }
    asm volatile("s_waitcnt vmcnt(0)" ::: "memory");
    __syncthreads();

    // ---- ac = (q+u) @ k^T : 4 col-tiles ----
    f32x4 ac[4];
#pragma unroll
    for (int ct = 0; ct < 4; ++ct) {
      f32x4 z = (f32x4){0.f, 0.f, 0.f, 0.f};
      bf16x8 kb0 = *(const bf16x8*)(lds_k + swzp(ct * 16 + l15, l4 * 16));
      bf16x8 kb1 = *(const bf16x8*)(lds_k + swzp(ct * 16 + l15, 64 + l4 * 16));
      z = mfma16(qu_f[0], kb0, z);
      z = mfma16(qu_f[1], kb1, z);
      ac[ct] = z;
    }
    // ---- e band = (q+v) @ p^T : 5 col-tiles -> per-wave LDS (bf16) ----
#pragma unroll
    for (int et = 0; et < 5; ++et) {
      f32x4 z = (f32x4){0.f, 0.f, 0.f, 0.f};
      int pr = prbase + et * 16 + l15;
      bf16x8 pb0 = *(const bf16x8*)(lds_pos + swzp(pr, l4 * 16));
      bf16x8 pb1 = *(const bf16x8*)(lds_pos + swzp(pr, 64 + l4 * 16));
      z = mfma16(qv_f[0], pb0, z);
      z = mfma16(qv_f[1], pb1, z);
#pragma unroll
      for (int r4 = 0; r4 < 4; ++r4)
        *(short*)(ewb + ((l4 * 4 + r4) * 84 + et * 16 + l15) * 2) = f2b(z[r4]);
    }
    WAIT_LGKM();

    // ---- banded gather + online softmax (per-wave, no block barrier) ----
    float pst[4][4];
#pragma unroll
    for (int r4 = 0; r4 < 4; ++r4) {
      int iloc = l4 * 4 + r4;
      float sv[4];
      float mt = -1e30f;
#pragma unroll
      for (int ct = 0; ct < 4; ++ct) {
        int jj = ct * 16 + l15;
        float ev = b2f(*(const short*)(ewb + (iloc * 84 + (15 - iloc + jj)) * 2));
        float sc = (ac[ct][r4] + ev) * 0.125f;
        sv[ct] = sc;
        mt = fmaxf(mt, sc);
      }
#pragma unroll
      for (int msk = 1; msk < 16; msk <<= 1) mt = fmaxf(mt, __shfl_xor(mt, msk));
      float mn = fmaxf(m_run[r4], mt);
      float fac = __expf(m_run[r4] - mn);
      float ls = 0.f;
#pragma unroll
      for (int ct = 0; ct < 4; ++ct) {
        float pp = __expf(sv[ct] - mn);
        pst[ct][r4] = pp;
        ls += pp;
      }
#pragma unroll
      for (int msk = 1; msk < 16; msk <<= 1) ls += __shfl_xor(ls, msk);
      l_run[r4] = l_run[r4] * fac + ls;
      m_run[r4] = mn;
#pragma unroll
      for (int dt = 0; dt < 4; ++dt) o_acc[dt][r4] *= fac;
    }
    WAIT_LGKM();
    // ---- P tile (bf16) into per-wave scratch (overlaps e region) ----
#pragma unroll
    for (int r4 = 0; r4 < 4; ++r4) {
      int iloc = l4 * 4 + r4;
#pragma unroll
      for (int ct = 0; ct < 4; ++ct) {
        int jj = ct * 16 + l15;
        *(short*)(ewb + swzp(iloc, jj * 2)) = f2b(pst[ct][r4]);
      }
    }
    WAIT_LGKM();

    // ---- PV ----
    bf16x8 pa[2];
#pragma unroll
    for (int ks = 0; ks < 2; ++ks)
      pa[ks] = *(const bf16x8*)(ewb + swzp(l15, ks * 64 + l4 * 16));
#pragma unroll
    for (int dt = 0; dt < 4; ++dt) {
      bf16x8 vb0 = *(const bf16x8*)(lds_vt + swzp(dt * 16 + l15, l4 * 16));
      bf16x8 vb1 = *(const bf16x8*)(lds_vt + swzp(dt * 16 + l15, 64 + l4 * 16));
      o_acc[dt] = mfma16(pa[0], vb0, o_acc[dt]);
      o_acc[dt] = mfma16(pa[1], vb1, o_acc[dt]);
    }
  }

  // write O back in (s, b, d) layout for out-projection GEMM
#pragma unroll
  for (int dt = 0; dt < 4; ++dt) {
#pragma unroll
    for (int r4 = 0; r4 < 4; ++r4) {
      int i = i0 + w * 16 + l4 * 4 + r4;
      int d = dt * 16 + l15;
      float val = o_acc[dt][r4] / l_run[r4];
      obuf[(size_t)(i * BB + b) * DM + h * 64 + d] = f2b(val);
    }
  }
}

// ---------------- GLU + depthwise conv (K=31, pad 15) ----------------
__global__ __launch_bounds__(256) void glu_dwconv_kernel(const short* __restrict__ pw1,
                                                         const float* __restrict__ dww,
                                                         const float* __restrict__ dwb,
                                                         float* __restrict__ out) {
  __shared__ short glu[38 * 512];
  int tid = threadIdx.x;
  int b = blockIdx.x & 7;
  int s0 = (blockIdx.x >> 3) << 3;
  for (int idx = tid; idx < 38 * 64; idx += 256) {
    int r = idx >> 6, c8 = idx & 63;
    int s = s0 - 15 + r;
    bf16x8 res;
    if (s >= 0 && s < SQ) {
      const short* row = pw1 + (size_t)(s * BB + b) * 1024;
      bf16x8 a8 = *(const bf16x8*)(row + c8 * 8);
      bf16x8 g8 = *(const bf16x8*)(row + 512 + c8 * 8);
#pragma unroll
      for (int e = 0; e < 8; ++e) res[e] = f2b(b2f(a8[e]) * sigm(b2f(g8[e])));
    } else {
#pragma unroll
      for (int e = 0; e < 8; ++e) res[e] = 0;
    }
    *(bf16x8*)(glu + r * 512 + c8 * 8) = res;
  }
  __syncthreads();
#pragma unroll
  for (int c = 0; c < 2; ++c) {
    int d = tid + c * 256;
    float wreg[31];
#pragma unroll
    for (int k = 0; k < 31; ++k) wreg[k] = dww[d * 31 + k];
    float bb = dwb[d];
    for (int ri = 0; ri < 8; ++ri) {
      float acc = bb;
#pragma unroll
      for (int k = 0; k < 31; ++k)
        acc += wreg[k] * b2f(glu[(ri + k) * 512 + d]);
      out[(size_t)((s0 + ri) * BB + b) * 512 + d] = acc;
    }
  }
}

// ---------------- host ----------------
extern "C" void kernel_launch(void* const* d_in, const int* in_sizes, int n_in,
                              void* d_out, int out_size, void* d_ws, size_t ws_size,
                              hipStream_t stream) {
  const float* src    = (const float*)d_in[0];
  const float* pose   = (const float*)d_in[1];
  const float* ffm_w1 = (const float*)d_in[2];
  const float* ffm_b1 = (const float*)d_in[3];
  const float* ffm_w2 = (const float*)d_in[4];
  const float* ffm_b2 = (const float*)d_in[5];
  const float* in_w   = (const float*)d_in[6];
  const float* in_b   = (const float*)d_in[7];
  const float* out_w  = (const float*)d_in[8];
  const float* out_b  = (const float*)d_in[9];
  const float* pos_w  = (const float*)d_in[10];
  const float* bias_u = (const float*)d_in[11];
  const float* bias_v = (const float*)d_in[12];
  const float* pw1_w  = (const float*)d_in[13];
  const float* pw1_b  = (const float*)d_in[14];
  const float* dw_w   = (const float*)d_in[15];
  const float* dw_b   = (const float*)d_in[16];
  const float* cng    = (const float*)d_in[17];
  const float* cnb    = (const float*)d_in[18];
  const float* pw2_w  = (const float*)d_in[19];
  const float* pw2_b  = (const float*)d_in[20];
  const float* ff_w1  = (const float*)d_in[21];
  const float* ff_b1  = (const float*)d_in[22];
  const float* ff_w2  = (const float*)d_in[23];
  const float* ff_b2  = (const float*)d_in[24];
  const float* g_ffm  = (const float*)d_in[25];
  const float* b_ffm  = (const float*)d_in[26];
  const float* g_mha  = (const float*)d_in[27];
  const float* b_mha  = (const float*)d_in[28];
  const float* g_conv = (const float*)d_in[29];
  const float* b_conv = (const float*)d_in[30];
  const float* g_ff   = (const float*)d_in[31];
  const float* b_ff   = (const float*)d_in[32];
  const float* g_fin  = (const float*)d_in[33];
  const float* b_fin  = (const float*)d_in[34];

  char* ws = (char*)d_ws;
  size_t off = 0;
  auto alloc = [&](size_t bytes) -> void* {
    void* p = ws + off;
    off += (bytes + 255) & ~(size_t)255;
    return p;
  };
  short* wb_ffm1 = (short*)alloc((size_t)FF * DM * 2);
  short* wb_ffm2 = (short*)alloc((size_t)DM * FF * 2);
  short* wb_in   = (short*)alloc((size_t)3 * DM * DM * 2);
  short* wb_out  = (short*)alloc((size_t)DM * DM * 2);
  short* wb_pos  = (short*)alloc((size_t)DM * DM * 2);
  short* wb_pw1  = (short*)alloc((size_t)2 * DM * DM * 2);
  short* wb_pw2  = (short*)alloc((size_t)DM * DM * 2);
  short* wb_ff1  = (short*)alloc((size_t)FF * DM * 2);
  short* wb_ff2  = (short*)alloc((size_t)DM * FF * 2);
  short* pos_src = (short*)alloc((size_t)2048 * DM * 2);
  short* pos_bf  = (short*)alloc((size_t)2048 * DM * 2);
  short* lnb     = (short*)alloc((size_t)NROWS * DM * 2);
  short* hbig    = (short*)alloc((size_t)NROWS * FF * 2);   // FFN hidden / pw1raw / QU,QV,K,VT
  short* qkvb    = (short*)alloc((size_t)NROWS * 3 * DM * 2); // qkv proj out / dwout f32
  short* obuf    = (short*)alloc((size_t)NROWS * DM * 2);   // attn out / conv_y
  float* x1      = (float*)alloc((size_t)NROWS * DM * 4);   // also x3
  float* x2      = (float*)alloc((size_t)NROWS * DM * 4);   // also x4
  float* dwout   = (float*)qkvb;
  short* pw1raw  = hbig;
  short* convy   = obuf;
  float* x3 = x1;
  float* x4 = x2;
  // attention prep buffers overlap hbig (free during MHA section): 4 x 8MB = 32MB = hbig
  short* QU  = hbig;
  short* QV  = hbig + (size_t)4194304;
  short* Kp  = hbig + (size_t)2 * 4194304;
  short* VTp = hbig + (size_t)3 * 4194304;

  auto cvt = [&](const float* s, short* d, size_t n) {
    int n4 = (int)(n >> 2);
    cvt_kernel<<<dim3((n4 + 255) / 256), dim3(256), 0, stream>>>(s, d, n4);
  };
  cvt(ffm_w1, wb_ffm1, (size_t)FF * DM);
  cvt(ffm_w2, wb_ffm2, (size_t)DM * FF);
  cvt(in_w,   wb_in,   (size_t)3 * DM * DM);
  cvt(out_w,  wb_out,  (size_t)DM * DM);
  cvt(pos_w,  wb_pos,  (size_t)DM * DM);
  cvt(pw1_w,  wb_pw1,  (size_t)2 * DM * DM);
  cvt(pw2_w,  wb_pw2,  (size_t)DM * DM);
  cvt(ff_w1,  wb_ff1,  (size_t)FF * DM);
  cvt(ff_w2,  wb_ff2,  (size_t)DM * FF);
  cvt(pose,   pos_src, (size_t)2047 * DM);

  auto gemm = [&](int EPI, const short* A, const short* W, const float* bias,
                  const float* res, float alpha, void* out, int M, int N, int K) {
    dim3 g((M / 128) * (N / 128)), blk(256);
    switch (EPI) {
      case 0: gemm_bt<0><<<g, blk, 0, stream>>>(A, W, bias, res, alpha, out, M, N, K); break;
      case 1: gemm_bt<1><<<g, blk, 0, stream>>>(A, W, bias, res, alpha, out, M, N, K); break;
      case 2: gemm_bt<2><<<g, blk, 0, stream>>>(A, W, bias, res, alpha, out, M, N, K); break;
      default: gemm_bt<3><<<g, blk, 0, stream>>>(A, W, bias, res, alpha, out, M, N, K); break;
    }
  };
  auto ln = [&](int MODE, const float* x, const float* g, const float* b, void* o) {
    dim3 grid(NROWS / 4), blk(256);
    if (MODE == 0)      ln_kernel<0><<<grid, blk, 0, stream>>>(x, g, b, o);
    else if (MODE == 1) ln_kernel<1><<<grid, blk, 0, stream>>>(x, g, b, o);
    else                ln_kernel<2><<<grid, blk, 0, stream>>>(x, g, b, o);
  };

  // positional projection: (2048 x 512) @ pos_w^T -> bf16 (row 2047 garbage, never gathered)
  gemm(3, pos_src, wb_pos, nullptr, nullptr, 0.f, pos_bf, 2048, DM, DM);

  // macaron FFN: x1 = src + 0.5*ffn(ln(src))
  ln(0, src, g_ffm, b_ffm, lnb);
  gemm(1, lnb, wb_ffm1, ffm_b1, nullptr, 0.f, hbig, NROWS, FF, DM);
  gemm(2, hbig, wb_ffm2, ffm_b2, src, 0.5f, x1, NROWS, DM, FF);

  // MHA: x2 = x1 + out_proj(attn(ln(x1)))
  ln(0, x1, g_mha, b_mha, lnb);
  gemm(0, lnb, wb_in, in_b, nullptr, 0.f, qkvb, NROWS, 3 * DM, DM);
  prep_kernel<<<dim3(1024), dim3(256), 0, stream>>>(qkvb, bias_u, bias_v, QU, QV, Kp, VTp);
  attn_kernel<<<dim3(512), dim3(512), 0, stream>>>(QU, QV, Kp, VTp, pos_bf, obuf);
  gemm(2, obuf, wb_out, out_b, x1, 1.f, x2, NROWS, DM, DM);

  // conv module: x3 = x2 + pw2(swish(ln(dwconv(glu(pw1(ln(x2)))))))
  ln(0, x2, g_conv, b_conv, lnb);
  gemm(0, lnb, wb_pw1, pw1_b, nullptr, 0.f, pw1raw, NROWS, 2 * DM, DM);
  glu_dwconv_kernel<<<dim3(1024), dim3(256), 0, stream>>>(pw1raw, dw_w, dw_b, dwout);
  ln(2, dwout, cng, cnb, convy);
  gemm(2, convy, wb_pw2, pw2_b, x2, 1.f, x3, NROWS, DM, DM);

  // final FFN: x4 = x3 + ffn(ln(x3))
  ln(0, x3, g_ff, b_ff, lnb);
  gemm(1, lnb, wb_ff1, ff_b1, nullptr, 0.f, hbig, NROWS, FF, DM);
  gemm(2, hbig, wb_ff2, ff_b2, x3, 1.f, x4, NROWS, DM, FF);

  // final LN -> f32 output
  ln(1, x4, g_fin, b_fin, d_out);

  (void)in_sizes; (void)n_in; (void)out_size; (void)ws_size;
}

// Round 4
// 446.707 us; speedup vs baseline: 1.0687x; 1.0035x over previous
//
#include <hip/hip_runtime.h>

typedef __attribute__((ext_vector_type(8))) short bf16x8;
typedef __attribute__((ext_vector_type(4))) short s16x4;
typedef __attribute__((ext_vector_type(4))) float f32x4;
typedef unsigned int u32;

#define SQ 1024
#define BB 8
#define DM 512
#define NH 8
#define HD 64
#define FF 2048
#define NROWS (SQ*BB)

static __device__ __forceinline__ float b2f(short s) {
  return __uint_as_float(((u32)(unsigned short)s) << 16);
}
static __device__ __forceinline__ short f2b(float f) {
  u32 u = __float_as_uint(f);
  return (short)((u + 0x7FFFu + ((u >> 16) & 1u)) >> 16);
}
static __device__ __forceinline__ float sigm(float x) { return 1.f / (1.f + __expf(-x)); }

static __device__ __forceinline__ f32x4 mfma16(bf16x8 a, bf16x8 b, f32x4 c) {
  return __builtin_amdgcn_mfma_f32_16x16x32_bf16(a, b, c, 0, 0, 0);
}

static __device__ __forceinline__ void gload16(const void* g, void* l) {
  __builtin_amdgcn_global_load_lds(
      (const __attribute__((address_space(1))) void*)g,
      (__attribute__((address_space(3))) void*)l, 16, 0, 0);
}

// XOR swizzle for row-major [*][64 bf16] tiles (128 B row stride)
static __device__ __forceinline__ int swzp(int r, int byteoff) {
  return (r * 128 + byteoff) ^ ((r & 7) << 4);
}

#define WAIT_LGKM() do { \
    asm volatile("s_waitcnt lgkmcnt(0)" ::: "memory"); \
    __builtin_amdgcn_sched_barrier(0); } while (0)
#define WAIT_VM(n) do { \
    asm volatile("s_waitcnt vmcnt(" #n ")" ::: "memory"); \
    __builtin_amdgcn_sched_barrier(0); } while (0)

// ---------------- f32 -> bf16 convert (4-wide) ----------------
__global__ __launch_bounds__(256) void cvt_kernel(const float* __restrict__ in,
                                                  short* __restrict__ out, int n4) {
  int i = blockIdx.x * 256 + threadIdx.x;
  if (i >= n4) return;
  float4 v = ((const float4*)in)[i];
  s16x4 r = { f2b(v.x), f2b(v.y), f2b(v.z), f2b(v.w) };
  ((s16x4*)out)[i] = r;
}

// ---------------- row LayerNorm, D=512, one wave per row ----------------
template<int MODE>
__global__ __launch_bounds__(256) void ln_kernel(const float* __restrict__ x,
                                                 const float* __restrict__ gam,
                                                 const float* __restrict__ bet,
                                                 void* __restrict__ out) {
  int w = threadIdx.x >> 6, lane = threadIdx.x & 63;
  int row = (blockIdx.x << 2) + w;
  const float* xr = x + (size_t)row * DM + lane * 8;
  float4 a = *(const float4*)xr;
  float4 c = *(const float4*)(xr + 4);
  float v[8] = {a.x, a.y, a.z, a.w, c.x, c.y, c.z, c.w};
  float s = 0.f, q = 0.f;
#pragma unroll
  for (int e = 0; e < 8; ++e) { s += v[e]; q += v[e] * v[e]; }
#pragma unroll
  for (int m = 1; m < 64; m <<= 1) { s += __shfl_xor(s, m); q += __shfl_xor(q, m); }
  float mean = s * (1.f / DM);
  float rstd = rsqrtf(q * (1.f / DM) - mean * mean + 1e-5f);
  int col = lane * 8;
  if (MODE == 1) {
    float* o = (float*)out + (size_t)row * DM + col;
    float y[8];
#pragma unroll
    for (int e = 0; e < 8; ++e) y[e] = (v[e] - mean) * rstd * gam[col + e] + bet[col + e];
    *(float4*)o = make_float4(y[0], y[1], y[2], y[3]);
    *(float4*)(o + 4) = make_float4(y[4], y[5], y[6], y[7]);
  } else {
    bf16x8 r;
#pragma unroll
    for (int e = 0; e < 8; ++e) {
      float y = (v[e] - mean) * rstd * gam[col + e] + bet[col + e];
      if (MODE == 2) y = y * sigm(y);
      r[e] = f2b(y);
    }
    *(bf16x8*)((short*)out + (size_t)row * DM + col) = r;
  }
}

// ---------------- 256x256 GEMM, BK=32, ring-3 frag-blocked LDS, counted vmcnt ----------------
// C = A(MxK) * W(NxK)^T.  EPI 0: +bias -> bf16 ; 1: swish(+bias) -> bf16
// 512 thr = 8 waves (wm=w>>2, wn=w&3); wave out 128x64; 1 block/CU (96KB LDS)
template<int EPI>
__global__ __launch_bounds__(512, 2) void gemm256(const short* __restrict__ A,
                                                  const short* __restrict__ W,
                                                  const float* __restrict__ bias,
                                                  short* __restrict__ out,
                                                  int M, int N, int K) {
  // 3 ring bufs x 32KB; each buf = 32 chunks x 1KB (chunks 0-15: A mf, 16-31: B nf)
  __shared__ __align__(16) short lds[3 * 16384];
  int nb = N >> 8;
  int nwg = gridDim.x, bid = blockIdx.x;
  int bid2 = ((nwg & 7) == 0) ? ((bid & 7) * (nwg >> 3) + (bid >> 3)) : bid;
  int bm = bid2 / nb, bn = bid2 % nb;
  int m0 = bm << 8, n0 = bn << 8;
  int tid = threadIdx.x, w = tid >> 6, lane = tid & 63;
  int wm = w >> 2, wn = w & 3;
  int l15 = lane & 15, l4 = lane >> 4;
  int srow = lane >> 2, scol = (lane & 3) << 3;  // stage: 16 rows x 4 slots of 8 elems

  // this wave's staging source (4 chunks of 16 rows; A for waves 0-3, B for 4-7)
  const short* gsrc = (w < 4) ? (A + (size_t)(m0 + w * 64 + srow) * K + scol)
                              : (W + (size_t)(n0 + (w - 4) * 64 + srow) * K + scol);

  f32x4 acc[8][4];
#pragma unroll
  for (int i = 0; i < 8; ++i)
#pragma unroll
    for (int j = 0; j < 4; ++j) acc[i][j] = (f32x4){0.f, 0.f, 0.f, 0.f};

  auto stage2 = [&](int u, int kt, int q0) {
#pragma unroll
    for (int q = q0; q < q0 + 2; ++q)
      gload16(gsrc + (size_t)(q * 16) * K + kt,
              (char*)lds + u * 32768 + (w * 4 + q) * 1024);
  };
  auto rdA = [&](int u, int mf) -> bf16x8 {
    return *(const bf16x8*)((char*)lds + u * 32768 + (wm * 8 + mf) * 1024 + l15 * 64 + l4 * 16);
  };
  auto rdB = [&](int u, int nf) -> bf16x8 {
    return *(const bf16x8*)((char*)lds + u * 32768 + 16384 + (wn * 4 + nf) * 1024 + l15 * 64 + l4 * 16);
  };

  int nt = K >> 5;
  // prologue: stage tiles 0,1 -> bufs 0,1 ; wait tile0 (leave tile1 in flight)
  stage2(0, 0, 0); stage2(0, 0, 2);
  stage2(1, 32, 0); stage2(1, 32, 2);
  WAIT_VM(4);
  __builtin_amdgcn_s_barrier();

  int u = 0;
  for (int t = 0; t < nt; ++t) {
    int kt2 = (t + 2) << 5;
    int us = u + 2; if (us >= 3) us -= 3;
    bool st = (t + 2) < nt;
    bf16x8 afrag[4], bfrag[4];
    // ---- phase A: mf 0-3 ----
#pragma unroll
    for (int nf = 0; nf < 4; ++nf) bfrag[nf] = rdB(u, nf);
#pragma unroll
    for (int mf = 0; mf < 4; ++mf) afrag[mf] = rdA(u, mf);
    if (st) stage2(us, kt2, 0);
    __builtin_amdgcn_s_barrier();
    WAIT_LGKM();
    __builtin_amdgcn_s_setprio(1);
#pragma unroll
    for (int mf = 0; mf < 4; ++mf)
#pragma unroll
      for (int nf = 0; nf < 4; ++nf)
        acc[mf][nf] = mfma16(afrag[mf], bfrag[nf], acc[mf][nf]);
    __builtin_amdgcn_s_setprio(0);
    __builtin_amdgcn_s_barrier();
    // ---- phase B: mf 4-7 ----
#pragma unroll
    for (int mf = 0; mf < 4; ++mf) afrag[mf] = rdA(u, mf + 4);
    if (st) stage2(us, kt2, 2);
    __builtin_amdgcn_s_barrier();
    WAIT_LGKM();
    __builtin_amdgcn_s_setprio(1);
#pragma unroll
    for (int mf = 0; mf < 4; ++mf)
#pragma unroll
      for (int nf = 0; nf < 4; ++nf)
        acc[mf + 4][nf] = mfma16(afrag[mf], bfrag[nf], acc[mf + 4][nf]);
    __builtin_amdgcn_s_setprio(0);
    if (t < nt - 1) {
      if (st) { WAIT_VM(4); } else { WAIT_VM(0); }
    }
    __builtin_amdgcn_s_barrier();
    ++u; if (u >= 3) u -= 3;
  }

  // epilogue
#pragma unroll
  for (int nf = 0; nf < 4; ++nf) {
    int col = n0 + wn * 64 + nf * 16 + l15;
    float bv = bias[col];
#pragma unroll
    for (int mf = 0; mf < 8; ++mf) {
#pragma unroll
      for (int r4 = 0; r4 < 4; ++r4) {
        int row = m0 + wm * 128 + mf * 16 + l4 * 4 + r4;
        float v = acc[mf][nf][r4] + bv;
        if (EPI == 1) v = v * sigm(v);
        out[(size_t)row * N + col] = f2b(v);
      }
    }
  }
}

// ---------------- 128x128 GEMM (2-phase), for N=512 / small grids ----------------
// EPI 0: +bias -> bf16 ; 1: swish(+bias) -> bf16 ; 2: res + alpha*(+bias) -> f32 ; 3: plain -> bf16
template<int EPI>
__global__ __launch_bounds__(256) void gemm_bt(const short* __restrict__ A,
                                               const short* __restrict__ W,
                                               const float* __restrict__ bias,
                                               const float* __restrict__ res,
                                               float alpha, void* __restrict__ out,
                                               int M, int N, int K) {
  __shared__ __align__(16) short ldsA[2 * 128 * 32];
  __shared__ __align__(16) short ldsB[2 * 128 * 32];
  int nb = N >> 7;
  int nwg = gridDim.x, bid = blockIdx.x;
  int bid2 = ((nwg & 7) == 0) ? ((bid & 7) * (nwg >> 3) + (bid >> 3)) : bid;
  int bm = bid2 / nb, bn = bid2 % nb;
  int m0 = bm << 7, n0 = bn << 7;
  int tid = threadIdx.x, w = tid >> 6, lane = tid & 63;
  int wm = w >> 1, wn = w & 1;
  f32x4 acc[4][4];
#pragma unroll
  for (int i = 0; i < 4; ++i)
#pragma unroll
    for (int j = 0; j < 4; ++j) acc[i][j] = (f32x4){0.f, 0.f, 0.f, 0.f};

  auto stage = [&](int bufsel, int kt) {
#pragma unroll
    for (int q = 0; q < 2; ++q) {
      int c = (q * 4 + w) * 64 + lane;
      int r = c >> 2, cc = c & 3;
      gload16(A + (size_t)(m0 + r) * K + kt + cc * 8,
              (char*)ldsA + bufsel * 8192 + (q * 4 + w) * 1024);
      gload16(W + (size_t)(n0 + r) * K + kt + cc * 8,
              (char*)ldsB + bufsel * 8192 + (q * 4 + w) * 1024);
    }
  };

  stage(0, 0);
  asm volatile("s_waitcnt vmcnt(0)" ::: "memory");
  __syncthreads();
  int cur = 0;
  for (int kt = 0; kt < K; kt += 32) {
    if (kt + 32 < K) stage(cur ^ 1, kt + 32);
    int rr = lane & 15, kk = (lane >> 4) << 3;
    bf16x8 af[4], bfr[4];
#pragma unroll
    for (int mt = 0; mt < 4; ++mt)
      af[mt] = *(const bf16x8*)(ldsA + cur * 4096 + (wm * 64 + mt * 16 + rr) * 32 + kk);
#pragma unroll
    for (int nt = 0; nt < 4; ++nt)
      bfr[nt] = *(const bf16x8*)(ldsB + cur * 4096 + (wn * 64 + nt * 16 + rr) * 32 + kk);
#pragma unroll
    for (int mt = 0; mt < 4; ++mt)
#pragma unroll
      for (int nt = 0; nt < 4; ++nt)
        acc[mt][nt] = mfma16(af[mt], bfr[nt], acc[mt][nt]);
    asm volatile("s_waitcnt vmcnt(0)" ::: "memory");
    __syncthreads();
    cur ^= 1;
  }

#pragma unroll
  for (int mt = 0; mt < 4; ++mt) {
#pragma unroll
    for (int nt = 0; nt < 4; ++nt) {
      int col = n0 + wn * 64 + nt * 16 + (lane & 15);
      float bv = (EPI == 3) ? 0.f : bias[col];
#pragma unroll
      for (int r4 = 0; r4 < 4; ++r4) {
        int row = m0 + wm * 64 + mt * 16 + (lane >> 4) * 4 + r4;
        size_t idx = (size_t)row * N + col;
        float v = acc[mt][nt][r4] + bv;
        if (EPI == 0 || EPI == 3) ((short*)out)[idx] = f2b(v);
        else if (EPI == 1) ((short*)out)[idx] = f2b(v * sigm(v));
        else ((float*)out)[idx] = res[idx] + alpha * v;
      }
    }
  }
}

// ---------------- QKV prep: per-head contiguous QU/QV/K and transposed V ----------------
__global__ __launch_bounds__(256) void prep_kernel(const short* __restrict__ qkv,
                                                   const float* __restrict__ bias_u,
                                                   const float* __restrict__ bias_v,
                                                   short* __restrict__ QU,
                                                   short* __restrict__ QV,
                                                   short* __restrict__ Kp,
                                                   short* __restrict__ VTp) {
  __shared__ short ldsv[64 * 66];
  int tid = threadIdx.x;
  int st = blockIdx.x & 15, bh = blockIdx.x >> 4;
  int b = bh >> 3, h = bh & 7;
  int s0 = st << 6;
#pragma unroll
  for (int pass = 0; pass < 2; ++pass) {
    int r = pass * 32 + (tid >> 3), c = tid & 7;
    int s = s0 + r;
    size_t grow = (size_t)(s * BB + b) * 1536 + h * 64 + c * 8;
    bf16x8 q8 = *(const bf16x8*)(qkv + grow);
    bf16x8 k8 = *(const bf16x8*)(qkv + grow + 512);
    bf16x8 v8 = *(const bf16x8*)(qkv + grow + 1024);
    bf16x8 u8, w8;
#pragma unroll
    for (int e = 0; e < 8; ++e) {
      float qf = b2f(q8[e]);
      u8[e] = f2b(qf + bias_u[h * 64 + c * 8 + e]);
      w8[e] = f2b(qf + bias_v[h * 64 + c * 8 + e]);
    }
    size_t dst = ((size_t)bh * SQ + s) * 64 + c * 8;
    *(bf16x8*)(QU + dst) = u8;
    *(bf16x8*)(QV + dst) = w8;
    *(bf16x8*)(Kp + dst) = k8;
    *(bf16x8*)(ldsv + r * 66 + c * 8) = v8;
  }
  __syncthreads();
#pragma unroll
  for (int pass = 0; pass < 2; ++pass) {
    int d = pass * 32 + (tid >> 3), sc = tid & 7;
    bf16x8 o;
#pragma unroll
    for (int u = 0; u < 8; ++u) o[u] = ldsv[(sc * 8 + u) * 66 + d];
    *(bf16x8*)(VTp + ((size_t)bh * 64 + d) * SQ + s0 + sc * 8) = o;
  }
}

// ---------------- fused rel-pos flash attention ----------------
__global__ __launch_bounds__(512, 4) void attn_kernel(const short* __restrict__ QU,
                                                      const short* __restrict__ QV,
                                                      const short* __restrict__ Kp,
                                                      const short* __restrict__ VTp,
                                                      const short* __restrict__ posb,
                                                      short* __restrict__ obuf) {
  __shared__ __align__(16) char smem[62464];
  char* lds_k   = smem;
  char* lds_vt  = smem + 8192;
  char* lds_pos = smem + 16384;
  char* lds_ew  = smem + 40960;

  int tid = threadIdx.x, w = tid >> 6, lane = tid & 63;
  int l15 = lane & 15, l4 = lane >> 4;
  int it = blockIdx.x & 7, bh = blockIdx.x >> 3;
  int b = bh >> 3, h = bh & 7;
  int i0 = it << 7;
  char* ewb = lds_ew + w * 2688;

  const size_t hoff = (size_t)bh * SQ * 64;
  const size_t hoffB = (size_t)bh * SQ * 128;

  int fr = i0 + w * 16 + l15;
  bf16x8 qu_f[2], qv_f[2];
  qu_f[0] = *(const bf16x8*)(QU + hoff + (size_t)fr * 64 + l4 * 8);
  qu_f[1] = *(const bf16x8*)(QU + hoff + (size_t)fr * 64 + 32 + l4 * 8);
  qv_f[0] = *(const bf16x8*)(QV + hoff + (size_t)fr * 64 + l4 * 8);
  qv_f[1] = *(const bf16x8*)(QV + hoff + (size_t)fr * 64 + 32 + l4 * 8);

  float m_run[4], l_run[4];
  f32x4 o_acc[4];
#pragma unroll
  for (int r4 = 0; r4 < 4; ++r4) { m_run[r4] = -1e30f; l_run[r4] = 0.f; }
#pragma unroll
  for (int dt = 0; dt < 4; ++dt) o_acc[dt] = (f32x4){0.f, 0.f, 0.f, 0.f};

  int prbase = 112 - 16 * w;
  int lnq = lane >> 3, lnr = lane & 7;

  for (int j0 = 0; j0 < SQ; j0 += 64) {
    __syncthreads();
    {
      int r = w * 8 + lnq;
      int byt = (lnr * 16) ^ ((r & 7) << 4);
      gload16((const char*)Kp + hoffB + (size_t)(j0 + r) * 128 + byt, lds_k + w * 1024);
      gload16((const char*)VTp + hoffB + (size_t)r * 2048 + (size_t)j0 * 2 + byt,
              lds_vt + w * 1024);
    }
    int nmin2 = 896 - i0 + j0;
#pragma unroll
    for (int q = 0; q < 3; ++q) {
      int ch = w * 3 + q;
      int r = ch * 8 + lnq;
      int byt = (lnr * 16) ^ ((r & 7) << 4);
      gload16((const char*)posb + (size_t)(nmin2 + r) * 1024 + h * 128 + byt,
              lds_pos + ch * 1024);
    }
    asm volatile("s_waitcnt vmcnt(0)" ::: "memory");
    __syncthreads();

    f32x4 ac[4];
    __builtin_amdgcn_s_setprio(1);
#pragma unroll
    for (int ct = 0; ct < 4; ++ct) {
      f32x4 z = (f32x4){0.f, 0.f, 0.f, 0.f};
      bf16x8 kb0 = *(const bf16x8*)(lds_k + swzp(ct * 16 + l15, l4 * 16));
      bf16x8 kb1 = *(const bf16x8*)(lds_k + swzp(ct * 16 + l15, 64 + l4 * 16));
      z = mfma16(qu_f[0], kb0, z);
      z = mfma16(qu_f[1], kb1, z);
      ac[ct] = z;
    }
    __builtin_amdgcn_s_setprio(0);
#pragma unroll
    for (int et = 0; et < 5; ++et) {
      f32x4 z = (f32x4){0.f, 0.f, 0.f, 0.f};
      int pr = prbase + et * 16 + l15;
      bf16x8 pb0 = *(const bf16x8*)(lds_pos + swzp(pr, l4 * 16));
      bf16x8 pb1 = *(const bf16x8*)(lds_pos + swzp(pr, 64 + l4 * 16));
      __builtin_amdgcn_s_setprio(1);
      z = mfma16(qv_f[0], pb0, z);
      z = mfma16(qv_f[1], pb1, z);
      __builtin_amdgcn_s_setprio(0);
#pragma unroll
      for (int r4 = 0; r4 < 4; ++r4)
        *(short*)(ewb + ((l4 * 4 + r4) * 84 + et * 16 + l15) * 2) = f2b(z[r4]);
    }
    WAIT_LGKM();

    float pst[4][4];
#pragma unroll
    for (int r4 = 0; r4 < 4; ++r4) {
      int iloc = l4 * 4 + r4;
      float sv[4];
      float mt = -1e30f;
#pragma unroll
      for (int ct = 0; ct < 4; ++ct) {
        int jj = ct * 16 + l15;
        float ev = b2f(*(const short*)(ewb + (iloc * 84 + (15 - iloc + jj)) * 2));
        float sc = (ac[ct][r4] + ev) * 0.125f;
        sv[ct] = sc;
        mt = fmaxf(mt, sc);
      }
#pragma unroll
      for (int msk = 1; msk < 16; msk <<= 1) mt = fmaxf(mt, __shfl_xor(mt, msk));
      float mn = fmaxf(m_run[r4], mt);
      float fac = __expf(m_run[r4] - mn);
      float ls = 0.f;
#pragma unroll
      for (int ct = 0; ct < 4; ++ct) {
        float pp = __expf(sv[ct] - mn);
        pst[ct][r4] = pp;
        ls += pp;
      }
#pragma unroll
      for (int msk = 1; msk < 16; msk <<= 1) ls += __shfl_xor(ls, msk);
      l_run[r4] = l_run[r4] * fac + ls;
      m_run[r4] = mn;
#pragma unroll
      for (int dt = 0; dt < 4; ++dt) o_acc[dt][r4] *= fac;
    }
    WAIT_LGKM();
#pragma unroll
    for (int r4 = 0; r4 < 4; ++r4) {
      int iloc = l4 * 4 + r4;
#pragma unroll
      for (int ct = 0; ct < 4; ++ct) {
        int jj = ct * 16 + l15;
        *(short*)(ewb + swzp(iloc, jj * 2)) = f2b(pst[ct][r4]);
      }
    }
    WAIT_LGKM();

    bf16x8 pa[2];
#pragma unroll
    for (int ks = 0; ks < 2; ++ks)
      pa[ks] = *(const bf16x8*)(ewb + swzp(l15, ks * 64 + l4 * 16));
    __builtin_amdgcn_s_setprio(1);
#pragma unroll
    for (int dt = 0; dt < 4; ++dt) {
      bf16x8 vb0 = *(const bf16x8*)(lds_vt + swzp(dt * 16 + l15, l4 * 16));
      bf16x8 vb1 = *(const bf16x8*)(lds_vt + swzp(dt * 16 + l15, 64 + l4 * 16));
      o_acc[dt] = mfma16(pa[0], vb0, o_acc[dt]);
      o_acc[dt] = mfma16(pa[1], vb1, o_acc[dt]);
    }
    __builtin_amdgcn_s_setprio(0);
  }

#pragma unroll
  for (int dt = 0; dt < 4; ++dt) {
#pragma unroll
    for (int r4 = 0; r4 < 4; ++r4) {
      int i = i0 + w * 16 + l4 * 4 + r4;
      int d = dt * 16 + l15;
      float val = o_acc[dt][r4] / l_run[r4];
      obuf[(size_t)(i * BB + b) * DM + h * 64 + d] = f2b(val);
    }
  }
}

// ---------------- GLU + depthwise conv (K=31, pad 15) ----------------
__global__ __launch_bounds__(256) void glu_dwconv_kernel(const short* __restrict__ pw1,
                                                         const float* __restrict__ dww,
                                                         const float* __restrict__ dwb,
                                                         float* __restrict__ out) {
  __shared__ short glu[38 * 512];
  int tid = threadIdx.x;
  int b = blockIdx.x & 7;
  int s0 = (blockIdx.x >> 3) << 3;
  for (int idx = tid; idx < 38 * 64; idx += 256) {
    int r = idx >> 6, c8 = idx & 63;
    int s = s0 - 15 + r;
    bf16x8 res;
    if (s >= 0 && s < SQ) {
      const short* row = pw1 + (size_t)(s * BB + b) * 1024;
      bf16x8 a8 = *(const bf16x8*)(row + c8 * 8);
      bf16x8 g8 = *(const bf16x8*)(row + 512 + c8 * 8);
#pragma unroll
      for (int e = 0; e < 8; ++e) res[e] = f2b(b2f(a8[e]) * sigm(b2f(g8[e])));
    } else {
#pragma unroll
      for (int e = 0; e < 8; ++e) res[e] = 0;
    }
    *(bf16x8*)(glu + r * 512 + c8 * 8) = res;
  }
  __syncthreads();
#pragma unroll
  for (int c = 0; c < 2; ++c) {
    int d = tid + c * 256;
    float wreg[31];
#pragma unroll
    for (int k = 0; k < 31; ++k) wreg[k] = dww[d * 31 + k];
    float bb = dwb[d];
    for (int ri = 0; ri < 8; ++ri) {
      float acc = bb;
#pragma unroll
      for (int k = 0; k < 31; ++k)
        acc += wreg[k] * b2f(glu[(ri + k) * 512 + d]);
      out[(size_t)((s0 + ri) * BB + b) * 512 + d] = acc;
    }
  }
}

// ---------------- host ----------------
extern "C" void kernel_launch(void* const* d_in, const int* in_sizes, int n_in,
                              void* d_out, int out_size, void* d_ws, size_t ws_size,
                              hipStream_t stream) {
  const float* src    = (const float*)d_in[0];
  const float* pose   = (const float*)d_in[1];
  const float* ffm_w1 = (const float*)d_in[2];
  const float* ffm_b1 = (const float*)d_in[3];
  const float* ffm_w2 = (const float*)d_in[4];
  const float* ffm_b2 = (const float*)d_in[5];
  const float* in_w   = (const float*)d_in[6];
  const float* in_b   = (const float*)d_in[7];
  const float* out_w  = (const float*)d_in[8];
  const float* out_b  = (const float*)d_in[9];
  const float* pos_w  = (const float*)d_in[10];
  const float* bias_u = (const float*)d_in[11];
  const float* bias_v = (const float*)d_in[12];
  const float* pw1_w  = (const float*)d_in[13];
  const float* pw1_b  = (const float*)d_in[14];
  const float* dw_w   = (const float*)d_in[15];
  const float* dw_b   = (const float*)d_in[16];
  const float* cng    = (const float*)d_in[17];
  const float* cnb    = (const float*)d_in[18];
  const float* pw2_w  = (const float*)d_in[19];
  const float* pw2_b  = (const float*)d_in[20];
  const float* ff_w1  = (const float*)d_in[21];
  const float* ff_b1  = (const float*)d_in[22];
  const float* ff_w2  = (const float*)d_in[23];
  const float* ff_b2  = (const float*)d_in[24];
  const float* g_ffm  = (const float*)d_in[25];
  const float* b_ffm  = (const float*)d_in[26];
  const float* g_mha  = (const float*)d_in[27];
  const float* b_mha  = (const float*)d_in[28];
  const float* g_conv = (const float*)d_in[29];
  const float* b_conv = (const float*)d_in[30];
  const float* g_ff   = (const float*)d_in[31];
  const float* b_ff   = (const float*)d_in[32];
  const float* g_fin  = (const float*)d_in[33];
  const float* b_fin  = (const float*)d_in[34];

  char* ws = (char*)d_ws;
  size_t off = 0;
  auto alloc = [&](size_t bytes) -> void* {
    void* p = ws + off;
    off += (bytes + 255) & ~(size_t)255;
    return p;
  };
  short* wb_ffm1 = (short*)alloc((size_t)FF * DM * 2);
  short* wb_ffm2 = (short*)alloc((size_t)DM * FF * 2);
  short* wb_in   = (short*)alloc((size_t)3 * DM * DM * 2);
  short* wb_out  = (short*)alloc((size_t)DM * DM * 2);
  short* wb_pos  = (short*)alloc((size_t)DM * DM * 2);
  short* wb_pw1  = (short*)alloc((size_t)2 * DM * DM * 2);
  short* wb_pw2  = (short*)alloc((size_t)DM * DM * 2);
  short* wb_ff1  = (short*)alloc((size_t)FF * DM * 2);
  short* wb_ff2  = (short*)alloc((size_t)DM * FF * 2);
  short* pos_src = (short*)alloc((size_t)2048 * DM * 2);
  short* pos_bf  = (short*)alloc((size_t)2048 * DM * 2);
  short* lnb     = (short*)alloc((size_t)NROWS * DM * 2);
  short* hbig    = (short*)alloc((size_t)NROWS * FF * 2);
  short* qkvb    = (short*)alloc((size_t)NROWS * 3 * DM * 2);
  short* obuf    = (short*)alloc((size_t)NROWS * DM * 2);
  float* x1      = (float*)alloc((size_t)NROWS * DM * 4);
  float* x2      = (float*)alloc((size_t)NROWS * DM * 4);
  float* dwout   = (float*)qkvb;
  short* pw1raw  = hbig;
  short* convy   = obuf;
  float* x3 = x1;
  float* x4 = x2;
  short* QU  = hbig;
  short* QV  = hbig + (size_t)4194304;
  short* Kp  = hbig + (size_t)2 * 4194304;
  short* VTp = hbig + (size_t)3 * 4194304;

  auto cvt = [&](const float* s, short* d, size_t n) {
    int n4 = (int)(n >> 2);
    cvt_kernel<<<dim3((n4 + 255) / 256), dim3(256), 0, stream>>>(s, d, n4);
  };
  cvt(ffm_w1, wb_ffm1, (size_t)FF * DM);
  cvt(ffm_w2, wb_ffm2, (size_t)DM * FF);
  cvt(in_w,   wb_in,   (size_t)3 * DM * DM);
  cvt(out_w,  wb_out,  (size_t)DM * DM);
  cvt(pos_w,  wb_pos,  (size_t)DM * DM);
  cvt(pw1_w,  wb_pw1,  (size_t)2 * DM * DM);
  cvt(pw2_w,  wb_pw2,  (size_t)DM * DM);
  cvt(ff_w1,  wb_ff1,  (size_t)FF * DM);
  cvt(ff_w2,  wb_ff2,  (size_t)DM * FF);
  cvt(pose,   pos_src, (size_t)2047 * DM);

  auto gemm = [&](int EPI, const short* A, const short* W, const float* bias,
                  const float* res, float alpha, void* out, int M, int N, int K) {
    dim3 g((M / 128) * (N / 128)), blk(256);
    switch (EPI) {
      case 0: gemm_bt<0><<<g, blk, 0, stream>>>(A, W, bias, res, alpha, out, M, N, K); break;
      case 1: gemm_bt<1><<<g, blk, 0, stream>>>(A, W, bias, res, alpha, out, M, N, K); break;
      case 2: gemm_bt<2><<<g, blk, 0, stream>>>(A, W, bias, res, alpha, out, M, N, K); break;
      default: gemm_bt<3><<<g, blk, 0, stream>>>(A, W, bias, res, alpha, out, M, N, K); break;
    }
  };
  auto gemm2 = [&](int EPI, const short* A, const short* W, const float* bias,
                   short* out, int M, int N, int K) {
    dim3 g((M / 256) * (N / 256)), blk(512);
    if (EPI == 0) gemm256<0><<<g, blk, 0, stream>>>(A, W, bias, out, M, N, K);
    else          gemm256<1><<<g, blk, 0, stream>>>(A, W, bias, out, M, N, K);
  };
  auto ln = [&](int MODE, const float* x, const float* g, const float* b, void* o) {
    dim3 grid(NROWS / 4), blk(256);
    if (MODE == 0)      ln_kernel<0><<<grid, blk, 0, stream>>>(x, g, b, o);
    else if (MODE == 1) ln_kernel<1><<<grid, blk, 0, stream>>>(x, g, b, o);
    else                ln_kernel<2><<<grid, blk, 0, stream>>>(x, g, b, o);
  };

  // positional projection
  gemm(3, pos_src, wb_pos, nullptr, nullptr, 0.f, pos_bf, 2048, DM, DM);

  // macaron FFN: x1 = src + 0.5*ffn(ln(src))
  ln(0, src, g_ffm, b_ffm, lnb);
  gemm2(1, lnb, wb_ffm1, ffm_b1, hbig, NROWS, FF, DM);
  gemm(2, hbig, wb_ffm2, ffm_b2, src, 0.5f, x1, NROWS, DM, FF);

  // MHA: x2 = x1 + out_proj(attn(ln(x1)))
  ln(0, x1, g_mha, b_mha, lnb);
  gemm2(0, lnb, wb_in, in_b, qkvb, NROWS, 3 * DM, DM);
  prep_kernel<<<dim3(1024), dim3(256), 0, stream>>>(qkvb, bias_u, bias_v, QU, QV, Kp, VTp);
  attn_kernel<<<dim3(512), dim3(512), 0, stream>>>(QU, QV, Kp, VTp, pos_bf, obuf);
  gemm(2, obuf, wb_out, out_b, x1, 1.f, x2, NROWS, DM, DM);

  // conv module
  ln(0, x2, g_conv, b_conv, lnb);
  gemm2(0, lnb, wb_pw1, pw1_b, pw1raw, NROWS, 2 * DM, DM);
  glu_dwconv_kernel<<<dim3(1024), dim3(256), 0, stream>>>(pw1raw, dw_w, dw_b, dwout);
  ln(2, dwout, cng, cnb, convy);
  gemm(2, convy, wb_pw2, pw2_b, x2, 1.f, x3, NROWS, DM, DM);

  // final FFN
  ln(0, x3, g_ff, b_ff, lnb);
  gemm2(1, lnb, wb_ff1, ff_b1, hbig, NROWS, FF, DM);
  gemm(2, hbig, wb_ff2, ff_b2, x3, 1.f, x4, NROWS, DM, FF);

  // final LN -> f32 output
  ln(1, x4, g_fin, b_fin, d_out);

  (void)in_sizes; (void)n_in; (void)out_size; (void)ws_size;
}

// Round 5
// 418.797 us; speedup vs baseline: 1.1399x; 1.0666x over previous
//
#include <hip/hip_runtime.h>

typedef __attribute__((ext_vector_type(8))) short bf16x8;
typedef __attribute__((ext_vector_type(4))) short s16x4;
typedef __attribute__((ext_vector_type(4))) float f32x4;
typedef unsigned int u32;

#define SQ 1024
#define BB 8
#define DM 512
#define NH 8
#define HD 64
#define FF 2048
#define NROWS (SQ*BB)

static __device__ __forceinline__ float b2f(short s) {
  return __uint_as_float(((u32)(unsigned short)s) << 16);
}
static __device__ __forceinline__ short f2b(float f) {
  u32 u = __float_as_uint(f);
  return (short)((u + 0x7FFFu + ((u >> 16) & 1u)) >> 16);
}
// cheap round (non-RNE) for hot inner-loop LDS stores
static __device__ __forceinline__ short f2bt(float f) {
  return (short)((__float_as_uint(f) + 0x8000u) >> 16);
}
static __device__ __forceinline__ float sigm(float x) { return 1.f / (1.f + __expf(-x)); }

static __device__ __forceinline__ f32x4 mfma16(bf16x8 a, bf16x8 b, f32x4 c) {
  return __builtin_amdgcn_mfma_f32_16x16x32_bf16(a, b, c, 0, 0, 0);
}

static __device__ __forceinline__ void gload16(const void* g, void* l) {
  __builtin_amdgcn_global_load_lds(
      (const __attribute__((address_space(1))) void*)g,
      (__attribute__((address_space(3))) void*)l, 16, 0, 0);
}

// XOR swizzle for row-major [*][64 bf16] tiles (128 B row stride)
static __device__ __forceinline__ int swzp(int r, int byteoff) {
  return (r * 128 + byteoff) ^ ((r & 7) << 4);
}

#define WAIT_LGKM() do { \
    asm volatile("s_waitcnt lgkmcnt(0)" ::: "memory"); \
    __builtin_amdgcn_sched_barrier(0); } while (0)
#define WAIT_VM(n) do { \
    asm volatile("s_waitcnt vmcnt(" #n ")" ::: "memory"); \
    __builtin_amdgcn_sched_barrier(0); } while (0)

// ---------------- f32 -> bf16 convert (4-wide) ----------------
__global__ __launch_bounds__(256) void cvt_kernel(const float* __restrict__ in,
                                                  short* __restrict__ out, int n4) {
  int i = blockIdx.x * 256 + threadIdx.x;
  if (i >= n4) return;
  float4 v = ((const float4*)in)[i];
  s16x4 r = { f2b(v.x), f2b(v.y), f2b(v.z), f2b(v.w) };
  ((s16x4*)out)[i] = r;
}

// ---------------- row LayerNorm, D=512, one wave per row ----------------
template<int MODE>
__global__ __launch_bounds__(256) void ln_kernel(const float* __restrict__ x,
                                                 const float* __restrict__ gam,
                                                 const float* __restrict__ bet,
                                                 void* __restrict__ out) {
  int w = threadIdx.x >> 6, lane = threadIdx.x & 63;
  int row = (blockIdx.x << 2) + w;
  const float* xr = x + (size_t)row * DM + lane * 8;
  float4 a = *(const float4*)xr;
  float4 c = *(const float4*)(xr + 4);
  float v[8] = {a.x, a.y, a.z, a.w, c.x, c.y, c.z, c.w};
  float s = 0.f, q = 0.f;
#pragma unroll
  for (int e = 0; e < 8; ++e) { s += v[e]; q += v[e] * v[e]; }
#pragma unroll
  for (int m = 1; m < 64; m <<= 1) { s += __shfl_xor(s, m); q += __shfl_xor(q, m); }
  float mean = s * (1.f / DM);
  float rstd = rsqrtf(q * (1.f / DM) - mean * mean + 1e-5f);
  int col = lane * 8;
  if (MODE == 1) {
    float* o = (float*)out + (size_t)row * DM + col;
    float y[8];
#pragma unroll
    for (int e = 0; e < 8; ++e) y[e] = (v[e] - mean) * rstd * gam[col + e] + bet[col + e];
    *(float4*)o = make_float4(y[0], y[1], y[2], y[3]);
    *(float4*)(o + 4) = make_float4(y[4], y[5], y[6], y[7]);
  } else {
    bf16x8 r;
#pragma unroll
    for (int e = 0; e < 8; ++e) {
      float y = (v[e] - mean) * rstd * gam[col + e] + bet[col + e];
      if (MODE == 2) y = y * sigm(y);
      r[e] = f2b(y);
    }
    *(bf16x8*)((short*)out + (size_t)row * DM + col) = r;
  }
}

// ---------------- 256x256 GEMM, BK=32, ring-3, counted vmcnt, st_16x32 swizzle ----------------
template<int EPI>
__global__ __launch_bounds__(512, 2) void gemm256(const short* __restrict__ A,
                                                  const short* __restrict__ W,
                                                  const float* __restrict__ bias,
                                                  short* __restrict__ out,
                                                  int M, int N, int K) {
  __shared__ __align__(16) short lds[3 * 16384];
  int nb = N >> 8;
  int nwg = gridDim.x, bid = blockIdx.x;
  int bid2 = ((nwg & 7) == 0) ? ((bid & 7) * (nwg >> 3) + (bid >> 3)) : bid;
  int bm = bid2 / nb, bn = bid2 % nb;
  int m0 = bm << 8, n0 = bn << 8;
  int tid = threadIdx.x, w = tid >> 6, lane = tid & 63;
  int wm = w >> 2, wn = w & 3;
  int l15 = lane & 15, l4 = lane >> 4;
  int srow = lane >> 2;
  // st_16x32: physical slot holds logical slot ^ ((row>>3)<<1); lane's phys slot = lane&3
  int slog = (lane & 3) ^ (((lane >> 5) & 1) << 1);
  int scol = slog << 3;

  const short* gsrc = (w < 4) ? (A + (size_t)(m0 + w * 64 + srow) * K + scol)
                              : (W + (size_t)(n0 + (w - 4) * 64 + srow) * K + scol);

  f32x4 acc[8][4];
#pragma unroll
  for (int i = 0; i < 8; ++i)
#pragma unroll
    for (int j = 0; j < 4; ++j) acc[i][j] = (f32x4){0.f, 0.f, 0.f, 0.f};

  auto stage2 = [&](int u, int kt, int q0) {
#pragma unroll
    for (int q = q0; q < q0 + 2; ++q)
      gload16(gsrc + (size_t)(q * 16) * K + kt,
              (char*)lds + u * 32768 + (w * 4 + q) * 1024);
  };
  // swizzled frag reads: phys slot = logical l4 ^ ((l15>>3)<<1)
  auto rdA = [&](int u, int mf) -> bf16x8 {
    int ps = l4 ^ (((l15 >> 3) & 1) << 1);
    return *(const bf16x8*)((char*)lds + u * 32768 + (wm * 8 + mf) * 1024 + l15 * 64 + ps * 16);
  };
  auto rdB = [&](int u, int nf) -> bf16x8 {
    int ps = l4 ^ (((l15 >> 3) & 1) << 1);
    return *(const bf16x8*)((char*)lds + u * 32768 + 16384 + (wn * 4 + nf) * 1024 + l15 * 64 + ps * 16);
  };

  int nt = K >> 5;
  stage2(0, 0, 0); stage2(0, 0, 2);
  stage2(1, 32, 0); stage2(1, 32, 2);
  WAIT_VM(4);
  __builtin_amdgcn_s_barrier();

  int u = 0;
  for (int t = 0; t < nt; ++t) {
    int kt2 = (t + 2) << 5;
    int us = u + 2; if (us >= 3) us -= 3;
    bool st = (t + 2) < nt;
    bf16x8 afrag[4], bfrag[4];
#pragma unroll
    for (int nf = 0; nf < 4; ++nf) bfrag[nf] = rdB(u, nf);
#pragma unroll
    for (int mf = 0; mf < 4; ++mf) afrag[mf] = rdA(u, mf);
    if (st) stage2(us, kt2, 0);
    __builtin_amdgcn_s_barrier();
    WAIT_LGKM();
    __builtin_amdgcn_s_setprio(1);
#pragma unroll
    for (int mf = 0; mf < 4; ++mf)
#pragma unroll
      for (int nf = 0; nf < 4; ++nf)
        acc[mf][nf] = mfma16(afrag[mf], bfrag[nf], acc[mf][nf]);
    __builtin_amdgcn_s_setprio(0);
    __builtin_amdgcn_s_barrier();
#pragma unroll
    for (int mf = 0; mf < 4; ++mf) afrag[mf] = rdA(u, mf + 4);
    if (st) stage2(us, kt2, 2);
    __builtin_amdgcn_s_barrier();
    WAIT_LGKM();
    __builtin_amdgcn_s_setprio(1);
#pragma unroll
    for (int mf = 0; mf < 4; ++mf)
#pragma unroll
      for (int nf = 0; nf < 4; ++nf)
        acc[mf + 4][nf] = mfma16(afrag[mf], bfrag[nf], acc[mf + 4][nf]);
    __builtin_amdgcn_s_setprio(0);
    if (t < nt - 1) {
      if (st) { WAIT_VM(4); } else { WAIT_VM(0); }
    }
    __builtin_amdgcn_s_barrier();
    ++u; if (u >= 3) u -= 3;
  }

#pragma unroll
  for (int nf = 0; nf < 4; ++nf) {
    int col = n0 + wn * 64 + nf * 16 + l15;
    float bv = bias[col];
#pragma unroll
    for (int mf = 0; mf < 8; ++mf) {
#pragma unroll
      for (int r4 = 0; r4 < 4; ++r4) {
        int row = m0 + wm * 128 + mf * 16 + l4 * 4 + r4;
        float v = acc[mf][nf][r4] + bv;
        if (EPI == 1) v = v * sigm(v);
        out[(size_t)row * N + col] = f2b(v);
      }
    }
  }
}

// ---------------- 128x128 GEMM (2-phase), for N=512 grids ----------------
template<int EPI>
__global__ __launch_bounds__(256) void gemm_bt(const short* __restrict__ A,
                                               const short* __restrict__ W,
                                               const float* __restrict__ bias,
                                               const float* __restrict__ res,
                                               float alpha, void* __restrict__ out,
                                               int M, int N, int K) {
  __shared__ __align__(16) short ldsA[2 * 128 * 32];
  __shared__ __align__(16) short ldsB[2 * 128 * 32];
  int nb = N >> 7;
  int nwg = gridDim.x, bid = blockIdx.x;
  int bid2 = ((nwg & 7) == 0) ? ((bid & 7) * (nwg >> 3) + (bid >> 3)) : bid;
  int bm = bid2 / nb, bn = bid2 % nb;
  int m0 = bm << 7, n0 = bn << 7;
  int tid = threadIdx.x, w = tid >> 6, lane = tid & 63;
  int wm = w >> 1, wn = w & 1;
  f32x4 acc[4][4];
#pragma unroll
  for (int i = 0; i < 4; ++i)
#pragma unroll
    for (int j = 0; j < 4; ++j) acc[i][j] = (f32x4){0.f, 0.f, 0.f, 0.f};

  auto stage = [&](int bufsel, int kt) {
#pragma unroll
    for (int q = 0; q < 2; ++q) {
      int c = (q * 4 + w) * 64 + lane;
      int r = c >> 2, cc = c & 3;
      gload16(A + (size_t)(m0 + r) * K + kt + cc * 8,
              (char*)ldsA + bufsel * 8192 + (q * 4 + w) * 1024);
      gload16(W + (size_t)(n0 + r) * K + kt + cc * 8,
              (char*)ldsB + bufsel * 8192 + (q * 4 + w) * 1024);
    }
  };

  stage(0, 0);
  asm volatile("s_waitcnt vmcnt(0)" ::: "memory");
  __syncthreads();
  int cur = 0;
  for (int kt = 0; kt < K; kt += 32) {
    if (kt + 32 < K) stage(cur ^ 1, kt + 32);
    int rr = lane & 15, kk = (lane >> 4) << 3;
    bf16x8 af[4], bfr[4];
#pragma unroll
    for (int mt = 0; mt < 4; ++mt)
      af[mt] = *(const bf16x8*)(ldsA + cur * 4096 + (wm * 64 + mt * 16 + rr) * 32 + kk);
#pragma unroll
    for (int nt = 0; nt < 4; ++nt)
      bfr[nt] = *(const bf16x8*)(ldsB + cur * 4096 + (wn * 64 + nt * 16 + rr) * 32 + kk);
#pragma unroll
    for (int mt = 0; mt < 4; ++mt)
#pragma unroll
      for (int nt = 0; nt < 4; ++nt)
        acc[mt][nt] = mfma16(af[mt], bfr[nt], acc[mt][nt]);
    asm volatile("s_waitcnt vmcnt(0)" ::: "memory");
    __syncthreads();
    cur ^= 1;
  }

#pragma unroll
  for (int mt = 0; mt < 4; ++mt) {
#pragma unroll
    for (int nt = 0; nt < 4; ++nt) {
      int col = n0 + wn * 64 + nt * 16 + (lane & 15);
      float bv = (EPI == 3) ? 0.f : bias[col];
#pragma unroll
      for (int r4 = 0; r4 < 4; ++r4) {
        int row = m0 + wm * 64 + mt * 16 + (lane >> 4) * 4 + r4;
        size_t idx = (size_t)row * N + col;
        float v = acc[mt][nt][r4] + bv;
        if (EPI == 0 || EPI == 3) ((short*)out)[idx] = f2b(v);
        else if (EPI == 1) ((short*)out)[idx] = f2b(v * sigm(v));
        else ((float*)out)[idx] = res[idx] + alpha * v;
      }
    }
  }
}

// ---------------- QKV prep ----------------
__global__ __launch_bounds__(256) void prep_kernel(const short* __restrict__ qkv,
                                                   const float* __restrict__ bias_u,
                                                   const float* __restrict__ bias_v,
                                                   short* __restrict__ QU,
                                                   short* __restrict__ QV,
                                                   short* __restrict__ Kp,
                                                   short* __restrict__ VTp) {
  __shared__ short ldsv[64 * 66];
  int tid = threadIdx.x;
  int st = blockIdx.x & 15, bh = blockIdx.x >> 4;
  int b = bh >> 3, h = bh & 7;
  int s0 = st << 6;
#pragma unroll
  for (int pass = 0; pass < 2; ++pass) {
    int r = pass * 32 + (tid >> 3), c = tid & 7;
    int s = s0 + r;
    size_t grow = (size_t)(s * BB + b) * 1536 + h * 64 + c * 8;
    bf16x8 q8 = *(const bf16x8*)(qkv + grow);
    bf16x8 k8 = *(const bf16x8*)(qkv + grow + 512);
    bf16x8 v8 = *(const bf16x8*)(qkv + grow + 1024);
    bf16x8 u8, w8;
#pragma unroll
    for (int e = 0; e < 8; ++e) {
      float qf = b2f(q8[e]);
      u8[e] = f2b(qf + bias_u[h * 64 + c * 8 + e]);
      w8[e] = f2b(qf + bias_v[h * 64 + c * 8 + e]);
    }
    size_t dst = ((size_t)bh * SQ + s) * 64 + c * 8;
    *(bf16x8*)(QU + dst) = u8;
    *(bf16x8*)(QV + dst) = w8;
    *(bf16x8*)(Kp + dst) = k8;
    *(bf16x8*)(ldsv + r * 66 + c * 8) = v8;
  }
  __syncthreads();
#pragma unroll
  for (int pass = 0; pass < 2; ++pass) {
    int d = pass * 32 + (tid >> 3), sc = tid & 7;
    bf16x8 o;
#pragma unroll
    for (int u = 0; u < 8; ++u) o[u] = ldsv[(sc * 8 + u) * 66 + d];
    *(bf16x8*)(VTp + ((size_t)bh * 64 + d) * SQ + s0 + sc * 8) = o;
  }
}

// ---------------- fused rel-pos flash attention (swapped-operand softmax) ----------------
// grid = 64(bh) * 8(i-tiles of 128); block 512 (8 waves, 16 q-rows each)
// Swapped mfma: lane owns q-row (l15); scores/e live on (reg, l4) dims.
__global__ __launch_bounds__(512, 4) void attn_kernel(const short* __restrict__ QU,
                                                      const short* __restrict__ QV,
                                                      const short* __restrict__ Kp,
                                                      const short* __restrict__ VTp,
                                                      const short* __restrict__ posb,
                                                      short* __restrict__ obuf) {
  __shared__ __align__(16) char smem[62464];
  char* lds_k   = smem;            // [64][64] bf16 swizzled
  char* lds_vt  = smem + 8192;     // [64 d][64 j]
  char* lds_pos = smem + 16384;    // [192][64]
  char* lds_ew  = smem + 40960;    // 8 waves x 2688B; e band [16 q][84 n]; P overlaps

  int tid = threadIdx.x, w = tid >> 6, lane = tid & 63;
  int l15 = lane & 15, l4 = lane >> 4;
  int it = blockIdx.x & 7, bh = blockIdx.x >> 3;
  int b = bh >> 3, h = bh & 7;
  int i0 = it << 7;
  char* ewb = lds_ew + w * 2688;

  const size_t hoff = (size_t)bh * SQ * 64;
  const size_t hoffB = (size_t)bh * SQ * 128;

  int fr = i0 + w * 16 + l15;
  bf16x8 qu_f[2], qv_f[2];
  qu_f[0] = *(const bf16x8*)(QU + hoff + (size_t)fr * 64 + l4 * 8);
  qu_f[1] = *(const bf16x8*)(QU + hoff + (size_t)fr * 64 + 32 + l4 * 8);
  qv_f[0] = *(const bf16x8*)(QV + hoff + (size_t)fr * 64 + l4 * 8);
  qv_f[1] = *(const bf16x8*)(QV + hoff + (size_t)fr * 64 + 32 + l4 * 8);

  float m_run = -1e30f, l_run = 0.f;
  f32x4 o_acc[4];
#pragma unroll
  for (int dt = 0; dt < 4; ++dt) o_acc[dt] = (f32x4){0.f, 0.f, 0.f, 0.f};

  int prbase = 112 - 16 * w;
  int lnq = lane >> 3, lnr = lane & 7;

  for (int j0 = 0; j0 < SQ; j0 += 64) {
    __syncthreads();
    {
      int r = w * 8 + lnq;
      int byt = (lnr * 16) ^ ((r & 7) << 4);
      gload16((const char*)Kp + hoffB + (size_t)(j0 + r) * 128 + byt, lds_k + w * 1024);
      gload16((const char*)VTp + hoffB + (size_t)r * 2048 + (size_t)j0 * 2 + byt,
              lds_vt + w * 1024);
    }
    int nmin2 = 896 - i0 + j0;
#pragma unroll
    for (int q = 0; q < 3; ++q) {
      int ch = w * 3 + q;
      int r = ch * 8 + lnq;
      int byt = (lnr * 16) ^ ((r & 7) << 4);
      gload16((const char*)posb + (size_t)(nmin2 + r) * 1024 + h * 128 + byt,
              lds_pos + ch * 1024);
    }
    asm volatile("s_waitcnt vmcnt(0)" ::: "memory");
    __syncthreads();

    // swapped QK^T: acs[kt] row = key-local (l4*4+r), col = q (l15)
    f32x4 acs[4];
    __builtin_amdgcn_s_setprio(1);
#pragma unroll
    for (int kt = 0; kt < 4; ++kt) {
      f32x4 z = (f32x4){0.f, 0.f, 0.f, 0.f};
      bf16x8 kb0 = *(const bf16x8*)(lds_k + swzp(kt * 16 + l15, l4 * 16));
      bf16x8 kb1 = *(const bf16x8*)(lds_k + swzp(kt * 16 + l15, 64 + l4 * 16));
      z = mfma16(kb0, qu_f[0], z);
      z = mfma16(kb1, qu_f[1], z);
      acs[kt] = z;
    }
    __builtin_amdgcn_s_setprio(0);
    // swapped e band: row = n-local (pt*16+l4*4+r), col = q (l15); store [q][n]
#pragma unroll
    for (int pt = 0; pt < 5; ++pt) {
      f32x4 z = (f32x4){0.f, 0.f, 0.f, 0.f};
      int pr = prbase + pt * 16 + l15;
      bf16x8 pb0 = *(const bf16x8*)(lds_pos + swzp(pr, l4 * 16));
      bf16x8 pb1 = *(const bf16x8*)(lds_pos + swzp(pr, 64 + l4 * 16));
      __builtin_amdgcn_s_setprio(1);
      z = mfma16(pb0, qv_f[0], z);
      z = mfma16(pb1, qv_f[1], z);
      __builtin_amdgcn_s_setprio(0);
#pragma unroll
      for (int r = 0; r < 4; ++r)
        *(short*)(ewb + (l15 * 84 + pt * 16 + l4 * 4 + r) * 2) = f2bt(z[r]);
    }
    WAIT_LGKM();

    // gather (n = 15 - q + j) + scores; lane-local row softmax
    float sv[4][4];
    float mt = -1e30f;
#pragma unroll
    for (int kt = 0; kt < 4; ++kt) {
#pragma unroll
      for (int r = 0; r < 4; ++r) {
        int n = 15 - l15 + kt * 16 + l4 * 4 + r;
        float ev = b2f(*(const short*)(ewb + (l15 * 84 + n) * 2));
        float sc = (acs[kt][r] + ev) * 0.125f;
        sv[kt][r] = sc;
        mt = fmaxf(mt, sc);
      }
    }
    mt = fmaxf(mt, __shfl_xor(mt, 16));
    mt = fmaxf(mt, __shfl_xor(mt, 32));
    // defer-max (T13): only rescale when max grew by > 8
    if (!__all(mt <= m_run + 8.f)) {
      float mn = fmaxf(m_run, mt);
      float fac = __expf(m_run - mn);
      m_run = mn;
      l_run *= fac;
      float fb[4];
#pragma unroll
      for (int r4 = 0; r4 < 4; ++r4) fb[r4] = __shfl(fac, (l4 << 2) + r4);
#pragma unroll
      for (int dt = 0; dt < 4; ++dt)
#pragma unroll
        for (int r4 = 0; r4 < 4; ++r4) o_acc[dt][r4] *= fb[r4];
    }
    float ls = 0.f;
#pragma unroll
    for (int kt = 0; kt < 4; ++kt) {
#pragma unroll
      for (int r = 0; r < 4; ++r) {
        float p = __expf(sv[kt][r] - m_run);
        ls += p;
        *(short*)(ewb + swzp(l15, (kt * 16 + l4 * 4 + r) * 2)) = f2bt(p);
      }
    }
    ls += __shfl_xor(ls, 16);
    ls += __shfl_xor(ls, 32);
    l_run += ls;
    WAIT_LGKM();

    // PV (unchanged): pa = P[q=l15][j], vb = VT[d][j]
    bf16x8 pa[2];
#pragma unroll
    for (int ks = 0; ks < 2; ++ks)
      pa[ks] = *(const bf16x8*)(ewb + swzp(l15, ks * 64 + l4 * 16));
    __builtin_amdgcn_s_setprio(1);
#pragma unroll
    for (int dt = 0; dt < 4; ++dt) {
      bf16x8 vb0 = *(const bf16x8*)(lds_vt + swzp(dt * 16 + l15, l4 * 16));
      bf16x8 vb1 = *(const bf16x8*)(lds_vt + swzp(dt * 16 + l15, 64 + l4 * 16));
      o_acc[dt] = mfma16(pa[0], vb0, o_acc[dt]);
      o_acc[dt] = mfma16(pa[1], vb1, o_acc[dt]);
    }
    __builtin_amdgcn_s_setprio(0);
  }

  // epilogue: l for q-row (l4*4+r4) lives in lane (l4*4+r4)
  float lb[4];
#pragma unroll
  for (int r4 = 0; r4 < 4; ++r4) lb[r4] = __shfl(l_run, (l4 << 2) + r4);
#pragma unroll
  for (int dt = 0; dt < 4; ++dt) {
#pragma unroll
    for (int r4 = 0; r4 < 4; ++r4) {
      int i = i0 + w * 16 + l4 * 4 + r4;
      int d = dt * 16 + l15;
      float val = o_acc[dt][r4] / lb[r4];
      obuf[(size_t)(i * BB + b) * DM + h * 64 + d] = f2b(val);
    }
  }
}

// ---------------- GLU + depthwise conv (K=31, pad 15) ----------------
__global__ __launch_bounds__(256) void glu_dwconv_kernel(const short* __restrict__ pw1,
                                                         const float* __restrict__ dww,
                                                         const float* __restrict__ dwb,
                                                         float* __restrict__ out) {
  __shared__ short glu[38 * 512];
  int tid = threadIdx.x;
  int b = blockIdx.x & 7;
  int s0 = (blockIdx.x >> 3) << 3;
  for (int idx = tid; idx < 38 * 64; idx += 256) {
    int r = idx >> 6, c8 = idx & 63;
    int s = s0 - 15 + r;
    bf16x8 res;
    if (s >= 0 && s < SQ) {
      const short* row = pw1 + (size_t)(s * BB + b) * 1024;
      bf16x8 a8 = *(const bf16x8*)(row + c8 * 8);
      bf16x8 g8 = *(const bf16x8*)(row + 512 + c8 * 8);
#pragma unroll
      for (int e = 0; e < 8; ++e) res[e] = f2b(b2f(a8[e]) * sigm(b2f(g8[e])));
    } else {
#pragma unroll
      for (int e = 0; e < 8; ++e) res[e] = 0;
    }
    *(bf16x8*)(glu + r * 512 + c8 * 8) = res;
  }
  __syncthreads();
#pragma unroll
  for (int c = 0; c < 2; ++c) {
    int d = tid + c * 256;
    float wreg[31];
#pragma unroll
    for (int k = 0; k < 31; ++k) wreg[k] = dww[d * 31 + k];
    float bb = dwb[d];
    for (int ri = 0; ri < 8; ++ri) {
      float acc = bb;
#pragma unroll
      for (int k = 0; k < 31; ++k)
        acc += wreg[k] * b2f(glu[(ri + k) * 512 + d]);
      out[(size_t)((s0 + ri) * BB + b) * 512 + d] = acc;
    }
  }
}

// ---------------- host ----------------
extern "C" void kernel_launch(void* const* d_in, const int* in_sizes, int n_in,
                              void* d_out, int out_size, void* d_ws, size_t ws_size,
                              hipStream_t stream) {
  const float* src    = (const float*)d_in[0];
  const float* pose   = (const float*)d_in[1];
  const float* ffm_w1 = (const float*)d_in[2];
  const float* ffm_b1 = (const float*)d_in[3];
  const float* ffm_w2 = (const float*)d_in[4];
  const float* ffm_b2 = (const float*)d_in[5];
  const float* in_w   = (const float*)d_in[6];
  const float* in_b   = (const float*)d_in[7];
  const float* out_w  = (const float*)d_in[8];
  const float* out_b  = (const float*)d_in[9];
  const float* pos_w  = (const float*)d_in[10];
  const float* bias_u = (const float*)d_in[11];
  const float* bias_v = (const float*)d_in[12];
  const float* pw1_w  = (const float*)d_in[13];
  const float* pw1_b  = (const float*)d_in[14];
  const float* dw_w   = (const float*)d_in[15];
  const float* dw_b   = (const float*)d_in[16];
  const float* cng    = (const float*)d_in[17];
  const float* cnb    = (const float*)d_in[18];
  const float* pw2_w  = (const float*)d_in[19];
  const float* pw2_b  = (const float*)d_in[20];
  const float* ff_w1  = (const float*)d_in[21];
  const float* ff_b1  = (const float*)d_in[22];
  const float* ff_w2  = (const float*)d_in[23];
  const float* ff_b2  = (const float*)d_in[24];
  const float* g_ffm  = (const float*)d_in[25];
  const float* b_ffm  = (const float*)d_in[26];
  const float* g_mha  = (const float*)d_in[27];
  const float* b_mha  = (const float*)d_in[28];
  const float* g_conv = (const float*)d_in[29];
  const float* b_conv = (const float*)d_in[30];
  const float* g_ff   = (const float*)d_in[31];
  const float* b_ff   = (const float*)d_in[32];
  const float* g_fin  = (const float*)d_in[33];
  const float* b_fin  = (const float*)d_in[34];

  char* ws = (char*)d_ws;
  size_t off = 0;
  auto alloc = [&](size_t bytes) -> void* {
    void* p = ws + off;
    off += (bytes + 255) & ~(size_t)255;
    return p;
  };
  short* wb_ffm1 = (short*)alloc((size_t)FF * DM * 2);
  short* wb_ffm2 = (short*)alloc((size_t)DM * FF * 2);
  short* wb_in   = (short*)alloc((size_t)3 * DM * DM * 2);
  short* wb_out  = (short*)alloc((size_t)DM * DM * 2);
  short* wb_pos  = (short*)alloc((size_t)DM * DM * 2);
  short* wb_pw1  = (short*)alloc((size_t)2 * DM * DM * 2);
  short* wb_pw2  = (short*)alloc((size_t)DM * DM * 2);
  short* wb_ff1  = (short*)alloc((size_t)FF * DM * 2);
  short* wb_ff2  = (short*)alloc((size_t)DM * FF * 2);
  short* pos_src = (short*)alloc((size_t)2048 * DM * 2);
  short* pos_bf  = (short*)alloc((size_t)2048 * DM * 2);
  short* lnb     = (short*)alloc((size_t)NROWS * DM * 2);
  short* hbig    = (short*)alloc((size_t)NROWS * FF * 2);
  short* qkvb    = (short*)alloc((size_t)NROWS * 3 * DM * 2);
  short* obuf    = (short*)alloc((size_t)NROWS * DM * 2);
  float* x1      = (float*)alloc((size_t)NROWS * DM * 4);
  float* x2      = (float*)alloc((size_t)NROWS * DM * 4);
  float* dwout   = (float*)qkvb;
  short* pw1raw  = hbig;
  short* convy   = obuf;
  float* x3 = x1;
  float* x4 = x2;
  short* QU  = hbig;
  short* QV  = hbig + (size_t)4194304;
  short* Kp  = hbig + (size_t)2 * 4194304;
  short* VTp = hbig + (size_t)3 * 4194304;

  auto cvt = [&](const float* s, short* d, size_t n) {
    int n4 = (int)(n >> 2);
    cvt_kernel<<<dim3((n4 + 255) / 256), dim3(256), 0, stream>>>(s, d, n4);
  };
  cvt(ffm_w1, wb_ffm1, (size_t)FF * DM);
  cvt(ffm_w2, wb_ffm2, (size_t)DM * FF);
  cvt(in_w,   wb_in,   (size_t)3 * DM * DM);
  cvt(out_w,  wb_out,  (size_t)DM * DM);
  cvt(pos_w,  wb_pos,  (size_t)DM * DM);
  cvt(pw1_w,  wb_pw1,  (size_t)2 * DM * DM);
  cvt(pw2_w,  wb_pw2,  (size_t)DM * DM);
  cvt(ff_w1,  wb_ff1,  (size_t)FF * DM);
  cvt(ff_w2,  wb_ff2,  (size_t)DM * FF);
  cvt(pose,   pos_src, (size_t)2047 * DM);

  auto gemm = [&](int EPI, const short* A, const short* W, const float* bias,
                  const float* res, float alpha, void* out, int M, int N, int K) {
    dim3 g((M / 128) * (N / 128)), blk(256);
    switch (EPI) {
      case 0: gemm_bt<0><<<g, blk, 0, stream>>>(A, W, bias, res, alpha, out, M, N, K); break;
      case 1: gemm_bt<1><<<g, blk, 0, stream>>>(A, W, bias, res, alpha, out, M, N, K); break;
      case 2: gemm_bt<2><<<g, blk, 0, stream>>>(A, W, bias, res, alpha, out, M, N, K); break;
      default: gemm_bt<3><<<g, blk, 0, stream>>>(A, W, bias, res, alpha, out, M, N, K); break;
    }
  };
  auto gemm2 = [&](int EPI, const short* A, const short* W, const float* bias,
                   short* out, int M, int N, int K) {
    dim3 g((M / 256) * (N / 256)), blk(512);
    if (EPI == 0) gemm256<0><<<g, blk, 0, stream>>>(A, W, bias, out, M, N, K);
    else          gemm256<1><<<g, blk, 0, stream>>>(A, W, bias, out, M, N, K);
  };
  auto ln = [&](int MODE, const float* x, const float* g, const float* b, void* o) {
    dim3 grid(NROWS / 4), blk(256);
    if (MODE == 0)      ln_kernel<0><<<grid, blk, 0, stream>>>(x, g, b, o);
    else if (MODE == 1) ln_kernel<1><<<grid, blk, 0, stream>>>(x, g, b, o);
    else                ln_kernel<2><<<grid, blk, 0, stream>>>(x, g, b, o);
  };

  // positional projection
  gemm(3, pos_src, wb_pos, nullptr, nullptr, 0.f, pos_bf, 2048, DM, DM);

  // macaron FFN: x1 = src + 0.5*ffn(ln(src))
  ln(0, src, g_ffm, b_ffm, lnb);
  gemm2(1, lnb, wb_ffm1, ffm_b1, hbig, NROWS, FF, DM);
  gemm(2, hbig, wb_ffm2, ffm_b2, src, 0.5f, x1, NROWS, DM, FF);

  // MHA: x2 = x1 + out_proj(attn(ln(x1)))
  ln(0, x1, g_mha, b_mha, lnb);
  gemm2(0, lnb, wb_in, in_b, qkvb, NROWS, 3 * DM, DM);
  prep_kernel<<<dim3(1024), dim3(256), 0, stream>>>(qkvb, bias_u, bias_v, QU, QV, Kp, VTp);
  attn_kernel<<<dim3(512), dim3(512), 0, stream>>>(QU, QV, Kp, VTp, pos_bf, obuf);
  gemm(2, obuf, wb_out, out_b, x1, 1.f, x2, NROWS, DM, DM);

  // conv module
  ln(0, x2, g_conv, b_conv, lnb);
  gemm2(0, lnb, wb_pw1, pw1_b, pw1raw, NROWS, 2 * DM, DM);
  glu_dwconv_kernel<<<dim3(1024), dim3(256), 0, stream>>>(pw1raw, dw_w, dw_b, dwout);
  ln(2, dwout, cng, cnb, convy);
  gemm(2, convy, wb_pw2, pw2_b, x2, 1.f, x3, NROWS, DM, DM);

  // final FFN
  ln(0, x3, g_ff, b_ff, lnb);
  gemm2(1, lnb, wb_ff1, ff_b1, hbig, NROWS, FF, DM);
  gemm(2, hbig, wb_ff2, ff_b2, x3, 1.f, x4, NROWS, DM, FF);

  // final LN -> f32 output
  ln(1, x4, g_fin, b_fin, d_out);

  (void)in_sizes; (void)n_in; (void)out_size; (void)ws_size;
}

// Round 6
// 407.072 us; speedup vs baseline: 1.1727x; 1.0288x over previous
//
#include <hip/hip_runtime.h>

typedef __attribute__((ext_vector_type(8))) short bf16x8;
typedef __attribute__((ext_vector_type(4))) short s16x4;
typedef __attribute__((ext_vector_type(4))) float f32x4;
typedef unsigned int u32;

#define SQ 1024
#define BB 8
#define DM 512
#define NH 8
#define HD 64
#define FF 2048
#define NROWS (SQ*BB)

static __device__ __forceinline__ float b2f(short s) {
  return __uint_as_float(((u32)(unsigned short)s) << 16);
}
static __device__ __forceinline__ short f2b(float f) {
  u32 u = __float_as_uint(f);
  return (short)((u + 0x7FFFu + ((u >> 16) & 1u)) >> 16);
}
// cheap round (non-RNE) for hot inner-loop LDS stores
static __device__ __forceinline__ short f2bt(float f) {
  return (short)((__float_as_uint(f) + 0x8000u) >> 16);
}
static __device__ __forceinline__ float sigm(float x) { return 1.f / (1.f + __expf(-x)); }

static __device__ __forceinline__ f32x4 mfma16(bf16x8 a, bf16x8 b, f32x4 c) {
  return __builtin_amdgcn_mfma_f32_16x16x32_bf16(a, b, c, 0, 0, 0);
}

static __device__ __forceinline__ void gload16(const void* g, void* l) {
  __builtin_amdgcn_global_load_lds(
      (const __attribute__((address_space(1))) void*)g,
      (__attribute__((address_space(3))) void*)l, 16, 0, 0);
}

// XOR swizzle for row-major [*][64 bf16] tiles (128 B row stride)
static __device__ __forceinline__ int swzp(int r, int byteoff) {
  return (r * 128 + byteoff) ^ ((r & 7) << 4);
}

#define WAIT_LGKM() do { \
    asm volatile("s_waitcnt lgkmcnt(0)" ::: "memory"); \
    __builtin_amdgcn_sched_barrier(0); } while (0)
#define WAIT_VM(n) do { \
    asm volatile("s_waitcnt vmcnt(" #n ")" ::: "memory"); \
    __builtin_amdgcn_sched_barrier(0); } while (0)

// ---------------- f32 -> bf16 convert (4-wide) ----------------
__global__ __launch_bounds__(256) void cvt_kernel(const float* __restrict__ in,
                                                  short* __restrict__ out, int n4) {
  int i = blockIdx.x * 256 + threadIdx.x;
  if (i >= n4) return;
  float4 v = ((const float4*)in)[i];
  s16x4 r = { f2b(v.x), f2b(v.y), f2b(v.z), f2b(v.w) };
  ((s16x4*)out)[i] = r;
}

// ---------------- row LayerNorm, D=512, one wave per row ----------------
template<int MODE>
__global__ __launch_bounds__(256) void ln_kernel(const float* __restrict__ x,
                                                 const float* __restrict__ gam,
                                                 const float* __restrict__ bet,
                                                 void* __restrict__ out) {
  int w = threadIdx.x >> 6, lane = threadIdx.x & 63;
  int row = (blockIdx.x << 2) + w;
  const float* xr = x + (size_t)row * DM + lane * 8;
  float4 a = *(const float4*)xr;
  float4 c = *(const float4*)(xr + 4);
  float v[8] = {a.x, a.y, a.z, a.w, c.x, c.y, c.z, c.w};
  float s = 0.f, q = 0.f;
#pragma unroll
  for (int e = 0; e < 8; ++e) { s += v[e]; q += v[e] * v[e]; }
#pragma unroll
  for (int m = 1; m < 64; m <<= 1) { s += __shfl_xor(s, m); q += __shfl_xor(q, m); }
  float mean = s * (1.f / DM);
  float rstd = rsqrtf(q * (1.f / DM) - mean * mean + 1e-5f);
  int col = lane * 8;
  if (MODE == 1) {
    float* o = (float*)out + (size_t)row * DM + col;
    float y[8];
#pragma unroll
    for (int e = 0; e < 8; ++e) y[e] = (v[e] - mean) * rstd * gam[col + e] + bet[col + e];
    *(float4*)o = make_float4(y[0], y[1], y[2], y[3]);
    *(float4*)(o + 4) = make_float4(y[4], y[5], y[6], y[7]);
  } else {
    bf16x8 r;
#pragma unroll
    for (int e = 0; e < 8; ++e) {
      float y = (v[e] - mean) * rstd * gam[col + e] + bet[col + e];
      if (MODE == 2) y = y * sigm(y);
      r[e] = f2b(y);
    }
    *(bf16x8*)((short*)out + (size_t)row * DM + col) = r;
  }
}

// ---------------- 256x256 GEMM, BK=32, ring-3, counted vmcnt, st_16x32 swizzle ----------------
template<int EPI>
__global__ __launch_bounds__(512, 2) void gemm256(const short* __restrict__ A,
                                                  const short* __restrict__ W,
                                                  const float* __restrict__ bias,
                                                  short* __restrict__ out,
                                                  int M, int N, int K) {
  __shared__ __align__(16) short lds[3 * 16384];
  int nb = N >> 8;
  int nwg = gridDim.x, bid = blockIdx.x;
  int bid2 = ((nwg & 7) == 0) ? ((bid & 7) * (nwg >> 3) + (bid >> 3)) : bid;
  int bm = bid2 / nb, bn = bid2 % nb;
  int m0 = bm << 8, n0 = bn << 8;
  int tid = threadIdx.x, w = tid >> 6, lane = tid & 63;
  int wm = w >> 2, wn = w & 3;
  int l15 = lane & 15, l4 = lane >> 4;
  int srow = lane >> 2;
  int slog = (lane & 3) ^ (((lane >> 5) & 1) << 1);
  int scol = slog << 3;

  const short* gsrc = (w < 4) ? (A + (size_t)(m0 + w * 64 + srow) * K + scol)
                              : (W + (size_t)(n0 + (w - 4) * 64 + srow) * K + scol);

  f32x4 acc[8][4];
#pragma unroll
  for (int i = 0; i < 8; ++i)
#pragma unroll
    for (int j = 0; j < 4; ++j) acc[i][j] = (f32x4){0.f, 0.f, 0.f, 0.f};

  auto stage2 = [&](int u, int kt, int q0) {
#pragma unroll
    for (int q = q0; q < q0 + 2; ++q)
      gload16(gsrc + (size_t)(q * 16) * K + kt,
              (char*)lds + u * 32768 + (w * 4 + q) * 1024);
  };
  auto rdA = [&](int u, int mf) -> bf16x8 {
    int ps = l4 ^ (((l15 >> 3) & 1) << 1);
    return *(const bf16x8*)((char*)lds + u * 32768 + (wm * 8 + mf) * 1024 + l15 * 64 + ps * 16);
  };
  auto rdB = [&](int u, int nf) -> bf16x8 {
    int ps = l4 ^ (((l15 >> 3) & 1) << 1);
    return *(const bf16x8*)((char*)lds + u * 32768 + 16384 + (wn * 4 + nf) * 1024 + l15 * 64 + ps * 16);
  };

  int nt = K >> 5;
  stage2(0, 0, 0); stage2(0, 0, 2);
  stage2(1, 32, 0); stage2(1, 32, 2);
  WAIT_VM(4);
  __builtin_amdgcn_s_barrier();

  int u = 0;
  for (int t = 0; t < nt; ++t) {
    int kt2 = (t + 2) << 5;
    int us = u + 2; if (us >= 3) us -= 3;
    bool st = (t + 2) < nt;
    bf16x8 afrag[4], bfrag[4];
#pragma unroll
    for (int nf = 0; nf < 4; ++nf) bfrag[nf] = rdB(u, nf);
#pragma unroll
    for (int mf = 0; mf < 4; ++mf) afrag[mf] = rdA(u, mf);
    if (st) stage2(us, kt2, 0);
    __builtin_amdgcn_s_barrier();
    WAIT_LGKM();
    __builtin_amdgcn_s_setprio(1);
#pragma unroll
    for (int mf = 0; mf < 4; ++mf)
#pragma unroll
      for (int nf = 0; nf < 4; ++nf)
        acc[mf][nf] = mfma16(afrag[mf], bfrag[nf], acc[mf][nf]);
    __builtin_amdgcn_s_setprio(0);
    __builtin_amdgcn_s_barrier();
#pragma unroll
    for (int mf = 0; mf < 4; ++mf) afrag[mf] = rdA(u, mf + 4);
    if (st) stage2(us, kt2, 2);
    __builtin_amdgcn_s_barrier();
    WAIT_LGKM();
    __builtin_amdgcn_s_setprio(1);
#pragma unroll
    for (int mf = 0; mf < 4; ++mf)
#pragma unroll
      for (int nf = 0; nf < 4; ++nf)
        acc[mf + 4][nf] = mfma16(afrag[mf], bfrag[nf], acc[mf + 4][nf]);
    __builtin_amdgcn_s_setprio(0);
    if (t < nt - 1) {
      if (st) { WAIT_VM(4); } else { WAIT_VM(0); }
    }
    __builtin_amdgcn_s_barrier();
    ++u; if (u >= 3) u -= 3;
  }

#pragma unroll
  for (int nf = 0; nf < 4; ++nf) {
    int col = n0 + wn * 64 + nf * 16 + l15;
    float bv = bias[col];
#pragma unroll
    for (int mf = 0; mf < 8; ++mf) {
#pragma unroll
      for (int r4 = 0; r4 < 4; ++r4) {
        int row = m0 + wm * 128 + mf * 16 + l4 * 4 + r4;
        float v = acc[mf][nf][r4] + bv;
        if (EPI == 1) v = v * sigm(v);
        out[(size_t)row * N + col] = f2b(v);
      }
    }
  }
}

// ---------------- 128x128 GEMM (2-phase), for N=512 grids ----------------
template<int EPI>
__global__ __launch_bounds__(256) void gemm_bt(const short* __restrict__ A,
                                               const short* __restrict__ W,
                                               const float* __restrict__ bias,
                                               const float* __restrict__ res,
                                               float alpha, void* __restrict__ out,
                                               int M, int N, int K) {
  __shared__ __align__(16) short ldsA[2 * 128 * 32];
  __shared__ __align__(16) short ldsB[2 * 128 * 32];
  int nb = N >> 7;
  int nwg = gridDim.x, bid = blockIdx.x;
  int bid2 = ((nwg & 7) == 0) ? ((bid & 7) * (nwg >> 3) + (bid >> 3)) : bid;
  int bm = bid2 / nb, bn = bid2 % nb;
  int m0 = bm << 7, n0 = bn << 7;
  int tid = threadIdx.x, w = tid >> 6, lane = tid & 63;
  int wm = w >> 1, wn = w & 1;
  f32x4 acc[4][4];
#pragma unroll
  for (int i = 0; i < 4; ++i)
#pragma unroll
    for (int j = 0; j < 4; ++j) acc[i][j] = (f32x4){0.f, 0.f, 0.f, 0.f};

  auto stage = [&](int bufsel, int kt) {
#pragma unroll
    for (int q = 0; q < 2; ++q) {
      int c = (q * 4 + w) * 64 + lane;
      int r = c >> 2, cc = c & 3;
      gload16(A + (size_t)(m0 + r) * K + kt + cc * 8,
              (char*)ldsA + bufsel * 8192 + (q * 4 + w) * 1024);
      gload16(W + (size_t)(n0 + r) * K + kt + cc * 8,
              (char*)ldsB + bufsel * 8192 + (q * 4 + w) * 1024);
    }
  };

  stage(0, 0);
  asm volatile("s_waitcnt vmcnt(0)" ::: "memory");
  __syncthreads();
  int cur = 0;
  for (int kt = 0; kt < K; kt += 32) {
    if (kt + 32 < K) stage(cur ^ 1, kt + 32);
    int rr = lane & 15, kk = (lane >> 4) << 3;
    bf16x8 af[4], bfr[4];
#pragma unroll
    for (int mt = 0; mt < 4; ++mt)
      af[mt] = *(const bf16x8*)(ldsA + cur * 4096 + (wm * 64 + mt * 16 + rr) * 32 + kk);
#pragma unroll
    for (int nt = 0; nt < 4; ++nt)
      bfr[nt] = *(const bf16x8*)(ldsB + cur * 4096 + (wn * 64 + nt * 16 + rr) * 32 + kk);
#pragma unroll
    for (int mt = 0; mt < 4; ++mt)
#pragma unroll
      for (int nt = 0; nt < 4; ++nt)
        acc[mt][nt] = mfma16(af[mt], bfr[nt], acc[mt][nt]);
    asm volatile("s_waitcnt vmcnt(0)" ::: "memory");
    __syncthreads();
    cur ^= 1;
  }

#pragma unroll
  for (int mt = 0; mt < 4; ++mt) {
#pragma unroll
    for (int nt = 0; nt < 4; ++nt) {
      int col = n0 + wn * 64 + nt * 16 + (lane & 15);
      float bv = (EPI == 3) ? 0.f : bias[col];
#pragma unroll
      for (int r4 = 0; r4 < 4; ++r4) {
        int row = m0 + wm * 64 + mt * 16 + (lane >> 4) * 4 + r4;
        size_t idx = (size_t)row * N + col;
        float v = acc[mt][nt][r4] + bv;
        if (EPI == 0 || EPI == 3) ((short*)out)[idx] = f2b(v);
        else if (EPI == 1) ((short*)out)[idx] = f2b(v * sigm(v));
        else ((float*)out)[idx] = res[idx] + alpha * v;
      }
    }
  }
}

// ---------------- V-transpose prep: qkv V section -> VT [bh][d][s] ----------------
__global__ __launch_bounds__(256) void prep_kernel(const short* __restrict__ qkv,
                                                   short* __restrict__ VTp) {
  __shared__ short ldsv[64 * 66];
  int tid = threadIdx.x;
  int st = blockIdx.x & 15, bh = blockIdx.x >> 4;
  int b = bh >> 3, h = bh & 7;
  int s0 = st << 6;
#pragma unroll
  for (int pass = 0; pass < 2; ++pass) {
    int r = pass * 32 + (tid >> 3), c = tid & 7;
    int s = s0 + r;
    bf16x8 v8 = *(const bf16x8*)(qkv + (size_t)(s * BB + b) * 1536 + 1024 + h * 64 + c * 8);
    *(bf16x8*)(ldsv + r * 66 + c * 8) = v8;
  }
  __syncthreads();
#pragma unroll
  for (int pass = 0; pass < 2; ++pass) {
    int d = pass * 32 + (tid >> 3), sc = tid & 7;
    bf16x8 o;
#pragma unroll
    for (int u = 0; u < 8; ++u) o[u] = ldsv[(sc * 8 + u) * 66 + d];
    *(bf16x8*)(VTp + ((size_t)bh * 64 + d) * SQ + s0 + sc * 8) = o;
  }
}

// ---------------- fused rel-pos flash attention (swapped softmax, lane-local state) ----------------
// grid = 8(it) * 64(bh) [XCD-local: all it of one bh on same XCD]; block 512
__global__ __launch_bounds__(512, 4) void attn_kernel(const short* __restrict__ qkv,
                                                      const short* __restrict__ VTp,
                                                      const short* __restrict__ posb,
                                                      const float* __restrict__ bias_u,
                                                      const float* __restrict__ bias_v,
                                                      short* __restrict__ obuf) {
  __shared__ __align__(16) char smem[62464];
  char* lds_k   = smem;            // [64][64] bf16 swizzled
  char* lds_vt  = smem + 8192;     // [64 d][64 j]
  char* lds_pos = smem + 16384;    // [192][64]
  char* lds_ew  = smem + 40960;    // 8 waves x 2688B; e band [16 q][84 n]; P overlaps

  int tid = threadIdx.x, w = tid >> 6, lane = tid & 63;
  int l15 = lane & 15, l4 = lane >> 4;
  int it = blockIdx.x >> 6, bh = blockIdx.x & 63;
  int b = bh >> 3, h = bh & 7;
  int i0 = it << 7;
  char* ewb = lds_ew + w * 2688;

  const size_t hoffB = (size_t)bh * SQ * 128;   // VTp bytes

  // Q fragments straight from qkv with inline bias add
  int fr = i0 + w * 16 + l15;
  const short* qrow = qkv + (size_t)(fr * BB + b) * 1536 + h * 64;
  bf16x8 qu_f[2], qv_f[2];
#pragma unroll
  for (int ks = 0; ks < 2; ++ks) {
    bf16x8 qraw = *(const bf16x8*)(qrow + ks * 32 + l4 * 8);
#pragma unroll
    for (int e = 0; e < 8; ++e) {
      float qf = b2f(qraw[e]);
      int d = h * 64 + ks * 32 + l4 * 8 + e;
      qu_f[ks][e] = f2b(qf + bias_u[d]);
      qv_f[ks][e] = f2b(qf + bias_v[d]);
    }
  }

  float m_run = -1e30f, l_run = 0.f;   // l_run is LANE-LOCAL partial
  f32x4 o_acc[4];
#pragma unroll
  for (int dt = 0; dt < 4; ++dt) o_acc[dt] = (f32x4){0.f, 0.f, 0.f, 0.f};

  int prbase = 112 - 16 * w;
  int lnq = lane >> 3, lnr = lane & 7;

  for (int j0 = 0; j0 < SQ; j0 += 64) {
    __syncthreads();
    // stage pos(3) first, then K, VT -- so vmcnt(1) covers pos+K
    int nmin2 = 896 - i0 + j0;
#pragma unroll
    for (int q = 0; q < 3; ++q) {
      int ch = w * 3 + q;
      int r = ch * 8 + lnq;
      int byt = (lnr * 16) ^ ((r & 7) << 4);
      gload16((const char*)posb + (size_t)(nmin2 + r) * 1024 + h * 128 + byt,
              lds_pos + ch * 1024);
    }
    {
      int r = w * 8 + lnq;
      int byt = (lnr * 16) ^ ((r & 7) << 4);
      gload16((const char*)qkv + (size_t)((j0 + r) * BB + b) * 3072 + 1024 + h * 128 + byt,
              lds_k + w * 1024);
      gload16((const char*)VTp + hoffB + (size_t)r * 2048 + (size_t)j0 * 2 + byt,
              lds_vt + w * 1024);
    }
    WAIT_VM(1);
    __builtin_amdgcn_s_barrier();

    // swapped QK^T: acs[kt] row = key-local (l4*4+r), col = q (l15)
    f32x4 acs[4];
    __builtin_amdgcn_s_setprio(1);
#pragma unroll
    for (int kt = 0; kt < 4; ++kt) {
      f32x4 z = (f32x4){0.f, 0.f, 0.f, 0.f};
      bf16x8 kb0 = *(const bf16x8*)(lds_k + swzp(kt * 16 + l15, l4 * 16));
      bf16x8 kb1 = *(const bf16x8*)(lds_k + swzp(kt * 16 + l15, 64 + l4 * 16));
      z = mfma16(kb0, qu_f[0], z);
      z = mfma16(kb1, qu_f[1], z);
      acs[kt] = z;
    }
    __builtin_amdgcn_s_setprio(0);
    // swapped e band -> per-wave LDS, vectorized b64 stores
#pragma unroll
    for (int pt = 0; pt < 5; ++pt) {
      f32x4 z = (f32x4){0.f, 0.f, 0.f, 0.f};
      int pr = prbase + pt * 16 + l15;
      bf16x8 pb0 = *(const bf16x8*)(lds_pos + swzp(pr, l4 * 16));
      bf16x8 pb1 = *(const bf16x8*)(lds_pos + swzp(pr, 64 + l4 * 16));
      __builtin_amdgcn_s_setprio(1);
      z = mfma16(pb0, qv_f[0], z);
      z = mfma16(pb1, qv_f[1], z);
      __builtin_amdgcn_s_setprio(0);
      s16x4 ek;
#pragma unroll
      for (int r = 0; r < 4; ++r) ek[r] = f2bt(z[r]);
      *(s16x4*)(ewb + (l15 * 84 + pt * 16 + l4 * 4) * 2) = ek;
    }
    WAIT_LGKM();

    // gather band + scores; per-lane local max
    float sv[4][4];
    float mt = -1e30f;
#pragma unroll
    for (int kt = 0; kt < 4; ++kt) {
#pragma unroll
      for (int r = 0; r < 4; ++r) {
        int n = 15 - l15 + kt * 16 + l4 * 4 + r;
        float ev = b2f(*(const short*)(ewb + (l15 * 84 + n) * 2));
        float sc = (acs[kt][r] + ev) * 0.125f;
        sv[kt][r] = sc;
        mt = fmaxf(mt, sc);
      }
    }
    // defer-max: cross-lane reduce only when the bound is violated
    if (!__all(mt <= m_run + 8.f)) {
      float mr = fmaxf(mt, __shfl_xor(mt, 16));
      mr = fmaxf(mr, __shfl_xor(mr, 32));
      float mn = fmaxf(m_run, mr);
      float fac = __expf(m_run - mn);
      m_run = mn;
      l_run *= fac;
      float fb[4];
#pragma unroll
      for (int r4 = 0; r4 < 4; ++r4) fb[r4] = __shfl(fac, (l4 << 2) + r4);
#pragma unroll
      for (int dt = 0; dt < 4; ++dt)
#pragma unroll
        for (int r4 = 0; r4 < 4; ++r4) o_acc[dt][r4] *= fb[r4];
    }
    float ls = 0.f;
    WAIT_LGKM();
#pragma unroll
    for (int kt = 0; kt < 4; ++kt) {
      s16x4 pk;
#pragma unroll
      for (int r = 0; r < 4; ++r) {
        float p = __expf(sv[kt][r] - m_run);
        ls += p;
        pk[r] = f2bt(p);
      }
      *(s16x4*)(ewb + l15 * 128 + ((kt * 32 + l4 * 8) ^ ((l15 & 7) << 4))) = pk;
    }
    l_run += ls;   // lane-local partial; reduced in epilogue
    __syncthreads();   // drains vm (VT landed) + lgkm (P visible)

    // PV
    bf16x8 pa[2];
#pragma unroll
    for (int ks = 0; ks < 2; ++ks)
      pa[ks] = *(const bf16x8*)(ewb + swzp(l15, ks * 64 + l4 * 16));
    __builtin_amdgcn_s_setprio(1);
#pragma unroll
    for (int dt = 0; dt < 4; ++dt) {
      bf16x8 vb0 = *(const bf16x8*)(lds_vt + swzp(dt * 16 + l15, l4 * 16));
      bf16x8 vb1 = *(const bf16x8*)(lds_vt + swzp(dt * 16 + l15, 64 + l4 * 16));
      o_acc[dt] = mfma16(pa[0], vb0, o_acc[dt]);
      o_acc[dt] = mfma16(pa[1], vb1, o_acc[dt]);
    }
    __builtin_amdgcn_s_setprio(0);
  }

  // epilogue: reduce lane-local l across the 4 l4-copies, then per-row broadcast
  float lt = l_run + __shfl_xor(l_run, 16);
  lt += __shfl_xor(lt, 32);
  float lb[4];
#pragma unroll
  for (int r4 = 0; r4 < 4; ++r4) lb[r4] = __shfl(lt, (l4 << 2) + r4);
#pragma unroll
  for (int dt = 0; dt < 4; ++dt) {
#pragma unroll
    for (int r4 = 0; r4 < 4; ++r4) {
      int i = i0 + w * 16 + l4 * 4 + r4;
      int d = dt * 16 + l15;
      float val = o_acc[dt][r4] / lb[r4];
      obuf[(size_t)(i * BB + b) * DM + h * 64 + d] = f2b(val);
    }
  }
}

// ---------------- GLU + depthwise conv (K=31, pad 15) ----------------
__global__ __launch_bounds__(256) void glu_dwconv_kernel(const short* __restrict__ pw1,
                                                         const float* __restrict__ dww,
                                                         const float* __restrict__ dwb,
                                                         float* __restrict__ out) {
  __shared__ short glu[38 * 512];
  int tid = threadIdx.x;
  int b = blockIdx.x & 7;
  int s0 = (blockIdx.x >> 3) << 3;
  for (int idx = tid; idx < 38 * 64; idx += 256) {
    int r = idx >> 6, c8 = idx & 63;
    int s = s0 - 15 + r;
    bf16x8 res;
    if (s >= 0 && s < SQ) {
      const short* row = pw1 + (size_t)(s * BB + b) * 1024;
      bf16x8 a8 = *(const bf16x8*)(row + c8 * 8);
      bf16x8 g8 = *(const bf16x8*)(row + 512 + c8 * 8);
#pragma unroll
      for (int e = 0; e < 8; ++e) res[e] = f2b(b2f(a8[e]) * sigm(b2f(g8[e])));
    } else {
#pragma unroll
      for (int e = 0; e < 8; ++e) res[e] = 0;
    }
    *(bf16x8*)(glu + r * 512 + c8 * 8) = res;
  }
  __syncthreads();
#pragma unroll
  for (int c = 0; c < 2; ++c) {
    int d = tid + c * 256;
    float wreg[31];
#pragma unroll
    for (int k = 0; k < 31; ++k) wreg[k] = dww[d * 31 + k];
    float bb = dwb[d];
    for (int ri = 0; ri < 8; ++ri) {
      float acc = bb;
#pragma unroll
      for (int k = 0; k < 31; ++k)
        acc += wreg[k] * b2f(glu[(ri + k) * 512 + d]);
      out[(size_t)((s0 + ri) * BB + b) * 512 + d] = acc;
    }
  }
}

// ---------------- host ----------------
extern "C" void kernel_launch(void* const* d_in, const int* in_sizes, int n_in,
                              void* d_out, int out_size, void* d_ws, size_t ws_size,
                              hipStream_t stream) {
  const float* src    = (const float*)d_in[0];
  const float* pose   = (const float*)d_in[1];
  const float* ffm_w1 = (const float*)d_in[2];
  const float* ffm_b1 = (const float*)d_in[3];
  const float* ffm_w2 = (const float*)d_in[4];
  const float* ffm_b2 = (const float*)d_in[5];
  const float* in_w   = (const float*)d_in[6];
  const float* in_b   = (const float*)d_in[7];
  const float* out_w  = (const float*)d_in[8];
  const float* out_b  = (const float*)d_in[9];
  const float* pos_w  = (const float*)d_in[10];
  const float* bias_u = (const float*)d_in[11];
  const float* bias_v = (const float*)d_in[12];
  const float* pw1_w  = (const float*)d_in[13];
  const float* pw1_b  = (const float*)d_in[14];
  const float* dw_w   = (const float*)d_in[15];
  const float* dw_b   = (const float*)d_in[16];
  const float* cng    = (const float*)d_in[17];
  const float* cnb    = (const float*)d_in[18];
  const float* pw2_w  = (const float*)d_in[19];
  const float* pw2_b  = (const float*)d_in[20];
  const float* ff_w1  = (const float*)d_in[21];
  const float* ff_b1  = (const float*)d_in[22];
  const float* ff_w2  = (const float*)d_in[23];
  const float* ff_b2  = (const float*)d_in[24];
  const float* g_ffm  = (const float*)d_in[25];
  const float* b_ffm  = (const float*)d_in[26];
  const float* g_mha  = (const float*)d_in[27];
  const float* b_mha  = (const float*)d_in[28];
  const float* g_conv = (const float*)d_in[29];
  const float* b_conv = (const float*)d_in[30];
  const float* g_ff   = (const float*)d_in[31];
  const float* b_ff   = (const float*)d_in[32];
  const float* g_fin  = (const float*)d_in[33];
  const float* b_fin  = (const float*)d_in[34];

  char* ws = (char*)d_ws;
  size_t off = 0;
  auto alloc = [&](size_t bytes) -> void* {
    void* p = ws + off;
    off += (bytes + 255) & ~(size_t)255;
    return p;
  };
  short* wb_ffm1 = (short*)alloc((size_t)FF * DM * 2);
  short* wb_ffm2 = (short*)alloc((size_t)DM * FF * 2);
  short* wb_in   = (short*)alloc((size_t)3 * DM * DM * 2);
  short* wb_out  = (short*)alloc((size_t)DM * DM * 2);
  short* wb_pos  = (short*)alloc((size_t)DM * DM * 2);
  short* wb_pw1  = (short*)alloc((size_t)2 * DM * DM * 2);
  short* wb_pw2  = (short*)alloc((size_t)DM * DM * 2);
  short* wb_ff1  = (short*)alloc((size_t)FF * DM * 2);
  short* wb_ff2  = (short*)alloc((size_t)DM * FF * 2);
  short* pos_src = (short*)alloc((size_t)2048 * DM * 2);
  short* pos_bf  = (short*)alloc((size_t)2048 * DM * 2);
  short* lnb     = (short*)alloc((size_t)NROWS * DM * 2);
  short* hbig    = (short*)alloc((size_t)NROWS * FF * 2);
  short* qkvb    = (short*)alloc((size_t)NROWS * 3 * DM * 2);
  short* obuf    = (short*)alloc((size_t)NROWS * DM * 2);
  float* x1      = (float*)alloc((size_t)NROWS * DM * 4);
  float* x2      = (float*)alloc((size_t)NROWS * DM * 4);
  float* dwout   = (float*)qkvb;
  short* pw1raw  = hbig;
  short* convy   = obuf;
  float* x3 = x1;
  float* x4 = x2;
  short* VTp = hbig + (size_t)3 * 4194304;   // V^T [bh][64][1024], 8MB; hbig free during MHA

  auto cvt = [&](const float* s, short* d, size_t n) {
    int n4 = (int)(n >> 2);
    cvt_kernel<<<dim3((n4 + 255) / 256), dim3(256), 0, stream>>>(s, d, n4);
  };
  cvt(ffm_w1, wb_ffm1, (size_t)FF * DM);
  cvt(ffm_w2, wb_ffm2, (size_t)DM * FF);
  cvt(in_w,   wb_in,   (size_t)3 * DM * DM);
  cvt(out_w,  wb_out,  (size_t)DM * DM);
  cvt(pos_w,  wb_pos,  (size_t)DM * DM);
  cvt(pw1_w,  wb_pw1,  (size_t)2 * DM * DM);
  cvt(pw2_w,  wb_pw2,  (size_t)DM * DM);
  cvt(ff_w1,  wb_ff1,  (size_t)FF * DM);
  cvt(ff_w2,  wb_ff2,  (size_t)DM * FF);
  cvt(pose,   pos_src, (size_t)2047 * DM);

  auto gemm = [&](int EPI, const short* A, const short* W, const float* bias,
                  const float* res, float alpha, void* out, int M, int N, int K) {
    dim3 g((M / 128) * (N / 128)), blk(256);
    switch (EPI) {
      case 0: gemm_bt<0><<<g, blk, 0, stream>>>(A, W, bias, res, alpha, out, M, N, K); break;
      case 1: gemm_bt<1><<<g, blk, 0, stream>>>(A, W, bias, res, alpha, out, M, N, K); break;
      case 2: gemm_bt<2><<<g, blk, 0, stream>>>(A, W, bias, res, alpha, out, M, N, K); break;
      default: gemm_bt<3><<<g, blk, 0, stream>>>(A, W, bias, res, alpha, out, M, N, K); break;
    }
  };
  auto gemm2 = [&](int EPI, const short* A, const short* W, const float* bias,
                   short* out, int M, int N, int K) {
    dim3 g((M / 256) * (N / 256)), blk(512);
    if (EPI == 0) gemm256<0><<<g, blk, 0, stream>>>(A, W, bias, out, M, N, K);
    else          gemm256<1><<<g, blk, 0, stream>>>(A, W, bias, out, M, N, K);
  };
  auto ln = [&](int MODE, const float* x, const float* g, const float* b, void* o) {
    dim3 grid(NROWS / 4), blk(256);
    if (MODE == 0)      ln_kernel<0><<<grid, blk, 0, stream>>>(x, g, b, o);
    else if (MODE == 1) ln_kernel<1><<<grid, blk, 0, stream>>>(x, g, b, o);
    else                ln_kernel<2><<<grid, blk, 0, stream>>>(x, g, b, o);
  };

  // positional projection
  gemm(3, pos_src, wb_pos, nullptr, nullptr, 0.f, pos_bf, 2048, DM, DM);

  // macaron FFN: x1 = src + 0.5*ffn(ln(src))
  ln(0, src, g_ffm, b_ffm, lnb);
  gemm2(1, lnb, wb_ffm1, ffm_b1, hbig, NROWS, FF, DM);
  gemm(2, hbig, wb_ffm2, ffm_b2, src, 0.5f, x1, NROWS, DM, FF);

  // MHA: x2 = x1 + out_proj(attn(ln(x1)))
  ln(0, x1, g_mha, b_mha, lnb);
  gemm2(0, lnb, wb_in, in_b, qkvb, NROWS, 3 * DM, DM);
  prep_kernel<<<dim3(1024), dim3(256), 0, stream>>>(qkvb, VTp);
  attn_kernel<<<dim3(512), dim3(512), 0, stream>>>(qkvb, VTp, pos_bf, bias_u, bias_v, obuf);
  gemm(2, obuf, wb_out, out_b, x1, 1.f, x2, NROWS, DM, DM);

  // conv module
  ln(0, x2, g_conv, b_conv, lnb);
  gemm2(0, lnb, wb_pw1, pw1_b, pw1raw, NROWS, 2 * DM, DM);
  glu_dwconv_kernel<<<dim3(1024), dim3(256), 0, stream>>>(pw1raw, dw_w, dw_b, dwout);
  ln(2, dwout, cng, cnb, convy);
  gemm(2, convy, wb_pw2, pw2_b, x2, 1.f, x3, NROWS, DM, DM);

  // final FFN
  ln(0, x3, g_ff, b_ff, lnb);
  gemm2(1, lnb, wb_ff1, ff_b1, hbig, NROWS, FF, DM);
  gemm(2, hbig, wb_ff2, ff_b2, x3, 1.f, x4, NROWS, DM, FF);

  // final LN -> f32 output
  ln(1, x4, g_fin, b_fin, d_out);

  (void)in_sizes; (void)n_in; (void)out_size; (void)ws_size;
}

// Round 7
// 406.712 us; speedup vs baseline: 1.1737x; 1.0009x over previous
//
#include <hip/hip_runtime.h>

typedef __attribute__((ext_vector_type(8))) short bf16x8;
typedef __attribute__((ext_vector_type(4))) short s16x4;
typedef __attribute__((ext_vector_type(4))) float f32x4;
typedef unsigned int u32;

#define SQ 1024
#define BB 8
#define DM 512
#define NH 8
#define HD 64
#define FF 2048
#define NROWS (SQ*BB)

static __device__ __forceinline__ float b2f(short s) {
  return __uint_as_float(((u32)(unsigned short)s) << 16);
}
static __device__ __forceinline__ short f2b(float f) {
  u32 u = __float_as_uint(f);
  return (short)((u + 0x7FFFu + ((u >> 16) & 1u)) >> 16);
}
// cheap round (non-RNE) for hot inner-loop LDS stores
static __device__ __forceinline__ short f2bt(float f) {
  return (short)((__float_as_uint(f) + 0x8000u) >> 16);
}
static __device__ __forceinline__ float sigm(float x) { return 1.f / (1.f + __expf(-x)); }

static __device__ __forceinline__ f32x4 mfma16(bf16x8 a, bf16x8 b, f32x4 c) {
  return __builtin_amdgcn_mfma_f32_16x16x32_bf16(a, b, c, 0, 0, 0);
}

static __device__ __forceinline__ void gload16(const void* g, void* l) {
  __builtin_amdgcn_global_load_lds(
      (const __attribute__((address_space(1))) void*)g,
      (__attribute__((address_space(3))) void*)l, 16, 0, 0);
}

// XOR swizzle for row-major [*][64 bf16] tiles (128 B row stride)
static __device__ __forceinline__ int swzp(int r, int byteoff) {
  return (r * 128 + byteoff) ^ ((r & 7) << 4);
}

#define WAIT_LGKM() do { \
    asm volatile("s_waitcnt lgkmcnt(0)" ::: "memory"); \
    __builtin_amdgcn_sched_barrier(0); } while (0)
#define WAIT_VM(n) do { \
    asm volatile("s_waitcnt vmcnt(" #n ")" ::: "memory"); \
    __builtin_amdgcn_sched_barrier(0); } while (0)

// ---------------- f32 -> bf16 convert (4-wide) ----------------
__global__ __launch_bounds__(256) void cvt_kernel(const float* __restrict__ in,
                                                  short* __restrict__ out, int n4) {
  int i = blockIdx.x * 256 + threadIdx.x;
  if (i >= n4) return;
  float4 v = ((const float4*)in)[i];
  s16x4 r = { f2b(v.x), f2b(v.y), f2b(v.z), f2b(v.w) };
  ((s16x4*)out)[i] = r;
}

// ---------------- row LayerNorm, D=512, one wave per row ----------------
template<int MODE>
__global__ __launch_bounds__(256) void ln_kernel(const float* __restrict__ x,
                                                 const float* __restrict__ gam,
                                                 const float* __restrict__ bet,
                                                 void* __restrict__ out) {
  int w = threadIdx.x >> 6, lane = threadIdx.x & 63;
  int row = (blockIdx.x << 2) + w;
  const float* xr = x + (size_t)row * DM + lane * 8;
  float4 a = *(const float4*)xr;
  float4 c = *(const float4*)(xr + 4);
  float v[8] = {a.x, a.y, a.z, a.w, c.x, c.y, c.z, c.w};
  float s = 0.f, q = 0.f;
#pragma unroll
  for (int e = 0; e < 8; ++e) { s += v[e]; q += v[e] * v[e]; }
#pragma unroll
  for (int m = 1; m < 64; m <<= 1) { s += __shfl_xor(s, m); q += __shfl_xor(q, m); }
  float mean = s * (1.f / DM);
  float rstd = rsqrtf(q * (1.f / DM) - mean * mean + 1e-5f);
  int col = lane * 8;
  if (MODE == 1) {
    float* o = (float*)out + (size_t)row * DM + col;
    float y[8];
#pragma unroll
    for (int e = 0; e < 8; ++e) y[e] = (v[e] - mean) * rstd * gam[col + e] + bet[col + e];
    *(float4*)o = make_float4(y[0], y[1], y[2], y[3]);
    *(float4*)(o + 4) = make_float4(y[4], y[5], y[6], y[7]);
  } else {
    bf16x8 r;
#pragma unroll
    for (int e = 0; e < 8; ++e) {
      float y = (v[e] - mean) * rstd * gam[col + e] + bet[col + e];
      if (MODE == 2) y = y * sigm(y);
      r[e] = f2b(y);
    }
    *(bf16x8*)((short*)out + (size_t)row * DM + col) = r;
  }
}

// ---------------- 256x256 GEMM, BK=32, ring-3, counted vmcnt, st_16x32 swizzle ----------------
template<int EPI>
__global__ __launch_bounds__(512, 2) void gemm256(const short* __restrict__ A,
                                                  const short* __restrict__ W,
                                                  const float* __restrict__ bias,
                                                  short* __restrict__ out,
                                                  int M, int N, int K) {
  __shared__ __align__(16) short lds[3 * 16384];
  int nb = N >> 8;
  int nwg = gridDim.x, bid = blockIdx.x;
  int bid2 = ((nwg & 7) == 0) ? ((bid & 7) * (nwg >> 3) + (bid >> 3)) : bid;
  int bm = bid2 / nb, bn = bid2 % nb;
  int m0 = bm << 8, n0 = bn << 8;
  int tid = threadIdx.x, w = tid >> 6, lane = tid & 63;
  int wm = w >> 2, wn = w & 3;
  int l15 = lane & 15, l4 = lane >> 4;
  int srow = lane >> 2;
  int slog = (lane & 3) ^ (((lane >> 5) & 1) << 1);
  int scol = slog << 3;

  const short* gsrc = (w < 4) ? (A + (size_t)(m0 + w * 64 + srow) * K + scol)
                              : (W + (size_t)(n0 + (w - 4) * 64 + srow) * K + scol);

  f32x4 acc[8][4];
#pragma unroll
  for (int i = 0; i < 8; ++i)
#pragma unroll
    for (int j = 0; j < 4; ++j) acc[i][j] = (f32x4){0.f, 0.f, 0.f, 0.f};

  auto stage2 = [&](int u, int kt, int q0) {
#pragma unroll
    for (int q = q0; q < q0 + 2; ++q)
      gload16(gsrc + (size_t)(q * 16) * K + kt,
              (char*)lds + u * 32768 + (w * 4 + q) * 1024);
  };
  auto rdA = [&](int u, int mf) -> bf16x8 {
    int ps = l4 ^ (((l15 >> 3) & 1) << 1);
    return *(const bf16x8*)((char*)lds + u * 32768 + (wm * 8 + mf) * 1024 + l15 * 64 + ps * 16);
  };
  auto rdB = [&](int u, int nf) -> bf16x8 {
    int ps = l4 ^ (((l15 >> 3) & 1) << 1);
    return *(const bf16x8*)((char*)lds + u * 32768 + 16384 + (wn * 4 + nf) * 1024 + l15 * 64 + ps * 16);
  };

  int nt = K >> 5;
  stage2(0, 0, 0); stage2(0, 0, 2);
  stage2(1, 32, 0); stage2(1, 32, 2);
  WAIT_VM(4);
  __builtin_amdgcn_s_barrier();

  int u = 0;
  for (int t = 0; t < nt; ++t) {
    int kt2 = (t + 2) << 5;
    int us = u + 2; if (us >= 3) us -= 3;
    bool st = (t + 2) < nt;
    bf16x8 afrag[4], bfrag[4];
#pragma unroll
    for (int nf = 0; nf < 4; ++nf) bfrag[nf] = rdB(u, nf);
#pragma unroll
    for (int mf = 0; mf < 4; ++mf) afrag[mf] = rdA(u, mf);
    if (st) stage2(us, kt2, 0);
    __builtin_amdgcn_s_barrier();
    WAIT_LGKM();
    __builtin_amdgcn_s_setprio(1);
#pragma unroll
    for (int mf = 0; mf < 4; ++mf)
#pragma unroll
      for (int nf = 0; nf < 4; ++nf)
        acc[mf][nf] = mfma16(afrag[mf], bfrag[nf], acc[mf][nf]);
    __builtin_amdgcn_s_setprio(0);
    __builtin_amdgcn_s_barrier();
#pragma unroll
    for (int mf = 0; mf < 4; ++mf) afrag[mf] = rdA(u, mf + 4);
    if (st) stage2(us, kt2, 2);
    __builtin_amdgcn_s_barrier();
    WAIT_LGKM();
    __builtin_amdgcn_s_setprio(1);
#pragma unroll
    for (int mf = 0; mf < 4; ++mf)
#pragma unroll
      for (int nf = 0; nf < 4; ++nf)
        acc[mf + 4][nf] = mfma16(afrag[mf], bfrag[nf], acc[mf + 4][nf]);
    __builtin_amdgcn_s_setprio(0);
    if (t < nt - 1) {
      if (st) { WAIT_VM(4); } else { WAIT_VM(0); }
    }
    __builtin_amdgcn_s_barrier();
    ++u; if (u >= 3) u -= 3;
  }

#pragma unroll
  for (int nf = 0; nf < 4; ++nf) {
    int col = n0 + wn * 64 + nf * 16 + l15;
    float bv = bias[col];
#pragma unroll
    for (int mf = 0; mf < 8; ++mf) {
#pragma unroll
      for (int r4 = 0; r4 < 4; ++r4) {
        int row = m0 + wm * 128 + mf * 16 + l4 * 4 + r4;
        float v = acc[mf][nf][r4] + bv;
        if (EPI == 1) v = v * sigm(v);
        out[(size_t)row * N + col] = f2b(v);
      }
    }
  }
}

// ---------------- 128x128 GEMM (2-phase), for N=512 grids ----------------
template<int EPI>
__global__ __launch_bounds__(256) void gemm_bt(const short* __restrict__ A,
                                               const short* __restrict__ W,
                                               const float* __restrict__ bias,
                                               const float* __restrict__ res,
                                               float alpha, void* __restrict__ out,
                                               int M, int N, int K) {
  __shared__ __align__(16) short ldsA[2 * 128 * 32];
  __shared__ __align__(16) short ldsB[2 * 128 * 32];
  int nb = N >> 7;
  int nwg = gridDim.x, bid = blockIdx.x;
  int bid2 = ((nwg & 7) == 0) ? ((bid & 7) * (nwg >> 3) + (bid >> 3)) : bid;
  int bm = bid2 / nb, bn = bid2 % nb;
  int m0 = bm << 7, n0 = bn << 7;
  int tid = threadIdx.x, w = tid >> 6, lane = tid & 63;
  int wm = w >> 1, wn = w & 1;
  f32x4 acc[4][4];
#pragma unroll
  for (int i = 0; i < 4; ++i)
#pragma unroll
    for (int j = 0; j < 4; ++j) acc[i][j] = (f32x4){0.f, 0.f, 0.f, 0.f};

  auto stage = [&](int bufsel, int kt) {
#pragma unroll
    for (int q = 0; q < 2; ++q) {
      int c = (q * 4 + w) * 64 + lane;
      int r = c >> 2, cc = c & 3;
      gload16(A + (size_t)(m0 + r) * K + kt + cc * 8,
              (char*)ldsA + bufsel * 8192 + (q * 4 + w) * 1024);
      gload16(W + (size_t)(n0 + r) * K + kt + cc * 8,
              (char*)ldsB + bufsel * 8192 + (q * 4 + w) * 1024);
    }
  };

  stage(0, 0);
  asm volatile("s_waitcnt vmcnt(0)" ::: "memory");
  __syncthreads();
  int cur = 0;
  for (int kt = 0; kt < K; kt += 32) {
    if (kt + 32 < K) stage(cur ^ 1, kt + 32);
    int rr = lane & 15, kk = (lane >> 4) << 3;
    bf16x8 af[4], bfr[4];
#pragma unroll
    for (int mt = 0; mt < 4; ++mt)
      af[mt] = *(const bf16x8*)(ldsA + cur * 4096 + (wm * 64 + mt * 16 + rr) * 32 + kk);
#pragma unroll
    for (int nt = 0; nt < 4; ++nt)
      bfr[nt] = *(const bf16x8*)(ldsB + cur * 4096 + (wn * 64 + nt * 16 + rr) * 32 + kk);
#pragma unroll
    for (int mt = 0; mt < 4; ++mt)
#pragma unroll
      for (int nt = 0; nt < 4; ++nt)
        acc[mt][nt] = mfma16(af[mt], bfr[nt], acc[mt][nt]);
    asm volatile("s_waitcnt vmcnt(0)" ::: "memory");
    __syncthreads();
    cur ^= 1;
  }

#pragma unroll
  for (int mt = 0; mt < 4; ++mt) {
#pragma unroll
    for (int nt = 0; nt < 4; ++nt) {
      int col = n0 + wn * 64 + nt * 16 + (lane & 15);
      float bv = (EPI == 3) ? 0.f : bias[col];
#pragma unroll
      for (int r4 = 0; r4 < 4; ++r4) {
        int row = m0 + wm * 64 + mt * 16 + (lane >> 4) * 4 + r4;
        size_t idx = (size_t)row * N + col;
        float v = acc[mt][nt][r4] + bv;
        if (EPI == 0 || EPI == 3) ((short*)out)[idx] = f2b(v);
        else if (EPI == 1) ((short*)out)[idx] = f2b(v * sigm(v));
        else ((float*)out)[idx] = res[idx] + alpha * v;
      }
    }
  }
}

// ---------------- V-transpose prep: qkv V section -> VT [bh][d][s] ----------------
__global__ __launch_bounds__(256) void prep_kernel(const short* __restrict__ qkv,
                                                   short* __restrict__ VTp) {
  __shared__ short ldsv[64 * 66];
  int tid = threadIdx.x;
  int st = blockIdx.x & 15, bh = blockIdx.x >> 4;
  int b = bh >> 3, h = bh & 7;
  int s0 = st << 6;
#pragma unroll
  for (int pass = 0; pass < 2; ++pass) {
    int r = pass * 32 + (tid >> 3), c = tid & 7;
    int s = s0 + r;
    bf16x8 v8 = *(const bf16x8*)(qkv + (size_t)(s * BB + b) * 1536 + 1024 + h * 64 + c * 8);
    *(bf16x8*)(ldsv + r * 66 + c * 8) = v8;
  }
  __syncthreads();
#pragma unroll
  for (int pass = 0; pass < 2; ++pass) {
    int d = pass * 32 + (tid >> 3), sc = tid & 7;
    bf16x8 o;
#pragma unroll
    for (int u = 0; u < 8; ++u) o[u] = ldsv[(sc * 8 + u) * 66 + d];
    *(bf16x8*)(VTp + ((size_t)bh * 64 + d) * SQ + s0 + sc * 8) = o;
  }
}

// ---------------- fused rel-pos flash attention ----------------
// Pipelined: K dbuf + circular 4-seg pos buffer + VT staged at top; all
// staging latency hidden under compute (counted vmcnt). 2 barriers/iter.
// grid = 8(it) * 64(bh) [XCD-local]; block 512 (8 waves)
__global__ __launch_bounds__(512, 4) void attn_kernel(const short* __restrict__ qkv,
                                                      const short* __restrict__ VTp,
                                                      const short* __restrict__ posb,
                                                      const float* __restrict__ bias_u,
                                                      const float* __restrict__ bias_v,
                                                      short* __restrict__ obuf) {
  __shared__ __align__(16) char smem[78848];
  char* lds_k   = smem;            // 2 x [64][64] bf16 swizzled (16KB)
  char* lds_vt  = smem + 16384;    // [64 d][64 j] (8KB)
  char* lds_pos = smem + 24576;    // 4 segs x [64][64] (32KB), circular
  char* lds_ew  = smem + 57344;    // 8 waves x 2688B; e band [16 q][84 n]; P overlaps

  int tid = threadIdx.x, w = tid >> 6, lane = tid & 63;
  int l15 = lane & 15, l4 = lane >> 4;
  int it = blockIdx.x >> 6, bh = blockIdx.x & 63;
  int b = bh >> 3, h = bh & 7;
  int i0 = it << 7;
  char* ewb = lds_ew + w * 2688;

  const size_t hoffB = (size_t)bh * SQ * 128;   // VTp bytes

  // Q fragments straight from qkv with inline bias add
  int fr = i0 + w * 16 + l15;
  const short* qrow = qkv + (size_t)(fr * BB + b) * 1536 + h * 64;
  bf16x8 qu_f[2], qv_f[2];
#pragma unroll
  for (int ks = 0; ks < 2; ++ks) {
    bf16x8 qraw = *(const bf16x8*)(qrow + ks * 32 + l4 * 8);
#pragma unroll
    for (int e = 0; e < 8; ++e) {
      float qf = b2f(qraw[e]);
      int d = h * 64 + ks * 32 + l4 * 8 + e;
      qu_f[ks][e] = f2b(qf + bias_u[d]);
      qv_f[ks][e] = f2b(qf + bias_v[d]);
    }
  }

  // exp2-domain softmax: scores pre-scaled by 0.125*log2(e)
  const float SC2 = 0.125f * 1.44269504f;
  float m_run = -1e30f, l_run = 0.f;   // lane-local partial l
  f32x4 o_acc[4];
#pragma unroll
  for (int dt = 0; dt < 4; ++dt) o_acc[dt] = (f32x4){0.f, 0.f, 0.f, 0.f};

  int prbase = 112 - 16 * w;
  int lnq = lane >> 3, lnr = lane & 7;
  int r8 = w * 8 + lnq;                       // staging row 0..63
  int byt = (lnr * 16) ^ ((r8 & 7) << 4);     // pre-swizzled source offset
  int nbase = 896 - i0;                       // pos global row base (t=0, pr=0)

  auto stageK = [&](int t1) {
    int j = (t1 << 6) + r8;
    gload16((const char*)qkv + (size_t)(j * BB + b) * 3072 + 1024 + h * 128 + byt,
            lds_k + (t1 & 1) * 8192 + w * 1024);
  };
  auto stageVT = [&](int t1) {
    gload16((const char*)VTp + hoffB + (size_t)r8 * 2048 + (size_t)(t1 << 7) + byt,
            lds_vt + w * 1024);
  };
  auto stagePosSeg = [&](int gbase, int pseg) {
    gload16((const char*)posb + (size_t)(gbase + r8) * 1024 + h * 128 + byt,
            lds_pos + pseg * 8192 + w * 1024);
  };

  // prologue: pos segs 0..2 (rows pr 0..191 of t=0) + K(0)
  stagePosSeg(nbase, 0);
  stagePosSeg(nbase + 64, 1);
  stagePosSeg(nbase + 128, 2);
  stageK(0);
  WAIT_VM(0);

  for (int t = 0; t < 16; ++t) {
    int cur = t & 1;
    __builtin_amdgcn_s_barrier();        // barrier1: K/pos(t) staged; PV(t-1) done
    stageVT(t);

    // swapped QK^T: acs[kt] row = key-local (l4*4+r), col = q (l15)
    f32x4 acs[4];
    __builtin_amdgcn_s_setprio(1);
#pragma unroll
    for (int kt = 0; kt < 4; ++kt) {
      f32x4 z = (f32x4){0.f, 0.f, 0.f, 0.f};
      bf16x8 kb0 = *(const bf16x8*)(lds_k + cur * 8192 + swzp(kt * 16 + l15, l4 * 16));
      bf16x8 kb1 = *(const bf16x8*)(lds_k + cur * 8192 + swzp(kt * 16 + l15, 64 + l4 * 16));
      z = mfma16(kb0, qu_f[0], z);
      z = mfma16(kb1, qu_f[1], z);
      acs[kt] = z;
    }
    __builtin_amdgcn_s_setprio(0);
    // swapped e band from circular pos buffer
#pragma unroll
    for (int pt = 0; pt < 5; ++pt) {
      f32x4 z = (f32x4){0.f, 0.f, 0.f, 0.f};
      int pr = prbase + pt * 16 + l15;
      char* pbase = lds_pos + (((t + (pr >> 6)) & 3) * 8192);
      bf16x8 pb0 = *(const bf16x8*)(pbase + swzp(pr & 63, l4 * 16));
      bf16x8 pb1 = *(const bf16x8*)(pbase + swzp(pr & 63, 64 + l4 * 16));
      __builtin_amdgcn_s_setprio(1);
      z = mfma16(pb0, qv_f[0], z);
      z = mfma16(pb1, qv_f[1], z);
      __builtin_amdgcn_s_setprio(0);
      s16x4 ek;
#pragma unroll
      for (int r = 0; r < 4; ++r) ek[r] = f2bt(z[r]);
      *(s16x4*)(ewb + (l15 * 84 + pt * 16 + l4 * 4) * 2) = ek;
    }

    // prefetch next tile's K + new pos segment (targets not read this iter)
    bool pf = (t + 1) < 16;
    if (pf) {
      stageK(t + 1);
      stagePosSeg(nbase + (t << 6) + 192, (t + 3) & 3);
    }

    WAIT_LGKM();   // e stores visible (own wave)

    // gather band + scores; per-lane local max (exp2 domain)
    float sv[4][4];
    float mt = -1e30f;
#pragma unroll
    for (int kt = 0; kt < 4; ++kt) {
#pragma unroll
      for (int r = 0; r < 4; ++r) {
        int n = 15 - l15 + kt * 16 + l4 * 4 + r;
        float ev = b2f(*(const short*)(ewb + (l15 * 84 + n) * 2));
        float sc = (acs[kt][r] + ev) * SC2;
        sv[kt][r] = sc;
        mt = fmaxf(mt, sc);
      }
    }
    // defer-max: cross-lane reduce only when bound violated (8 in e-domain)
    if (!__all(mt <= m_run + 11.5415604f)) {
      float mr = fmaxf(mt, __shfl_xor(mt, 16));
      mr = fmaxf(mr, __shfl_xor(mr, 32));
      float mn = fmaxf(m_run, mr);
      float fac = exp2f(m_run - mn);
      m_run = mn;
      l_run *= fac;
      float fb[4];
#pragma unroll
      for (int r4 = 0; r4 < 4; ++r4) fb[r4] = __shfl(fac, (l4 << 2) + r4);
#pragma unroll
      for (int dt = 0; dt < 4; ++dt)
#pragma unroll
        for (int r4 = 0; r4 < 4; ++r4) o_acc[dt][r4] *= fb[r4];
    }
    float ls = 0.f;
#pragma unroll
    for (int kt = 0; kt < 4; ++kt) {
      s16x4 pk;
#pragma unroll
      for (int r = 0; r < 4; ++r) {
        float p = exp2f(sv[kt][r] - m_run);
        ls += p;
        pk[r] = f2bt(p);
      }
      *(s16x4*)(ewb + l15 * 128 + ((kt * 32 + l4 * 8) ^ ((l15 & 7) << 4))) = pk;
    }
    l_run += ls;

    // drain VT (leave K/pos prefetch in flight), make P visible, sync for PV
    if (pf) { WAIT_VM(2); } else { WAIT_VM(0); }
    WAIT_LGKM();
    __builtin_amdgcn_s_barrier();        // barrier2: all VT writes landed

    // PV
    bf16x8 pa[2];
#pragma unroll
    for (int ks = 0; ks < 2; ++ks)
      pa[ks] = *(const bf16x8*)(ewb + swzp(l15, ks * 64 + l4 * 16));
    __builtin_amdgcn_s_setprio(1);
#pragma unroll
    for (int dt = 0; dt < 4; ++dt) {
      bf16x8 vb0 = *(const bf16x8*)(lds_vt + swzp(dt * 16 + l15, l4 * 16));
      bf16x8 vb1 = *(const bf16x8*)(lds_vt + swzp(dt * 16 + l15, 64 + l4 * 16));
      o_acc[dt] = mfma16(pa[0], vb0, o_acc[dt]);
      o_acc[dt] = mfma16(pa[1], vb1, o_acc[dt]);
    }
    __builtin_amdgcn_s_setprio(0);

    WAIT_VM(0);    // K/pos prefetch landed before next barrier1
  }

  // epilogue: reduce lane-local l across the 4 l4-copies, then per-row broadcast
  float lt = l_run + __shfl_xor(l_run, 16);
  lt += __shfl_xor(lt, 32);
  float lb[4];
#pragma unroll
  for (int r4 = 0; r4 < 4; ++r4) lb[r4] = __shfl(lt, (l4 << 2) + r4);
#pragma unroll
  for (int dt = 0; dt < 4; ++dt) {
#pragma unroll
    for (int r4 = 0; r4 < 4; ++r4) {
      int i = i0 + w * 16 + l4 * 4 + r4;
      int d = dt * 16 + l15;
      float val = o_acc[dt][r4] / lb[r4];
      obuf[(size_t)(i * BB + b) * DM + h * 64 + d] = f2b(val);
    }
  }
}

// ---------------- GLU + depthwise conv (K=31, pad 15) ----------------
__global__ __launch_bounds__(256) void glu_dwconv_kernel(const short* __restrict__ pw1,
                                                         const float* __restrict__ dww,
                                                         const float* __restrict__ dwb,
                                                         float* __restrict__ out) {
  __shared__ short glu[38 * 512];
  int tid = threadIdx.x;
  int b = blockIdx.x & 7;
  int s0 = (blockIdx.x >> 3) << 3;
  for (int idx = tid; idx < 38 * 64; idx += 256) {
    int r = idx >> 6, c8 = idx & 63;
    int s = s0 - 15 + r;
    bf16x8 res;
    if (s >= 0 && s < SQ) {
      const short* row = pw1 + (size_t)(s * BB + b) * 1024;
      bf16x8 a8 = *(const bf16x8*)(row + c8 * 8);
      bf16x8 g8 = *(const bf16x8*)(row + 512 + c8 * 8);
#pragma unroll
      for (int e = 0; e < 8; ++e) res[e] = f2b(b2f(a8[e]) * sigm(b2f(g8[e])));
    } else {
#pragma unroll
      for (int e = 0; e < 8; ++e) res[e] = 0;
    }
    *(bf16x8*)(glu + r * 512 + c8 * 8) = res;
  }
  __syncthreads();
#pragma unroll
  for (int c = 0; c < 2; ++c) {
    int d = tid + c * 256;
    float wreg[31];
#pragma unroll
    for (int k = 0; k < 31; ++k) wreg[k] = dww[d * 31 + k];
    float bb = dwb[d];
    for (int ri = 0; ri < 8; ++ri) {
      float acc = bb;
#pragma unroll
      for (int k = 0; k < 31; ++k)
        acc += wreg[k] * b2f(glu[(ri + k) * 512 + d]);
      out[(size_t)((s0 + ri) * BB + b) * 512 + d] = acc;
    }
  }
}

// ---------------- host ----------------
extern "C" void kernel_launch(void* const* d_in, const int* in_sizes, int n_in,
                              void* d_out, int out_size, void* d_ws, size_t ws_size,
                              hipStream_t stream) {
  const float* src    = (const float*)d_in[0];
  const float* pose   = (const float*)d_in[1];
  const float* ffm_w1 = (const float*)d_in[2];
  const float* ffm_b1 = (const float*)d_in[3];
  const float* ffm_w2 = (const float*)d_in[4];
  const float* ffm_b2 = (const float*)d_in[5];
  const float* in_w   = (const float*)d_in[6];
  const float* in_b   = (const float*)d_in[7];
  const float* out_w  = (const float*)d_in[8];
  const float* out_b  = (const float*)d_in[9];
  const float* pos_w  = (const float*)d_in[10];
  const float* bias_u = (const float*)d_in[11];
  const float* bias_v = (const float*)d_in[12];
  const float* pw1_w  = (const float*)d_in[13];
  const float* pw1_b  = (const float*)d_in[14];
  const float* dw_w   = (const float*)d_in[15];
  const float* dw_b   = (const float*)d_in[16];
  const float* cng    = (const float*)d_in[17];
  const float* cnb    = (const float*)d_in[18];
  const float* pw2_w  = (const float*)d_in[19];
  const float* pw2_b  = (const float*)d_in[20];
  const float* ff_w1  = (const float*)d_in[21];
  const float* ff_b1  = (const float*)d_in[22];
  const float* ff_w2  = (const float*)d_in[23];
  const float* ff_b2  = (const float*)d_in[24];
  const float* g_ffm  = (const float*)d_in[25];
  const float* b_ffm  = (const float*)d_in[26];
  const float* g_mha  = (const float*)d_in[27];
  const float* b_mha  = (const float*)d_in[28];
  const float* g_conv = (const float*)d_in[29];
  const float* b_conv = (const float*)d_in[30];
  const float* g_ff   = (const float*)d_in[31];
  const float* b_ff   = (const float*)d_in[32];
  const float* g_fin  = (const float*)d_in[33];
  const float* b_fin  = (const float*)d_in[34];

  char* ws = (char*)d_ws;
  size_t off = 0;
  auto alloc = [&](size_t bytes) -> void* {
    void* p = ws + off;
    off += (bytes + 255) & ~(size_t)255;
    return p;
  };
  short* wb_ffm1 = (short*)alloc((size_t)FF * DM * 2);
  short* wb_ffm2 = (short*)alloc((size_t)DM * FF * 2);
  short* wb_in   = (short*)alloc((size_t)3 * DM * DM * 2);
  short* wb_out  = (short*)alloc((size_t)DM * DM * 2);
  short* wb_pos  = (short*)alloc((size_t)DM * DM * 2);
  short* wb_pw1  = (short*)alloc((size_t)2 * DM * DM * 2);
  short* wb_pw2  = (short*)alloc((size_t)DM * DM * 2);
  short* wb_ff1  = (short*)alloc((size_t)FF * DM * 2);
  short* wb_ff2  = (short*)alloc((size_t)DM * FF * 2);
  short* pos_src = (short*)alloc((size_t)2048 * DM * 2);
  short* pos_bf  = (short*)alloc((size_t)2048 * DM * 2);
  short* lnb     = (short*)alloc((size_t)NROWS * DM * 2);
  short* hbig    = (short*)alloc((size_t)NROWS * FF * 2);
  short* qkvb    = (short*)alloc((size_t)NROWS * 3 * DM * 2);
  short* obuf    = (short*)alloc((size_t)NROWS * DM * 2);
  float* x1      = (float*)alloc((size_t)NROWS * DM * 4);
  float* x2      = (float*)alloc((size_t)NROWS * DM * 4);
  float* dwout   = (float*)qkvb;
  short* pw1raw  = hbig;
  short* convy   = obuf;
  float* x3 = x1;
  float* x4 = x2;
  short* VTp = hbig + (size_t)3 * 4194304;   // V^T [bh][64][1024], 8MB

  auto cvt = [&](const float* s, short* d, size_t n) {
    int n4 = (int)(n >> 2);
    cvt_kernel<<<dim3((n4 + 255) / 256), dim3(256), 0, stream>>>(s, d, n4);
  };
  cvt(ffm_w1, wb_ffm1, (size_t)FF * DM);
  cvt(ffm_w2, wb_ffm2, (size_t)DM * FF);
  cvt(in_w,   wb_in,   (size_t)3 * DM * DM);
  cvt(out_w,  wb_out,  (size_t)DM * DM);
  cvt(pos_w,  wb_pos,  (size_t)DM * DM);
  cvt(pw1_w,  wb_pw1,  (size_t)2 * DM * DM);
  cvt(pw2_w,  wb_pw2,  (size_t)DM * DM);
  cvt(ff_w1,  wb_ff1,  (size_t)FF * DM);
  cvt(ff_w2,  wb_ff2,  (size_t)DM * FF);
  cvt(pose,   pos_src, (size_t)2047 * DM);

  auto gemm = [&](int EPI, const short* A, const short* W, const float* bias,
                  const float* res, float alpha, void* out, int M, int N, int K) {
    dim3 g((M / 128) * (N / 128)), blk(256);
    switch (EPI) {
      case 0: gemm_bt<0><<<g, blk, 0, stream>>>(A, W, bias, res, alpha, out, M, N, K); break;
      case 1: gemm_bt<1><<<g, blk, 0, stream>>>(A, W, bias, res, alpha, out, M, N, K); break;
      case 2: gemm_bt<2><<<g, blk, 0, stream>>>(A, W, bias, res, alpha, out, M, N, K); break;
      default: gemm_bt<3><<<g, blk, 0, stream>>>(A, W, bias, res, alpha, out, M, N, K); break;
    }
  };
  auto gemm2 = [&](int EPI, const short* A, const short* W, const float* bias,
                   short* out, int M, int N, int K) {
    dim3 g((M / 256) * (N / 256)), blk(512);
    if (EPI == 0) gemm256<0><<<g, blk, 0, stream>>>(A, W, bias, out, M, N, K);
    else          gemm256<1><<<g, blk, 0, stream>>>(A, W, bias, out, M, N, K);
  };
  auto ln = [&](int MODE, const float* x, const float* g, const float* b, void* o) {
    dim3 grid(NROWS / 4), blk(256);
    if (MODE == 0)      ln_kernel<0><<<grid, blk, 0, stream>>>(x, g, b, o);
    else if (MODE == 1) ln_kernel<1><<<grid, blk, 0, stream>>>(x, g, b, o);
    else                ln_kernel<2><<<grid, blk, 0, stream>>>(x, g, b, o);
  };

  // positional projection
  gemm(3, pos_src, wb_pos, nullptr, nullptr, 0.f, pos_bf, 2048, DM, DM);

  // macaron FFN: x1 = src + 0.5*ffn(ln(src))
  ln(0, src, g_ffm, b_ffm, lnb);
  gemm2(1, lnb, wb_ffm1, ffm_b1, hbig, NROWS, FF, DM);
  gemm(2, hbig, wb_ffm2, ffm_b2, src, 0.5f, x1, NROWS, DM, FF);

  // MHA: x2 = x1 + out_proj(attn(ln(x1)))
  ln(0, x1, g_mha, b_mha, lnb);
  gemm2(0, lnb, wb_in, in_b, qkvb, NROWS, 3 * DM, DM);
  prep_kernel<<<dim3(1024), dim3(256), 0, stream>>>(qkvb, VTp);
  attn_kernel<<<dim3(512), dim3(512), 0, stream>>>(qkvb, VTp, pos_bf, bias_u, bias_v, obuf);
  gemm(2, obuf, wb_out, out_b, x1, 1.f, x2, NROWS, DM, DM);

  // conv module
  ln(0, x2, g_conv, b_conv, lnb);
  gemm2(0, lnb, wb_pw1, pw1_b, pw1raw, NROWS, 2 * DM, DM);
  glu_dwconv_kernel<<<dim3(1024), dim3(256), 0, stream>>>(pw1raw, dw_w, dw_b, dwout);
  ln(2, dwout, cng, cnb, convy);
  gemm(2, convy, wb_pw2, pw2_b, x2, 1.f, x3, NROWS, DM, DM);

  // final FFN
  ln(0, x3, g_ff, b_ff, lnb);
  gemm2(1, lnb, wb_ff1, ff_b1, hbig, NROWS, FF, DM);
  gemm(2, hbig, wb_ff2, ff_b2, x3, 1.f, x4, NROWS, DM, FF);

  // final LN -> f32 output
  ln(1, x4, g_fin, b_fin, d_out);

  (void)in_sizes; (void)n_in; (void)out_size; (void)ws_size;
}

// Round 8
// 375.276 us; speedup vs baseline: 1.2721x; 1.0838x over previous
//
#include <hip/hip_runtime.h>

typedef __attribute__((ext_vector_type(8))) short bf16x8;
typedef __attribute__((ext_vector_type(4))) short s16x4;
typedef __attribute__((ext_vector_type(4))) float f32x4;
typedef unsigned int u32;

#define SQ 1024
#define BB 8
#define DM 512
#define NH 8
#define HD 64
#define FF 2048
#define NROWS (SQ*BB)

static __device__ __forceinline__ float b2f(short s) {
  return __uint_as_float(((u32)(unsigned short)s) << 16);
}
static __device__ __forceinline__ short f2b(float f) {
  u32 u = __float_as_uint(f);
  return (short)((u + 0x7FFFu + ((u >> 16) & 1u)) >> 16);
}
// cheap round (non-RNE) for hot inner-loop LDS stores
static __device__ __forceinline__ short f2bt(float f) {
  return (short)((__float_as_uint(f) + 0x8000u) >> 16);
}
static __device__ __forceinline__ float sigm(float x) { return 1.f / (1.f + __expf(-x)); }

static __device__ __forceinline__ f32x4 mfma16(bf16x8 a, bf16x8 b, f32x4 c) {
  return __builtin_amdgcn_mfma_f32_16x16x32_bf16(a, b, c, 0, 0, 0);
}

static __device__ __forceinline__ void gload16(const void* g, void* l) {
  __builtin_amdgcn_global_load_lds(
      (const __attribute__((address_space(1))) void*)g,
      (__attribute__((address_space(3))) void*)l, 16, 0, 0);
}

// XOR swizzle for row-major [*][64 bf16] tiles (128 B row stride)
static __device__ __forceinline__ int swzp(int r, int byteoff) {
  return (r * 128 + byteoff) ^ ((r & 7) << 4);
}

#define WAIT_LGKM() do { \
    asm volatile("s_waitcnt lgkmcnt(0)" ::: "memory"); \
    __builtin_amdgcn_sched_barrier(0); } while (0)
#define WAIT_VM(n) do { \
    asm volatile("s_waitcnt vmcnt(" #n ")" ::: "memory"); \
    __builtin_amdgcn_sched_barrier(0); } while (0)

// ---------------- batched f32 -> bf16 convert (10 segments, 1 launch) ----------------
struct CvtArgs {
  const float* s[10];
  short* d[10];
  int n4[10];
  int cum[10];   // first block index of each segment
};
__global__ __launch_bounds__(256) void cvt_multi(CvtArgs a) {
  int bid = blockIdx.x;
  int seg = 0;
#pragma unroll
  for (int i = 1; i < 10; ++i) if (bid >= a.cum[i]) seg = i;
  int idx = (bid - a.cum[seg]) * 256 + threadIdx.x;
  if (idx >= a.n4[seg]) return;
  float4 v = ((const float4*)a.s[seg])[idx];
  s16x4 r = { f2b(v.x), f2b(v.y), f2b(v.z), f2b(v.w) };
  ((s16x4*)a.d[seg])[idx] = r;
}

// ---------------- row LayerNorm, D=512, one wave per row ----------------
// MODE 0: bf16 out; 1: f32 out.  INF32: input dtype.
template<int MODE, int INF32>
__global__ __launch_bounds__(256) void ln_kernel(const void* __restrict__ xin,
                                                 const float* __restrict__ gam,
                                                 const float* __restrict__ bet,
                                                 void* __restrict__ out) {
  int w = threadIdx.x >> 6, lane = threadIdx.x & 63;
  int row = (blockIdx.x << 2) + w;
  float v[8];
  if (INF32) {
    const float* xr = (const float*)xin + (size_t)row * DM + lane * 8;
    float4 a = *(const float4*)xr;
    float4 c = *(const float4*)(xr + 4);
    v[0]=a.x; v[1]=a.y; v[2]=a.z; v[3]=a.w; v[4]=c.x; v[5]=c.y; v[6]=c.z; v[7]=c.w;
  } else {
    bf16x8 x8 = *(const bf16x8*)((const short*)xin + (size_t)row * DM + lane * 8);
#pragma unroll
    for (int e = 0; e < 8; ++e) v[e] = b2f(x8[e]);
  }
  float s = 0.f, q = 0.f;
#pragma unroll
  for (int e = 0; e < 8; ++e) { s += v[e]; q += v[e] * v[e]; }
#pragma unroll
  for (int m = 1; m < 64; m <<= 1) { s += __shfl_xor(s, m); q += __shfl_xor(q, m); }
  float mean = s * (1.f / DM);
  float rstd = rsqrtf(q * (1.f / DM) - mean * mean + 1e-5f);
  int col = lane * 8;
  if (MODE == 1) {
    float* o = (float*)out + (size_t)row * DM + col;
    float y[8];
#pragma unroll
    for (int e = 0; e < 8; ++e) y[e] = (v[e] - mean) * rstd * gam[col + e] + bet[col + e];
    *(float4*)o = make_float4(y[0], y[1], y[2], y[3]);
    *(float4*)(o + 4) = make_float4(y[4], y[5], y[6], y[7]);
  } else {
    bf16x8 r;
#pragma unroll
    for (int e = 0; e < 8; ++e) {
      float y = (v[e] - mean) * rstd * gam[col + e] + bet[col + e];
      r[e] = f2b(y);
    }
    *(bf16x8*)((short*)out + (size_t)row * DM + col) = r;
  }
}

// ---------------- 256x256 GEMM, BK=32, ring-3, counted vmcnt, st_16x32 swizzle ----------------
template<int EPI>
__global__ __launch_bounds__(512, 2) void gemm256(const short* __restrict__ A,
                                                  const short* __restrict__ W,
                                                  const float* __restrict__ bias,
                                                  short* __restrict__ out,
                                                  int M, int N, int K) {
  __shared__ __align__(16) short lds[3 * 16384];
  int nb = N >> 8;
  int nwg = gridDim.x, bid = blockIdx.x;
  int bid2 = ((nwg & 7) == 0) ? ((bid & 7) * (nwg >> 3) + (bid >> 3)) : bid;
  int bm = bid2 / nb, bn = bid2 % nb;
  int m0 = bm << 8, n0 = bn << 8;
  int tid = threadIdx.x, w = tid >> 6, lane = tid & 63;
  int wm = w >> 2, wn = w & 3;
  int l15 = lane & 15, l4 = lane >> 4;
  int srow = lane >> 2;
  int slog = (lane & 3) ^ (((lane >> 5) & 1) << 1);
  int scol = slog << 3;

  const short* gsrc = (w < 4) ? (A + (size_t)(m0 + w * 64 + srow) * K + scol)
                              : (W + (size_t)(n0 + (w - 4) * 64 + srow) * K + scol);

  f32x4 acc[8][4];
#pragma unroll
  for (int i = 0; i < 8; ++i)
#pragma unroll
    for (int j = 0; j < 4; ++j) acc[i][j] = (f32x4){0.f, 0.f, 0.f, 0.f};

  auto stage2 = [&](int u, int kt, int q0) {
#pragma unroll
    for (int q = q0; q < q0 + 2; ++q)
      gload16(gsrc + (size_t)(q * 16) * K + kt,
              (char*)lds + u * 32768 + (w * 4 + q) * 1024);
  };
  auto rdA = [&](int u, int mf) -> bf16x8 {
    int ps = l4 ^ (((l15 >> 3) & 1) << 1);
    return *(const bf16x8*)((char*)lds + u * 32768 + (wm * 8 + mf) * 1024 + l15 * 64 + ps * 16);
  };
  auto rdB = [&](int u, int nf) -> bf16x8 {
    int ps = l4 ^ (((l15 >> 3) & 1) << 1);
    return *(const bf16x8*)((char*)lds + u * 32768 + 16384 + (wn * 4 + nf) * 1024 + l15 * 64 + ps * 16);
  };

  int nt = K >> 5;
  stage2(0, 0, 0); stage2(0, 0, 2);
  stage2(1, 32, 0); stage2(1, 32, 2);
  WAIT_VM(4);
  __builtin_amdgcn_s_barrier();

  int u = 0;
  for (int t = 0; t < nt; ++t) {
    int kt2 = (t + 2) << 5;
    int us = u + 2; if (us >= 3) us -= 3;
    bool st = (t + 2) < nt;
    bf16x8 afrag[4], bfrag[4];
#pragma unroll
    for (int nf = 0; nf < 4; ++nf) bfrag[nf] = rdB(u, nf);
#pragma unroll
    for (int mf = 0; mf < 4; ++mf) afrag[mf] = rdA(u, mf);
    if (st) stage2(us, kt2, 0);
    __builtin_amdgcn_s_barrier();
    WAIT_LGKM();
    __builtin_amdgcn_s_setprio(1);
#pragma unroll
    for (int mf = 0; mf < 4; ++mf)
#pragma unroll
      for (int nf = 0; nf < 4; ++nf)
        acc[mf][nf] = mfma16(afrag[mf], bfrag[nf], acc[mf][nf]);
    __builtin_amdgcn_s_setprio(0);
    __builtin_amdgcn_s_barrier();
#pragma unroll
    for (int mf = 0; mf < 4; ++mf) afrag[mf] = rdA(u, mf + 4);
    if (st) stage2(us, kt2, 2);
    __builtin_amdgcn_s_barrier();
    WAIT_LGKM();
    __builtin_amdgcn_s_setprio(1);
#pragma unroll
    for (int mf = 0; mf < 4; ++mf)
#pragma unroll
      for (int nf = 0; nf < 4; ++nf)
        acc[mf + 4][nf] = mfma16(afrag[mf], bfrag[nf], acc[mf + 4][nf]);
    __builtin_amdgcn_s_setprio(0);
    if (t < nt - 1) {
      if (st) { WAIT_VM(4); } else { WAIT_VM(0); }
    }
    __builtin_amdgcn_s_barrier();
    ++u; if (u >= 3) u -= 3;
  }

#pragma unroll
  for (int nf = 0; nf < 4; ++nf) {
    int col = n0 + wn * 64 + nf * 16 + l15;
    float bv = bias[col];
#pragma unroll
    for (int mf = 0; mf < 8; ++mf) {
#pragma unroll
      for (int r4 = 0; r4 < 4; ++r4) {
        int row = m0 + wm * 128 + mf * 16 + l4 * 4 + r4;
        float v = acc[mf][nf][r4] + bv;
        if (EPI == 1) v = v * sigm(v);
        out[(size_t)row * N + col] = f2b(v);
      }
    }
  }
}

// ---------------- 128x128 GEMM (2-phase) ----------------
// EPI 2: res + alpha*(acc+bias) -> bf16 ; 3: plain -> bf16.  RESF32: residual dtype.
template<int EPI, int RESF32>
__global__ __launch_bounds__(256) void gemm_bt(const short* __restrict__ A,
                                               const short* __restrict__ W,
                                               const float* __restrict__ bias,
                                               const void* __restrict__ res,
                                               float alpha, short* __restrict__ out,
                                               int M, int N, int K) {
  __shared__ __align__(16) short ldsA[2 * 128 * 32];
  __shared__ __align__(16) short ldsB[2 * 128 * 32];
  int nb = N >> 7;
  int nwg = gridDim.x, bid = blockIdx.x;
  int bid2 = ((nwg & 7) == 0) ? ((bid & 7) * (nwg >> 3) + (bid >> 3)) : bid;
  int bm = bid2 / nb, bn = bid2 % nb;
  int m0 = bm << 7, n0 = bn << 7;
  int tid = threadIdx.x, w = tid >> 6, lane = tid & 63;
  int wm = w >> 1, wn = w & 1;
  f32x4 acc[4][4];
#pragma unroll
  for (int i = 0; i < 4; ++i)
#pragma unroll
    for (int j = 0; j < 4; ++j) acc[i][j] = (f32x4){0.f, 0.f, 0.f, 0.f};

  auto stage = [&](int bufsel, int kt) {
#pragma unroll
    for (int q = 0; q < 2; ++q) {
      int c = (q * 4 + w) * 64 + lane;
      int r = c >> 2, cc = c & 3;
      gload16(A + (size_t)(m0 + r) * K + kt + cc * 8,
              (char*)ldsA + bufsel * 8192 + (q * 4 + w) * 1024);
      gload16(W + (size_t)(n0 + r) * K + kt + cc * 8,
              (char*)ldsB + bufsel * 8192 + (q * 4 + w) * 1024);
    }
  };

  stage(0, 0);
  asm volatile("s_waitcnt vmcnt(0)" ::: "memory");
  __syncthreads();
  int cur = 0;
  for (int kt = 0; kt < K; kt += 32) {
    if (kt + 32 < K) stage(cur ^ 1, kt + 32);
    int rr = lane & 15, kk = (lane >> 4) << 3;
    bf16x8 af[4], bfr[4];
#pragma unroll
    for (int mt = 0; mt < 4; ++mt)
      af[mt] = *(const bf16x8*)(ldsA + cur * 4096 + (wm * 64 + mt * 16 + rr) * 32 + kk);
#pragma unroll
    for (int nt = 0; nt < 4; ++nt)
      bfr[nt] = *(const bf16x8*)(ldsB + cur * 4096 + (wn * 64 + nt * 16 + rr) * 32 + kk);
#pragma unroll
    for (int mt = 0; mt < 4; ++mt)
#pragma unroll
      for (int nt = 0; nt < 4; ++nt)
        acc[mt][nt] = mfma16(af[mt], bfr[nt], acc[mt][nt]);
    asm volatile("s_waitcnt vmcnt(0)" ::: "memory");
    __syncthreads();
    cur ^= 1;
  }

#pragma unroll
  for (int mt = 0; mt < 4; ++mt) {
#pragma unroll
    for (int nt = 0; nt < 4; ++nt) {
      int col = n0 + wn * 64 + nt * 16 + (lane & 15);
      float bv = (EPI == 3) ? 0.f : bias[col];
#pragma unroll
      for (int r4 = 0; r4 < 4; ++r4) {
        int row = m0 + wm * 64 + mt * 16 + (lane >> 4) * 4 + r4;
        size_t idx = (size_t)row * N + col;
        float v = acc[mt][nt][r4] + bv;
        if (EPI == 3) {
          out[idx] = f2b(v);
        } else {
          float rv = RESF32 ? ((const float*)res)[idx] : b2f(((const short*)res)[idx]);
          out[idx] = f2b(rv + alpha * v);
        }
      }
    }
  }
}

// ---------------- V-transpose prep: qkv V section -> VT [bh][d][s] ----------------
__global__ __launch_bounds__(256) void prep_kernel(const short* __restrict__ qkv,
                                                   short* __restrict__ VTp) {
  __shared__ short ldsv[64 * 66];
  int tid = threadIdx.x;
  int st = blockIdx.x & 15, bh = blockIdx.x >> 4;
  int b = bh >> 3, h = bh & 7;
  int s0 = st << 6;
#pragma unroll
  for (int pass = 0; pass < 2; ++pass) {
    int r = pass * 32 + (tid >> 3), c = tid & 7;
    int s = s0 + r;
    bf16x8 v8 = *(const bf16x8*)(qkv + (size_t)(s * BB + b) * 1536 + 1024 + h * 64 + c * 8);
    *(bf16x8*)(ldsv + r * 66 + c * 8) = v8;
  }
  __syncthreads();
#pragma unroll
  for (int pass = 0; pass < 2; ++pass) {
    int d = pass * 32 + (tid >> 3), sc = tid & 7;
    bf16x8 o;
#pragma unroll
    for (int u = 0; u < 8; ++u) o[u] = ldsv[(sc * 8 + u) * 66 + d];
    *(bf16x8*)(VTp + ((size_t)bh * 64 + d) * SQ + s0 + sc * 8) = o;
  }
}

// ---------------- fused rel-pos flash attention ----------------
// grid = 8(it) * 64(bh) [XCD-local]; block 512 (8 waves)
__global__ __launch_bounds__(512, 4) void attn_kernel(const short* __restrict__ qkv,
                                                      const short* __restrict__ VTp,
                                                      const short* __restrict__ posb,
                                                      const float* __restrict__ bias_u,
                                                      const float* __restrict__ bias_v,
                                                      short* __restrict__ obuf) {
  __shared__ __align__(16) char smem[78848];
  char* lds_k   = smem;            // 2 x [64][64] bf16 swizzled (16KB)
  char* lds_vt  = smem + 16384;    // [64 d][64 j] (8KB)
  char* lds_pos = smem + 24576;    // 4 segs x [64][64] (32KB), circular
  char* lds_ew  = smem + 57344;    // 8 waves x 2688B; e band [16 q][84 n]; P overlaps

  int tid = threadIdx.x, w = tid >> 6, lane = tid & 63;
  int l15 = lane & 15, l4 = lane >> 4;
  int it = blockIdx.x >> 6, bh = blockIdx.x & 63;
  int b = bh >> 3, h = bh & 7;
  int i0 = it << 7;
  char* ewb = lds_ew + w * 2688;

  const size_t hoffB = (size_t)bh * SQ * 128;   // VTp bytes

  // Q fragments with inline bias add; SC2 folded into the operands
  const float SC2 = 0.125f * 1.44269504f;
  int fr = i0 + w * 16 + l15;
  const short* qrow = qkv + (size_t)(fr * BB + b) * 1536 + h * 64;
  bf16x8 qu_f[2], qv_f[2];
#pragma unroll
  for (int ks = 0; ks < 2; ++ks) {
    bf16x8 qraw = *(const bf16x8*)(qrow + ks * 32 + l4 * 8);
#pragma unroll
    for (int e = 0; e < 8; ++e) {
      float qf = b2f(qraw[e]);
      int d = h * 64 + ks * 32 + l4 * 8 + e;
      qu_f[ks][e] = f2b((qf + bias_u[d]) * SC2);
      qv_f[ks][e] = f2b((qf + bias_v[d]) * SC2);
    }
  }

  float m_run = -1e30f, l_run = 0.f;   // lane-local partial l
  f32x4 o_acc[4];
#pragma unroll
  for (int dt = 0; dt < 4; ++dt) o_acc[dt] = (f32x4){0.f, 0.f, 0.f, 0.f};

  int prbase = 112 - 16 * w;
  int lnq = lane >> 3, lnr = lane & 7;
  int r8 = w * 8 + lnq;
  int byt = (lnr * 16) ^ ((r8 & 7) << 4);
  int nbase = 896 - i0;

  auto stageK = [&](int t1) {
    int j = (t1 << 6) + r8;
    gload16((const char*)qkv + (size_t)(j * BB + b) * 3072 + 1024 + h * 128 + byt,
            lds_k + (t1 & 1) * 8192 + w * 1024);
  };
  auto stageVT = [&](int t1) {
    gload16((const char*)VTp + hoffB + (size_t)r8 * 2048 + (size_t)(t1 << 7) + byt,
            lds_vt + w * 1024);
  };
  auto stagePosSeg = [&](int gbase, int pseg) {
    gload16((const char*)posb + (size_t)(gbase + r8) * 1024 + h * 128 + byt,
            lds_pos + pseg * 8192 + w * 1024);
  };

  stagePosSeg(nbase, 0);
  stagePosSeg(nbase + 64, 1);
  stagePosSeg(nbase + 128, 2);
  stageK(0);
  WAIT_VM(0);

  for (int t = 0; t < 16; ++t) {
    int cur = t & 1;
    __builtin_amdgcn_s_barrier();        // barrier1: K/pos(t) staged; PV(t-1) done
    stageVT(t);

    f32x4 acs[4];
    __builtin_amdgcn_s_setprio(1);
#pragma unroll
    for (int kt = 0; kt < 4; ++kt) {
      f32x4 z = (f32x4){0.f, 0.f, 0.f, 0.f};
      bf16x8 kb0 = *(const bf16x8*)(lds_k + cur * 8192 + swzp(kt * 16 + l15, l4 * 16));
      bf16x8 kb1 = *(const bf16x8*)(lds_k + cur * 8192 + swzp(kt * 16 + l15, 64 + l4 * 16));
      z = mfma16(kb0, qu_f[0], z);
      z = mfma16(kb1, qu_f[1], z);
      acs[kt] = z;
    }
    __builtin_amdgcn_s_setprio(0);
#pragma unroll
    for (int pt = 0; pt < 5; ++pt) {
      f32x4 z = (f32x4){0.f, 0.f, 0.f, 0.f};
      int pr = prbase + pt * 16 + l15;
      char* pbase = lds_pos + (((t + (pr >> 6)) & 3) * 8192);
      bf16x8 pb0 = *(const bf16x8*)(pbase + swzp(pr & 63, l4 * 16));
      bf16x8 pb1 = *(const bf16x8*)(pbase + swzp(pr & 63, 64 + l4 * 16));
      __builtin_amdgcn_s_setprio(1);
      z = mfma16(pb0, qv_f[0], z);
      z = mfma16(pb1, qv_f[1], z);
      __builtin_amdgcn_s_setprio(0);
      s16x4 ek;
#pragma unroll
      for (int r = 0; r < 4; ++r) ek[r] = f2bt(z[r]);
      *(s16x4*)(ewb + (l15 * 84 + pt * 16 + l4 * 4) * 2) = ek;
    }

    bool pf = (t + 1) < 16;
    if (pf) {
      stageK(t + 1);
      stagePosSeg(nbase + (t << 6) + 192, (t + 3) & 3);
    }

    WAIT_LGKM();

    float sv[4][4];
    float mt = -1e30f;
#pragma unroll
    for (int kt = 0; kt < 4; ++kt) {
#pragma unroll
      for (int r = 0; r < 4; ++r) {
        int n = 15 - l15 + kt * 16 + l4 * 4 + r;
        float ev = b2f(*(const short*)(ewb + (l15 * 84 + n) * 2));
        float sc = acs[kt][r] + ev;   // SC2 pre-folded into operands
        sv[kt][r] = sc;
        mt = fmaxf(mt, sc);
      }
    }
    if (!__all(mt <= m_run + 11.5415604f)) {
      float mr = fmaxf(mt, __shfl_xor(mt, 16));
      mr = fmaxf(mr, __shfl_xor(mr, 32));
      float mn = fmaxf(m_run, mr);
      float fac = exp2f(m_run - mn);
      m_run = mn;
      l_run *= fac;
      float fb[4];
#pragma unroll
      for (int r4 = 0; r4 < 4; ++r4) fb[r4] = __shfl(fac, (l4 << 2) + r4);
#pragma unroll
      for (int dt = 0; dt < 4; ++dt)
#pragma unroll
        for (int r4 = 0; r4 < 4; ++r4) o_acc[dt][r4] *= fb[r4];
    }
    float ls = 0.f;
#pragma unroll
    for (int kt = 0; kt < 4; ++kt) {
      s16x4 pk;
#pragma unroll
      for (int r = 0; r < 4; ++r) {
        float p = exp2f(sv[kt][r] - m_run);
        ls += p;
        pk[r] = f2bt(p);
      }
      *(s16x4*)(ewb + l15 * 128 + ((kt * 32 + l4 * 8) ^ ((l15 & 7) << 4))) = pk;
    }
    l_run += ls;

    if (pf) { WAIT_VM(2); } else { WAIT_VM(0); }
    WAIT_LGKM();
    __builtin_amdgcn_s_barrier();        // barrier2: all VT writes landed

    bf16x8 pa[2];
#pragma unroll
    for (int ks = 0; ks < 2; ++ks)
      pa[ks] = *(const bf16x8*)(ewb + swzp(l15, ks * 64 + l4 * 16));
    __builtin_amdgcn_s_setprio(1);
#pragma unroll
    for (int dt = 0; dt < 4; ++dt) {
      bf16x8 vb0 = *(const bf16x8*)(lds_vt + swzp(dt * 16 + l15, l4 * 16));
      bf16x8 vb1 = *(const bf16x8*)(lds_vt + swzp(dt * 16 + l15, 64 + l4 * 16));
      o_acc[dt] = mfma16(pa[0], vb0, o_acc[dt]);
      o_acc[dt] = mfma16(pa[1], vb1, o_acc[dt]);
    }
    __builtin_amdgcn_s_setprio(0);

    WAIT_VM(0);
  }

  float lt = l_run + __shfl_xor(l_run, 16);
  lt += __shfl_xor(lt, 32);
  float lb[4];
#pragma unroll
  for (int r4 = 0; r4 < 4; ++r4) lb[r4] = __shfl(lt, (l4 << 2) + r4);
#pragma unroll
  for (int dt = 0; dt < 4; ++dt) {
#pragma unroll
    for (int r4 = 0; r4 < 4; ++r4) {
      int i = i0 + w * 16 + l4 * 4 + r4;
      int d = dt * 16 + l15;
      float val = o_acc[dt][r4] / lb[r4];
      obuf[(size_t)(i * BB + b) * DM + h * 64 + d] = f2b(val);
    }
  }
}

// ---------------- GLU + depthwise conv (K=31) + fused LayerNorm + swish -> bf16 ----------------
__global__ __launch_bounds__(256) void glu_dwconv_kernel(const short* __restrict__ pw1,
                                                         const float* __restrict__ dww,
                                                         const float* __restrict__ dwb,
                                                         const float* __restrict__ cg,
                                                         const float* __restrict__ cb,
                                                         short* __restrict__ outbf) {
  __shared__ short glu[38 * 512];
  __shared__ float red[8][4][2];
  int tid = threadIdx.x;
  int b = blockIdx.x & 7;
  int s0 = (blockIdx.x >> 3) << 3;
  for (int idx = tid; idx < 38 * 64; idx += 256) {
    int r = idx >> 6, c8 = idx & 63;
    int s = s0 - 15 + r;
    bf16x8 res;
    if (s >= 0 && s < SQ) {
      const short* row = pw1 + (size_t)(s * BB + b) * 1024;
      bf16x8 a8 = *(const bf16x8*)(row + c8 * 8);
      bf16x8 g8 = *(const bf16x8*)(row + 512 + c8 * 8);
#pragma unroll
      for (int e = 0; e < 8; ++e) res[e] = f2b(b2f(a8[e]) * sigm(b2f(g8[e])));
    } else {
#pragma unroll
      for (int e = 0; e < 8; ++e) res[e] = 0;
    }
    *(bf16x8*)(glu + r * 512 + c8 * 8) = res;
  }
  __syncthreads();

  float a0[8], a1[8];
  {
    float wreg[31];
#pragma unroll
    for (int k = 0; k < 31; ++k) wreg[k] = dww[tid * 31 + k];
    float bb = dwb[tid];
    for (int ri = 0; ri < 8; ++ri) {
      float acc = bb;
#pragma unroll
      for (int k = 0; k < 31; ++k)
        acc += wreg[k] * b2f(glu[(ri + k) * 512 + tid]);
      a0[ri] = acc;
    }
  }
  {
    int d = tid + 256;
    float wreg[31];
#pragma unroll
    for (int k = 0; k < 31; ++k) wreg[k] = dww[d * 31 + k];
    float bb = dwb[d];
    for (int ri = 0; ri < 8; ++ri) {
      float acc = bb;
#pragma unroll
      for (int k = 0; k < 31; ++k)
        acc += wreg[k] * b2f(glu[(ri + k) * 512 + d]);
      a1[ri] = acc;
    }
  }

  // fused LayerNorm over 512 channels per row + swish
  int w = tid >> 6, lane = tid & 63;
#pragma unroll
  for (int ri = 0; ri < 8; ++ri) {
    float sp = a0[ri] + a1[ri];
    float qp = a0[ri] * a0[ri] + a1[ri] * a1[ri];
#pragma unroll
    for (int m = 1; m < 64; m <<= 1) { sp += __shfl_xor(sp, m); qp += __shfl_xor(qp, m); }
    if (lane == 0) { red[ri][w][0] = sp; red[ri][w][1] = qp; }
  }
  __syncthreads();
  float g0 = cg[tid], b0 = cb[tid], g1 = cg[tid + 256], b1 = cb[tid + 256];
#pragma unroll
  for (int ri = 0; ri < 8; ++ri) {
    float s = red[ri][0][0] + red[ri][1][0] + red[ri][2][0] + red[ri][3][0];
    float q = red[ri][0][1] + red[ri][1][1] + red[ri][2][1] + red[ri][3][1];
    float mean = s * (1.f / DM);
    float rstd = rsqrtf(q * (1.f / DM) - mean * mean + 1e-5f);
    float y0 = (a0[ri] - mean) * rstd * g0 + b0;
    float y1 = (a1[ri] - mean) * rstd * g1 + b1;
    y0 = y0 * sigm(y0);
    y1 = y1 * sigm(y1);
    size_t base = (size_t)((s0 + ri) * BB + b) * 512;
    outbf[base + tid] = f2b(y0);
    outbf[base + tid + 256] = f2b(y1);
  }
}

// ---------------- host ----------------
extern "C" void kernel_launch(void* const* d_in, const int* in_sizes, int n_in,
                              void* d_out, int out_size, void* d_ws, size_t ws_size,
                              hipStream_t stream) {
  const float* src    = (const float*)d_in[0];
  const float* pose   = (const float*)d_in[1];
  const float* ffm_w1 = (const float*)d_in[2];
  const float* ffm_b1 = (const float*)d_in[3];
  const float* ffm_w2 = (const float*)d_in[4];
  const float* ffm_b2 = (const float*)d_in[5];
  const float* in_w   = (const float*)d_in[6];
  const float* in_b   = (const float*)d_in[7];
  const float* out_w  = (const float*)d_in[8];
  const float* out_b  = (const float*)d_in[9];
  const float* pos_w  = (const float*)d_in[10];
  const float* bias_u = (const float*)d_in[11];
  const float* bias_v = (const float*)d_in[12];
  const float* pw1_w  = (const float*)d_in[13];
  const float* pw1_b  = (const float*)d_in[14];
  const float* dw_w   = (const float*)d_in[15];
  const float* dw_b   = (const float*)d_in[16];
  const float* cng    = (const float*)d_in[17];
  const float* cnb    = (const float*)d_in[18];
  const float* pw2_w  = (const float*)d_in[19];
  const float* pw2_b  = (const float*)d_in[20];
  const float* ff_w1  = (const float*)d_in[21];
  const float* ff_b1  = (const float*)d_in[22];
  const float* ff_w2  = (const float*)d_in[23];
  const float* ff_b2  = (const float*)d_in[24];
  const float* g_ffm  = (const float*)d_in[25];
  const float* b_ffm  = (const float*)d_in[26];
  const float* g_mha  = (const float*)d_in[27];
  const float* b_mha  = (const float*)d_in[28];
  const float* g_conv = (const float*)d_in[29];
  const float* b_conv = (const float*)d_in[30];
  const float* g_ff   = (const float*)d_in[31];
  const float* b_ff   = (const float*)d_in[32];
  const float* g_fin  = (const float*)d_in[33];
  const float* b_fin  = (const float*)d_in[34];

  char* ws = (char*)d_ws;
  size_t off = 0;
  auto alloc = [&](size_t bytes) -> void* {
    void* p = ws + off;
    off += (bytes + 255) & ~(size_t)255;
    return p;
  };
  short* wb_ffm1 = (short*)alloc((size_t)FF * DM * 2);
  short* wb_ffm2 = (short*)alloc((size_t)DM * FF * 2);
  short* wb_in   = (short*)alloc((size_t)3 * DM * DM * 2);
  short* wb_out  = (short*)alloc((size_t)DM * DM * 2);
  short* wb_pos  = (short*)alloc((size_t)DM * DM * 2);
  short* wb_pw1  = (short*)alloc((size_t)2 * DM * DM * 2);
  short* wb_pw2  = (short*)alloc((size_t)DM * DM * 2);
  short* wb_ff1  = (short*)alloc((size_t)FF * DM * 2);
  short* wb_ff2  = (short*)alloc((size_t)DM * FF * 2);
  short* pos_src = (short*)alloc((size_t)2048 * DM * 2);
  short* pos_bf  = (short*)alloc((size_t)2048 * DM * 2);
  short* lnb     = (short*)alloc((size_t)NROWS * DM * 2);
  short* hbig    = (short*)alloc((size_t)NROWS * FF * 2);
  short* qkvb    = (short*)alloc((size_t)NROWS * 3 * DM * 2);
  short* obuf    = (short*)alloc((size_t)NROWS * DM * 2);
  short* x1      = (short*)alloc((size_t)NROWS * DM * 2);   // bf16 residual stream
  short* x2      = (short*)alloc((size_t)NROWS * DM * 2);
  short* pw1raw  = hbig;
  short* convy   = obuf;
  short* x3 = x1;
  short* x4 = x2;
  short* VTp = hbig + (size_t)3 * 4194304;   // V^T [bh][64][1024], 8MB

  // ---- batched weight conversion (1 launch) ----
  CvtArgs ca;
  const float* srcs[10] = {ffm_w1, ffm_w2, in_w, out_w, pos_w, pw1_w, pw2_w, ff_w1, ff_w2, pose};
  short* dsts[10] = {wb_ffm1, wb_ffm2, wb_in, wb_out, wb_pos, wb_pw1, wb_pw2, wb_ff1, wb_ff2, pos_src};
  size_t ns[10] = {(size_t)FF*DM, (size_t)DM*FF, (size_t)3*DM*DM, (size_t)DM*DM, (size_t)DM*DM,
                   (size_t)2*DM*DM, (size_t)DM*DM, (size_t)FF*DM, (size_t)DM*FF, (size_t)2047*DM};
  int cum = 0;
  for (int i = 0; i < 10; ++i) {
    ca.s[i] = srcs[i]; ca.d[i] = dsts[i];
    ca.n4[i] = (int)(ns[i] >> 2);
    ca.cum[i] = cum;
    cum += (ca.n4[i] + 255) / 256;
  }
  cvt_multi<<<dim3(cum), dim3(256), 0, stream>>>(ca);

  auto gemmR = [&](int RESF32, const short* A, const short* W, const float* bias,
                   const void* res, float alpha, short* out, int M, int N, int K) {
    dim3 g((M / 128) * (N / 128)), blk(256);
    if (RESF32) gemm_bt<2, 1><<<g, blk, 0, stream>>>(A, W, bias, res, alpha, out, M, N, K);
    else        gemm_bt<2, 0><<<g, blk, 0, stream>>>(A, W, bias, res, alpha, out, M, N, K);
  };
  auto gemm2 = [&](int EPI, const short* A, const short* W, const float* bias,
                   short* out, int M, int N, int K) {
    dim3 g((M / 256) * (N / 256)), blk(512);
    if (EPI == 0) gemm256<0><<<g, blk, 0, stream>>>(A, W, bias, out, M, N, K);
    else          gemm256<1><<<g, blk, 0, stream>>>(A, W, bias, out, M, N, K);
  };

  // positional projection (plain bf16 out)
  gemm_bt<3, 0><<<dim3(64), dim3(256), 0, stream>>>(pos_src, wb_pos, nullptr, nullptr, 0.f,
                                                    pos_bf, 2048, DM, DM);

  // macaron FFN: x1 = src + 0.5*ffn(ln(src))
  ln_kernel<0, 1><<<dim3(NROWS / 4), dim3(256), 0, stream>>>(src, g_ffm, b_ffm, lnb);
  gemm2(1, lnb, wb_ffm1, ffm_b1, hbig, NROWS, FF, DM);
  gemmR(1, hbig, wb_ffm2, ffm_b2, src, 0.5f, x1, NROWS, DM, FF);

  // MHA: x2 = x1 + out_proj(attn(ln(x1)))
  ln_kernel<0, 0><<<dim3(NROWS / 4), dim3(256), 0, stream>>>(x1, g_mha, b_mha, lnb);
  gemm2(0, lnb, wb_in, in_b, qkvb, NROWS, 3 * DM, DM);
  prep_kernel<<<dim3(1024), dim3(256), 0, stream>>>(qkvb, VTp);
  attn_kernel<<<dim3(512), dim3(512), 0, stream>>>(qkvb, VTp, pos_bf, bias_u, bias_v, obuf);
  gemmR(0, obuf, wb_out, out_b, x1, 1.f, x2, NROWS, DM, DM);

  // conv module: x3 = x2 + pw2(fused[swish(ln(dwconv(glu(pw1(ln(x2))))))])
  ln_kernel<0, 0><<<dim3(NROWS / 4), dim3(256), 0, stream>>>(x2, g_conv, b_conv, lnb);
  gemm2(0, lnb, wb_pw1, pw1_b, pw1raw, NROWS, 2 * DM, DM);
  glu_dwconv_kernel<<<dim3(1024), dim3(256), 0, stream>>>(pw1raw, dw_w, dw_b, cng, cnb, convy);
  gemmR(0, convy, wb_pw2, pw2_b, x2, 1.f, x3, NROWS, DM, DM);

  // final FFN: x4 = x3 + ffn(ln(x3))
  ln_kernel<0, 0><<<dim3(NROWS / 4), dim3(256), 0, stream>>>(x3, g_ff, b_ff, lnb);
  gemm2(1, lnb, wb_ff1, ff_b1, hbig, NROWS, FF, DM);
  gemmR(0, hbig, wb_ff2, ff_b2, x3, 1.f, x4, NROWS, DM, FF);

  // final LN -> f32 output
  ln_kernel<1, 0><<<dim3(NROWS / 4), dim3(256), 0, stream>>>(x4, g_fin, b_fin, d_out);

  (void)in_sizes; (void)n_in; (void)out_size; (void)ws_size;
}

// Round 9
// 329.814 us; speedup vs baseline: 1.4474x; 1.1378x over previous
//
#include <hip/hip_runtime.h>

typedef __attribute__((ext_vector_type(8))) short bf16x8;
typedef __attribute__((ext_vector_type(4))) short s16x4;
typedef __attribute__((ext_vector_type(4))) float f32x4;
typedef unsigned int u32;

#define SQ 1024
#define BB 8
#define DM 512
#define NH 8
#define HD 64
#define FF 2048
#define NROWS (SQ*BB)

static __device__ __forceinline__ float b2f(short s) {
  return __uint_as_float(((u32)(unsigned short)s) << 16);
}
static __device__ __forceinline__ short f2b(float f) {
  u32 u = __float_as_uint(f);
  return (short)((u + 0x7FFFu + ((u >> 16) & 1u)) >> 16);
}
// cheap round (non-RNE) for hot inner-loop LDS stores
static __device__ __forceinline__ short f2bt(float f) {
  return (short)((__float_as_uint(f) + 0x8000u) >> 16);
}
static __device__ __forceinline__ float sigm(float x) { return 1.f / (1.f + __expf(-x)); }

static __device__ __forceinline__ f32x4 mfma16(bf16x8 a, bf16x8 b, f32x4 c) {
  return __builtin_amdgcn_mfma_f32_16x16x32_bf16(a, b, c, 0, 0, 0);
}

static __device__ __forceinline__ void gload16(const void* g, void* l) {
  __builtin_amdgcn_global_load_lds(
      (const __attribute__((address_space(1))) void*)g,
      (__attribute__((address_space(3))) void*)l, 16, 0, 0);
}

// XOR swizzle for row-major [*][64 bf16] tiles (128 B row stride)
static __device__ __forceinline__ int swzp(int r, int byteoff) {
  return (r * 128 + byteoff) ^ ((r & 7) << 4);
}

#define WAIT_LGKM() do { \
    asm volatile("s_waitcnt lgkmcnt(0)" ::: "memory"); \
    __builtin_amdgcn_sched_barrier(0); } while (0)
#define WAIT_VM(n) do { \
    asm volatile("s_waitcnt vmcnt(" #n ")" ::: "memory"); \
    __builtin_amdgcn_sched_barrier(0); } while (0)

// ---------------- batched f32 -> bf16 convert (10 segments, 1 launch) ----------------
struct CvtArgs {
  const float* s[10];
  short* d[10];
  int n4[10];
  int cum[10];
};
__global__ __launch_bounds__(256) void cvt_multi(CvtArgs a) {
  int bid = blockIdx.x;
  int seg = 0;
#pragma unroll
  for (int i = 1; i < 10; ++i) if (bid >= a.cum[i]) seg = i;
  int idx = (bid - a.cum[seg]) * 256 + threadIdx.x;
  if (idx >= a.n4[seg]) return;
  float4 v = ((const float4*)a.s[seg])[idx];
  s16x4 r = { f2b(v.x), f2b(v.y), f2b(v.z), f2b(v.w) };
  ((s16x4*)a.d[seg])[idx] = r;
}

// ---------------- row LayerNorm, D=512, one wave per row ----------------
// MODE 0: bf16 out; 1: f32 out.  INF32: input dtype.
template<int MODE, int INF32>
__global__ __launch_bounds__(256) void ln_kernel(const void* __restrict__ xin,
                                                 const float* __restrict__ gam,
                                                 const float* __restrict__ bet,
                                                 void* __restrict__ out) {
  int w = threadIdx.x >> 6, lane = threadIdx.x & 63;
  int row = (blockIdx.x << 2) + w;
  float v[8];
  if (INF32) {
    const float* xr = (const float*)xin + (size_t)row * DM + lane * 8;
    float4 a = *(const float4*)xr;
    float4 c = *(const float4*)(xr + 4);
    v[0]=a.x; v[1]=a.y; v[2]=a.z; v[3]=a.w; v[4]=c.x; v[5]=c.y; v[6]=c.z; v[7]=c.w;
  } else {
    bf16x8 x8 = *(const bf16x8*)((const short*)xin + (size_t)row * DM + lane * 8);
#pragma unroll
    for (int e = 0; e < 8; ++e) v[e] = b2f(x8[e]);
  }
  float s = 0.f, q = 0.f;
#pragma unroll
  for (int e = 0; e < 8; ++e) { s += v[e]; q += v[e] * v[e]; }
#pragma unroll
  for (int m = 1; m < 64; m <<= 1) { s += __shfl_xor(s, m); q += __shfl_xor(q, m); }
  float mean = s * (1.f / DM);
  float rstd = rsqrtf(q * (1.f / DM) - mean * mean + 1e-5f);
  int col = lane * 8;
  if (MODE == 1) {
    float* o = (float*)out + (size_t)row * DM + col;
    float y[8];
#pragma unroll
    for (int e = 0; e < 8; ++e) y[e] = (v[e] - mean) * rstd * gam[col + e] + bet[col + e];
    *(float4*)o = make_float4(y[0], y[1], y[2], y[3]);
    *(float4*)(o + 4) = make_float4(y[4], y[5], y[6], y[7]);
  } else {
    bf16x8 r;
#pragma unroll
    for (int e = 0; e < 8; ++e) {
      float y = (v[e] - mean) * rstd * gam[col + e] + bet[col + e];
      r[e] = f2b(y);
    }
    *(bf16x8*)((short*)out + (size_t)row * DM + col) = r;
  }
}

// ---------------- 256x256 GEMM, BK=32, ring-3, counted vmcnt, st_16x32 swizzle ----------------
template<int EPI>
__global__ __launch_bounds__(512, 2) void gemm256(const short* __restrict__ A,
                                                  const short* __restrict__ W,
                                                  const float* __restrict__ bias,
                                                  short* __restrict__ out,
                                                  int M, int N, int K) {
  __shared__ __align__(16) short lds[3 * 16384];
  int nb = N >> 8;
  int nwg = gridDim.x, bid = blockIdx.x;
  int bid2 = ((nwg & 7) == 0) ? ((bid & 7) * (nwg >> 3) + (bid >> 3)) : bid;
  int bm = bid2 / nb, bn = bid2 % nb;
  int m0 = bm << 8, n0 = bn << 8;
  int tid = threadIdx.x, w = tid >> 6, lane = tid & 63;
  int wm = w >> 2, wn = w & 3;
  int l15 = lane & 15, l4 = lane >> 4;
  int srow = lane >> 2;
  int slog = (lane & 3) ^ (((lane >> 5) & 1) << 1);
  int scol = slog << 3;

  const short* gsrc = (w < 4) ? (A + (size_t)(m0 + w * 64 + srow) * K + scol)
                              : (W + (size_t)(n0 + (w - 4) * 64 + srow) * K + scol);

  f32x4 acc[8][4];
#pragma unroll
  for (int i = 0; i < 8; ++i)
#pragma unroll
    for (int j = 0; j < 4; ++j) acc[i][j] = (f32x4){0.f, 0.f, 0.f, 0.f};

  auto stage2 = [&](int u, int kt, int q0) {
#pragma unroll
    for (int q = q0; q < q0 + 2; ++q)
      gload16(gsrc + (size_t)(q * 16) * K + kt,
              (char*)lds + u * 32768 + (w * 4 + q) * 1024);
  };
  auto rdA = [&](int u, int mf) -> bf16x8 {
    int ps = l4 ^ (((l15 >> 3) & 1) << 1);
    return *(const bf16x8*)((char*)lds + u * 32768 + (wm * 8 + mf) * 1024 + l15 * 64 + ps * 16);
  };
  auto rdB = [&](int u, int nf) -> bf16x8 {
    int ps = l4 ^ (((l15 >> 3) & 1) << 1);
    return *(const bf16x8*)((char*)lds + u * 32768 + 16384 + (wn * 4 + nf) * 1024 + l15 * 64 + ps * 16);
  };

  int nt = K >> 5;
  stage2(0, 0, 0); stage2(0, 0, 2);
  stage2(1, 32, 0); stage2(1, 32, 2);
  WAIT_VM(4);
  __builtin_amdgcn_s_barrier();

  int u = 0;
  for (int t = 0; t < nt; ++t) {
    int kt2 = (t + 2) << 5;
    int us = u + 2; if (us >= 3) us -= 3;
    bool st = (t + 2) < nt;
    bf16x8 afrag[4], bfrag[4];
#pragma unroll
    for (int nf = 0; nf < 4; ++nf) bfrag[nf] = rdB(u, nf);
#pragma unroll
    for (int mf = 0; mf < 4; ++mf) afrag[mf] = rdA(u, mf);
    if (st) stage2(us, kt2, 0);
    __builtin_amdgcn_s_barrier();
    WAIT_LGKM();
    __builtin_amdgcn_s_setprio(1);
#pragma unroll
    for (int mf = 0; mf < 4; ++mf)
#pragma unroll
      for (int nf = 0; nf < 4; ++nf)
        acc[mf][nf] = mfma16(afrag[mf], bfrag[nf], acc[mf][nf]);
    __builtin_amdgcn_s_setprio(0);
    __builtin_amdgcn_s_barrier();
#pragma unroll
    for (int mf = 0; mf < 4; ++mf) afrag[mf] = rdA(u, mf + 4);
    if (st) stage2(us, kt2, 2);
    __builtin_amdgcn_s_barrier();
    WAIT_LGKM();
    __builtin_amdgcn_s_setprio(1);
#pragma unroll
    for (int mf = 0; mf < 4; ++mf)
#pragma unroll
      for (int nf = 0; nf < 4; ++nf)
        acc[mf + 4][nf] = mfma16(afrag[mf], bfrag[nf], acc[mf + 4][nf]);
    __builtin_amdgcn_s_setprio(0);
    if (t < nt - 1) {
      if (st) { WAIT_VM(4); } else { WAIT_VM(0); }
    }
    __builtin_amdgcn_s_barrier();
    ++u; if (u >= 3) u -= 3;
  }

#pragma unroll
  for (int nf = 0; nf < 4; ++nf) {
    int col = n0 + wn * 64 + nf * 16 + l15;
    float bv = bias[col];
#pragma unroll
    for (int mf = 0; mf < 8; ++mf) {
#pragma unroll
      for (int r4 = 0; r4 < 4; ++r4) {
        int row = m0 + wm * 128 + mf * 16 + l4 * 4 + r4;
        float v = acc[mf][nf][r4] + bv;
        if (EPI == 1) v = v * sigm(v);
        out[(size_t)row * N + col] = f2b(v);
      }
    }
  }
}

// ---------------- 128x128 GEMM: ring-3, counted vmcnt, 1 barrier/iter ----------------
// EPI 2: res + alpha*(acc+bias) -> bf16 ; 3: plain -> bf16.  RESF32: residual dtype.
// 256 thr, 4 waves (wm=w>>1, wn=w&1), wave out 64x64, LDS 48KB -> 3 blocks/CU.
template<int EPI, int RESF32>
__global__ __launch_bounds__(256, 3) void gemm128(const short* __restrict__ A,
                                                  const short* __restrict__ W,
                                                  const float* __restrict__ bias,
                                                  const void* __restrict__ res,
                                                  float alpha, short* __restrict__ out,
                                                  int M, int N, int K) {
  __shared__ __align__(16) short lds[3 * 8192];   // 3 bufs x 16KB (A 8KB + B 8KB, 1KB chunks)
  int nb = N >> 7;
  int nwg = gridDim.x, bid = blockIdx.x;
  int bid2 = ((nwg & 7) == 0) ? ((bid & 7) * (nwg >> 3) + (bid >> 3)) : bid;
  int bm = bid2 / nb, bn = bid2 % nb;
  int m0 = bm << 7, n0 = bn << 7;
  int tid = threadIdx.x, w = tid >> 6, lane = tid & 63;
  int wm = w >> 1, wn = w & 1;
  int l15 = lane & 15, l4 = lane >> 4;
  int srow = lane >> 2;
  int slog = (lane & 3) ^ (((lane >> 5) & 1) << 1);  // st_16x32 inverse-swizzled source slot
  int scol = slog << 3;

  // wave w stages 4 chunks (64 rows): w 0-1 -> A rows m0+w*64.., w 2-3 -> B rows n0+(w-2)*64..
  const short* gsrc = (w < 2) ? (A + (size_t)(m0 + w * 64 + srow) * K + scol)
                              : (W + (size_t)(n0 + (w - 2) * 64 + srow) * K + scol);
  int ldsbase = w * 4096;   // A chunks at 0..8191, B chunks at 8192..16383

  f32x4 acc[4][4];
#pragma unroll
  for (int i = 0; i < 4; ++i)
#pragma unroll
    for (int j = 0; j < 4; ++j) acc[i][j] = (f32x4){0.f, 0.f, 0.f, 0.f};

  auto stage = [&](int u, int kt) {
#pragma unroll
    for (int q = 0; q < 4; ++q)
      gload16(gsrc + (size_t)(q * 16) * K + kt,
              (char*)lds + u * 16384 + ldsbase + q * 1024);
  };
  auto rdA = [&](int u, int mf) -> bf16x8 {
    int ps = l4 ^ (((l15 >> 3) & 1) << 1);
    return *(const bf16x8*)((char*)lds + u * 16384 + (wm * 4 + mf) * 1024 + l15 * 64 + ps * 16);
  };
  auto rdB = [&](int u, int nf) -> bf16x8 {
    int ps = l4 ^ (((l15 >> 3) & 1) << 1);
    return *(const bf16x8*)((char*)lds + u * 16384 + 8192 + (wn * 4 + nf) * 1024 + l15 * 64 + ps * 16);
  };

  int nt = K >> 5;
  stage(0, 0);
  stage(1, 32);
  WAIT_VM(4);              // tile 0 landed (tile 1's 4 loads stay in flight)
  __builtin_amdgcn_s_barrier();

  int u = 0;
  for (int t = 0; t < nt; ++t) {
    int us = u + 2; if (us >= 3) us -= 3;
    bool st = (t + 2) < nt;
    bf16x8 afrag[4], bfrag[4];
#pragma unroll
    for (int mf = 0; mf < 4; ++mf) afrag[mf] = rdA(u, mf);
#pragma unroll
    for (int nf = 0; nf < 4; ++nf) bfrag[nf] = rdB(u, nf);
    if (st) stage(us, (t + 2) << 5);   // buf us held tile t-1; all reads done pre-barrier(t-1)
    WAIT_LGKM();                        // own-wave frag reads complete
    __builtin_amdgcn_s_setprio(1);
#pragma unroll
    for (int mf = 0; mf < 4; ++mf)
#pragma unroll
      for (int nf = 0; nf < 4; ++nf)
        acc[mf][nf] = mfma16(afrag[mf], bfrag[nf], acc[mf][nf]);
    __builtin_amdgcn_s_setprio(0);
    if (t < nt - 1) {
      if (st) { WAIT_VM(4); } else { WAIT_VM(0); }   // tile t+1 landed (wave-local)
    }
    __builtin_amdgcn_s_barrier();                    // block-wide: tile t+1 visible
    ++u; if (u >= 3) u -= 3;
  }

#pragma unroll
  for (int mf = 0; mf < 4; ++mf) {
#pragma unroll
    for (int nf = 0; nf < 4; ++nf) {
      int col = n0 + wn * 64 + nf * 16 + l15;
      float bv = (EPI == 3) ? 0.f : bias[col];
#pragma unroll
      for (int r4 = 0; r4 < 4; ++r4) {
        int row = m0 + wm * 64 + mf * 16 + l4 * 4 + r4;
        size_t idx = (size_t)row * N + col;
        float v = acc[mf][nf][r4] + bv;
        if (EPI == 3) {
          out[idx] = f2b(v);
        } else {
          float rv = RESF32 ? ((const float*)res)[idx] : b2f(((const short*)res)[idx]);
          out[idx] = f2b(rv + alpha * v);
        }
      }
    }
  }
}

// ---------------- V-transpose prep: qkv V section -> VT [bh][d][s] ----------------
__global__ __launch_bounds__(256) void prep_kernel(const short* __restrict__ qkv,
                                                   short* __restrict__ VTp) {
  __shared__ short ldsv[64 * 66];
  int tid = threadIdx.x;
  int st = blockIdx.x & 15, bh = blockIdx.x >> 4;
  int b = bh >> 3, h = bh & 7;
  int s0 = st << 6;
#pragma unroll
  for (int pass = 0; pass < 2; ++pass) {
    int r = pass * 32 + (tid >> 3), c = tid & 7;
    int s = s0 + r;
    bf16x8 v8 = *(const bf16x8*)(qkv + (size_t)(s * BB + b) * 1536 + 1024 + h * 64 + c * 8);
    *(bf16x8*)(ldsv + r * 66 + c * 8) = v8;
  }
  __syncthreads();
#pragma unroll
  for (int pass = 0; pass < 2; ++pass) {
    int d = pass * 32 + (tid >> 3), sc = tid & 7;
    bf16x8 o;
#pragma unroll
    for (int u = 0; u < 8; ++u) o[u] = ldsv[(sc * 8 + u) * 66 + d];
    *(bf16x8*)(VTp + ((size_t)bh * 64 + d) * SQ + s0 + sc * 8) = o;
  }
}

// ---------------- fused rel-pos flash attention ----------------
// grid = 8(it) * 64(bh) [XCD-local]; block 512 (8 waves)
__global__ __launch_bounds__(512, 4) void attn_kernel(const short* __restrict__ qkv,
                                                      const short* __restrict__ VTp,
                                                      const short* __restrict__ posb,
                                                      const float* __restrict__ bias_u,
                                                      const float* __restrict__ bias_v,
                                                      short* __restrict__ obuf) {
  __shared__ __align__(16) char smem[78848];
  char* lds_k   = smem;            // 2 x [64][64] bf16 swizzled (16KB)
  char* lds_vt  = smem + 16384;    // [64 d][64 j] (8KB)
  char* lds_pos = smem + 24576;    // 4 segs x [64][64] (32KB), circular
  char* lds_ew  = smem + 57344;    // 8 waves x 2688B; e band [16 q][84 n]; P overlaps

  int tid = threadIdx.x, w = tid >> 6, lane = tid & 63;
  int l15 = lane & 15, l4 = lane >> 4;
  int it = blockIdx.x >> 6, bh = blockIdx.x & 63;
  int b = bh >> 3, h = bh & 7;
  int i0 = it << 7;
  char* ewb = lds_ew + w * 2688;

  const size_t hoffB = (size_t)bh * SQ * 128;

  const float SC2 = 0.125f * 1.44269504f;
  int fr = i0 + w * 16 + l15;
  const short* qrow = qkv + (size_t)(fr * BB + b) * 1536 + h * 64;
  bf16x8 qu_f[2], qv_f[2];
#pragma unroll
  for (int ks = 0; ks < 2; ++ks) {
    bf16x8 qraw = *(const bf16x8*)(qrow + ks * 32 + l4 * 8);
#pragma unroll
    for (int e = 0; e < 8; ++e) {
      float qf = b2f(qraw[e]);
      int d = h * 64 + ks * 32 + l4 * 8 + e;
      qu_f[ks][e] = f2b((qf + bias_u[d]) * SC2);
      qv_f[ks][e] = f2b((qf + bias_v[d]) * SC2);
    }
  }

  float m_run = -1e30f, l_run = 0.f;
  f32x4 o_acc[4];
#pragma unroll
  for (int dt = 0; dt < 4; ++dt) o_acc[dt] = (f32x4){0.f, 0.f, 0.f, 0.f};

  int prbase = 112 - 16 * w;
  int lnq = lane >> 3, lnr = lane & 7;
  int r8 = w * 8 + lnq;
  int byt = (lnr * 16) ^ ((r8 & 7) << 4);
  int nbase = 896 - i0;

  auto stageK = [&](int t1) {
    int j = (t1 << 6) + r8;
    gload16((const char*)qkv + (size_t)(j * BB + b) * 3072 + 1024 + h * 128 + byt,
            lds_k + (t1 & 1) * 8192 + w * 1024);
  };
  auto stageVT = [&](int t1) {
    gload16((const char*)VTp + hoffB + (size_t)r8 * 2048 + (size_t)(t1 << 7) + byt,
            lds_vt + w * 1024);
  };
  auto stagePosSeg = [&](int gbase, int pseg) {
    gload16((const char*)posb + (size_t)(gbase + r8) * 1024 + h * 128 + byt,
            lds_pos + pseg * 8192 + w * 1024);
  };

  stagePosSeg(nbase, 0);
  stagePosSeg(nbase + 64, 1);
  stagePosSeg(nbase + 128, 2);
  stageK(0);
  WAIT_VM(0);

  for (int t = 0; t < 16; ++t) {
    int cur = t & 1;
    __builtin_amdgcn_s_barrier();
    stageVT(t);

    f32x4 acs[4];
    __builtin_amdgcn_s_setprio(1);
#pragma unroll
    for (int kt = 0; kt < 4; ++kt) {
      f32x4 z = (f32x4){0.f, 0.f, 0.f, 0.f};
      bf16x8 kb0 = *(const bf16x8*)(lds_k + cur * 8192 + swzp(kt * 16 + l15, l4 * 16));
      bf16x8 kb1 = *(const bf16x8*)(lds_k + cur * 8192 + swzp(kt * 16 + l15, 64 + l4 * 16));
      z = mfma16(kb0, qu_f[0], z);
      z = mfma16(kb1, qu_f[1], z);
      acs[kt] = z;
    }
    __builtin_amdgcn_s_setprio(0);
#pragma unroll
    for (int pt = 0; pt < 5; ++pt) {
      f32x4 z = (f32x4){0.f, 0.f, 0.f, 0.f};
      int pr = prbase + pt * 16 + l15;
      char* pbase = lds_pos + (((t + (pr >> 6)) & 3) * 8192);
      bf16x8 pb0 = *(const bf16x8*)(pbase + swzp(pr & 63, l4 * 16));
      bf16x8 pb1 = *(const bf16x8*)(pbase + swzp(pr & 63, 64 + l4 * 16));
      __builtin_amdgcn_s_setprio(1);
      z = mfma16(pb0, qv_f[0], z);
      z = mfma16(pb1, qv_f[1], z);
      __builtin_amdgcn_s_setprio(0);
      s16x4 ek;
#pragma unroll
      for (int r = 0; r < 4; ++r) ek[r] = f2bt(z[r]);
      *(s16x4*)(ewb + (l15 * 84 + pt * 16 + l4 * 4) * 2) = ek;
    }

    bool pf = (t + 1) < 16;
    if (pf) {
      stageK(t + 1);
      stagePosSeg(nbase + (t << 6) + 192, (t + 3) & 3);
    }

    WAIT_LGKM();

    float sv[4][4];
    float mt = -1e30f;
#pragma unroll
    for (int kt = 0; kt < 4; ++kt) {
#pragma unroll
      for (int r = 0; r < 4; ++r) {
        int n = 15 - l15 + kt * 16 + l4 * 4 + r;
        float ev = b2f(*(const short*)(ewb + (l15 * 84 + n) * 2));
        float sc = acs[kt][r] + ev;
        sv[kt][r] = sc;
        mt = fmaxf(mt, sc);
      }
    }
    if (!__all(mt <= m_run + 11.5415604f)) {
      float mr = fmaxf(mt, __shfl_xor(mt, 16));
      mr = fmaxf(mr, __shfl_xor(mr, 32));
      float mn = fmaxf(m_run, mr);
      float fac = exp2f(m_run - mn);
      m_run = mn;
      l_run *= fac;
      float fb[4];
#pragma unroll
      for (int r4 = 0; r4 < 4; ++r4) fb[r4] = __shfl(fac, (l4 << 2) + r4);
#pragma unroll
      for (int dt = 0; dt < 4; ++dt)
#pragma unroll
        for (int r4 = 0; r4 < 4; ++r4) o_acc[dt][r4] *= fb[r4];
    }
    float ls = 0.f;
#pragma unroll
    for (int kt = 0; kt < 4; ++kt) {
      s16x4 pk;
#pragma unroll
      for (int r = 0; r < 4; ++r) {
        float p = exp2f(sv[kt][r] - m_run);
        ls += p;
        pk[r] = f2bt(p);
      }
      *(s16x4*)(ewb + l15 * 128 + ((kt * 32 + l4 * 8) ^ ((l15 & 7) << 4))) = pk;
    }
    l_run += ls;

    if (pf) { WAIT_VM(2); } else { WAIT_VM(0); }
    WAIT_LGKM();
    __builtin_amdgcn_s_barrier();

    bf16x8 pa[2];
#pragma unroll
    for (int ks = 0; ks < 2; ++ks)
      pa[ks] = *(const bf16x8*)(ewb + swzp(l15, ks * 64 + l4 * 16));
    __builtin_amdgcn_s_setprio(1);
#pragma unroll
    for (int dt = 0; dt < 4; ++dt) {
      bf16x8 vb0 = *(const bf16x8*)(lds_vt + swzp(dt * 16 + l15, l4 * 16));
      bf16x8 vb1 = *(const bf16x8*)(lds_vt + swzp(dt * 16 + l15, 64 + l4 * 16));
      o_acc[dt] = mfma16(pa[0], vb0, o_acc[dt]);
      o_acc[dt] = mfma16(pa[1], vb1, o_acc[dt]);
    }
    __builtin_amdgcn_s_setprio(0);

    WAIT_VM(0);
  }

  float lt = l_run + __shfl_xor(l_run, 16);
  lt += __shfl_xor(lt, 32);
  float lb[4];
#pragma unroll
  for (int r4 = 0; r4 < 4; ++r4) lb[r4] = __shfl(lt, (l4 << 2) + r4);
#pragma unroll
  for (int dt = 0; dt < 4; ++dt) {
#pragma unroll
    for (int r4 = 0; r4 < 4; ++r4) {
      int i = i0 + w * 16 + l4 * 4 + r4;
      int d = dt * 16 + l15;
      float val = o_acc[dt][r4] / lb[r4];
      obuf[(size_t)(i * BB + b) * DM + h * 64 + d] = f2b(val);
    }
  }
}

// ---------------- GLU + depthwise conv (K=31) + fused LayerNorm + swish -> bf16 ----------------
__global__ __launch_bounds__(256) void glu_dwconv_kernel(const short* __restrict__ pw1,
                                                         const float* __restrict__ dww,
                                                         const float* __restrict__ dwb,
                                                         const float* __restrict__ cg,
                                                         const float* __restrict__ cb,
                                                         short* __restrict__ outbf) {
  __shared__ short glu[38 * 512];
  __shared__ float red[8][4][2];
  int tid = threadIdx.x;
  int b = blockIdx.x & 7;
  int s0 = (blockIdx.x >> 3) << 3;
  for (int idx = tid; idx < 38 * 64; idx += 256) {
    int r = idx >> 6, c8 = idx & 63;
    int s = s0 - 15 + r;
    bf16x8 res;
    if (s >= 0 && s < SQ) {
      const short* row = pw1 + (size_t)(s * BB + b) * 1024;
      bf16x8 a8 = *(const bf16x8*)(row + c8 * 8);
      bf16x8 g8 = *(const bf16x8*)(row + 512 + c8 * 8);
#pragma unroll
      for (int e = 0; e < 8; ++e) res[e] = f2b(b2f(a8[e]) * sigm(b2f(g8[e])));
    } else {
#pragma unroll
      for (int e = 0; e < 8; ++e) res[e] = 0;
    }
    *(bf16x8*)(glu + r * 512 + c8 * 8) = res;
  }
  __syncthreads();

  float a0[8], a1[8];
  {
    float wreg[31];
#pragma unroll
    for (int k = 0; k < 31; ++k) wreg[k] = dww[tid * 31 + k];
    float bb = dwb[tid];
    for (int ri = 0; ri < 8; ++ri) {
      float acc = bb;
#pragma unroll
      for (int k = 0; k < 31; ++k)
        acc += wreg[k] * b2f(glu[(ri + k) * 512 + tid]);
      a0[ri] = acc;
    }
  }
  {
    int d = tid + 256;
    float wreg[31];
#pragma unroll
    for (int k = 0; k < 31; ++k) wreg[k] = dww[d * 31 + k];
    float bb = dwb[d];
    for (int ri = 0; ri < 8; ++ri) {
      float acc = bb;
#pragma unroll
      for (int k = 0; k < 31; ++k)
        acc += wreg[k] * b2f(glu[(ri + k) * 512 + d]);
      a1[ri] = acc;
    }
  }

  int w = tid >> 6, lane = tid & 63;
#pragma unroll
  for (int ri = 0; ri < 8; ++ri) {
    float sp = a0[ri] + a1[ri];
    float qp = a0[ri] * a0[ri] + a1[ri] * a1[ri];
#pragma unroll
    for (int m = 1; m < 64; m <<= 1) { sp += __shfl_xor(sp, m); qp += __shfl_xor(qp, m); }
    if (lane == 0) { red[ri][w][0] = sp; red[ri][w][1] = qp; }
  }
  __syncthreads();
  float g0 = cg[tid], b0 = cb[tid], g1 = cg[tid + 256], b1 = cb[tid + 256];
#pragma unroll
  for (int ri = 0; ri < 8; ++ri) {
    float s = red[ri][0][0] + red[ri][1][0] + red[ri][2][0] + red[ri][3][0];
    float q = red[ri][0][1] + red[ri][1][1] + red[ri][2][1] + red[ri][3][1];
    float mean = s * (1.f / DM);
    float rstd = rsqrtf(q * (1.f / DM) - mean * mean + 1e-5f);
    float y0 = (a0[ri] - mean) * rstd * g0 + b0;
    float y1 = (a1[ri] - mean) * rstd * g1 + b1;
    y0 = y0 * sigm(y0);
    y1 = y1 * sigm(y1);
    size_t base = (size_t)((s0 + ri) * BB + b) * 512;
    outbf[base + tid] = f2b(y0);
    outbf[base + tid + 256] = f2b(y1);
  }
}

// ---------------- host ----------------
extern "C" void kernel_launch(void* const* d_in, const int* in_sizes, int n_in,
                              void* d_out, int out_size, void* d_ws, size_t ws_size,
                              hipStream_t stream) {
  const float* src    = (const float*)d_in[0];
  const float* pose   = (const float*)d_in[1];
  const float* ffm_w1 = (const float*)d_in[2];
  const float* ffm_b1 = (const float*)d_in[3];
  const float* ffm_w2 = (const float*)d_in[4];
  const float* ffm_b2 = (const float*)d_in[5];
  const float* in_w   = (const float*)d_in[6];
  const float* in_b   = (const float*)d_in[7];
  const float* out_w  = (const float*)d_in[8];
  const float* out_b  = (const float*)d_in[9];
  const float* pos_w  = (const float*)d_in[10];
  const float* bias_u = (const float*)d_in[11];
  const float* bias_v = (const float*)d_in[12];
  const float* pw1_w  = (const float*)d_in[13];
  const float* pw1_b  = (const float*)d_in[14];
  const float* dw_w   = (const float*)d_in[15];
  const float* dw_b   = (const float*)d_in[16];
  const float* cng    = (const float*)d_in[17];
  const float* cnb    = (const float*)d_in[18];
  const float* pw2_w  = (const float*)d_in[19];
  const float* pw2_b  = (const float*)d_in[20];
  const float* ff_w1  = (const float*)d_in[21];
  const float* ff_b1  = (const float*)d_in[22];
  const float* ff_w2  = (const float*)d_in[23];
  const float* ff_b2  = (const float*)d_in[24];
  const float* g_ffm  = (const float*)d_in[25];
  const float* b_ffm  = (const float*)d_in[26];
  const float* g_mha  = (const float*)d_in[27];
  const float* b_mha  = (const float*)d_in[28];
  const float* g_conv = (const float*)d_in[29];
  const float* b_conv = (const float*)d_in[30];
  const float* g_ff   = (const float*)d_in[31];
  const float* b_ff   = (const float*)d_in[32];
  const float* g_fin  = (const float*)d_in[33];
  const float* b_fin  = (const float*)d_in[34];

  char* ws = (char*)d_ws;
  size_t off = 0;
  auto alloc = [&](size_t bytes) -> void* {
    void* p = ws + off;
    off += (bytes + 255) & ~(size_t)255;
    return p;
  };
  short* wb_ffm1 = (short*)alloc((size_t)FF * DM * 2);
  short* wb_ffm2 = (short*)alloc((size_t)DM * FF * 2);
  short* wb_in   = (short*)alloc((size_t)3 * DM * DM * 2);
  short* wb_out  = (short*)alloc((size_t)DM * DM * 2);
  short* wb_pos  = (short*)alloc((size_t)DM * DM * 2);
  short* wb_pw1  = (short*)alloc((size_t)2 * DM * DM * 2);
  short* wb_pw2  = (short*)alloc((size_t)DM * DM * 2);
  short* wb_ff1  = (short*)alloc((size_t)FF * DM * 2);
  short* wb_ff2  = (short*)alloc((size_t)DM * FF * 2);
  short* pos_src = (short*)alloc((size_t)2048 * DM * 2);
  short* pos_bf  = (short*)alloc((size_t)2048 * DM * 2);
  short* lnb     = (short*)alloc((size_t)NROWS * DM * 2);
  short* hbig    = (short*)alloc((size_t)NROWS * FF * 2);
  short* qkvb    = (short*)alloc((size_t)NROWS * 3 * DM * 2);
  short* obuf    = (short*)alloc((size_t)NROWS * DM * 2);
  short* x1      = (short*)alloc((size_t)NROWS * DM * 2);
  short* x2      = (short*)alloc((size_t)NROWS * DM * 2);
  short* pw1raw  = hbig;
  short* convy   = obuf;
  short* x3 = x1;
  short* x4 = x2;
  short* VTp = hbig + (size_t)3 * 4194304;

  CvtArgs ca;
  const float* srcs[10] = {ffm_w1, ffm_w2, in_w, out_w, pos_w, pw1_w, pw2_w, ff_w1, ff_w2, pose};
  short* dsts[10] = {wb_ffm1, wb_ffm2, wb_in, wb_out, wb_pos, wb_pw1, wb_pw2, wb_ff1, wb_ff2, pos_src};
  size_t ns[10] = {(size_t)FF*DM, (size_t)DM*FF, (size_t)3*DM*DM, (size_t)DM*DM, (size_t)DM*DM,
                   (size_t)2*DM*DM, (size_t)DM*DM, (size_t)FF*DM, (size_t)DM*FF, (size_t)2047*DM};
  int cum = 0;
  for (int i = 0; i < 10; ++i) {
    ca.s[i] = srcs[i]; ca.d[i] = dsts[i];
    ca.n4[i] = (int)(ns[i] >> 2);
    ca.cum[i] = cum;
    cum += (ca.n4[i] + 255) / 256;
  }
  cvt_multi<<<dim3(cum), dim3(256), 0, stream>>>(ca);

  auto gemmR = [&](int RESF32, const short* A, const short* W, const float* bias,
                   const void* res, float alpha, short* out, int M, int N, int K) {
    dim3 g((M / 128) * (N / 128)), blk(256);
    if (RESF32) gemm128<2, 1><<<g, blk, 0, stream>>>(A, W, bias, res, alpha, out, M, N, K);
    else        gemm128<2, 0><<<g, blk, 0, stream>>>(A, W, bias, res, alpha, out, M, N, K);
  };
  auto gemm2 = [&](int EPI, const short* A, const short* W, const float* bias,
                   short* out, int M, int N, int K) {
    dim3 g((M / 256) * (N / 256)), blk(512);
    if (EPI == 0) gemm256<0><<<g, blk, 0, stream>>>(A, W, bias, out, M, N, K);
    else          gemm256<1><<<g, blk, 0, stream>>>(A, W, bias, out, M, N, K);
  };

  // positional projection (plain bf16 out)
  gemm128<3, 0><<<dim3(64), dim3(256), 0, stream>>>(pos_src, wb_pos, nullptr, nullptr, 0.f,
                                                    pos_bf, 2048, DM, DM);

  // macaron FFN: x1 = src + 0.5*ffn(ln(src))
  ln_kernel<0, 1><<<dim3(NROWS / 4), dim3(256), 0, stream>>>(src, g_ffm, b_ffm, lnb);
  gemm2(1, lnb, wb_ffm1, ffm_b1, hbig, NROWS, FF, DM);
  gemmR(1, hbig, wb_ffm2, ffm_b2, src, 0.5f, x1, NROWS, DM, FF);

  // MHA: x2 = x1 + out_proj(attn(ln(x1)))
  ln_kernel<0, 0><<<dim3(NROWS / 4), dim3(256), 0, stream>>>(x1, g_mha, b_mha, lnb);
  gemm2(0, lnb, wb_in, in_b, qkvb, NROWS, 3 * DM, DM);
  prep_kernel<<<dim3(1024), dim3(256), 0, stream>>>(qkvb, VTp);
  attn_kernel<<<dim3(512), dim3(512), 0, stream>>>(qkvb, VTp, pos_bf, bias_u, bias_v, obuf);
  gemmR(0, obuf, wb_out, out_b, x1, 1.f, x2, NROWS, DM, DM);

  // conv module: x3 = x2 + pw2(fused[swish(ln(dwconv(glu(pw1(ln(x2))))))])
  ln_kernel<0, 0><<<dim3(NROWS / 4), dim3(256), 0, stream>>>(x2, g_conv, b_conv, lnb);
  gemm2(0, lnb, wb_pw1, pw1_b, pw1raw, NROWS, 2 * DM, DM);
  glu_dwconv_kernel<<<dim3(1024), dim3(256), 0, stream>>>(pw1raw, dw_w, dw_b, cng, cnb, convy);
  gemmR(0, convy, wb_pw2, pw2_b, x2, 1.f, x3, NROWS, DM, DM);

  // final FFN: x4 = x3 + ffn(ln(x3))
  ln_kernel<0, 0><<<dim3(NROWS / 4), dim3(256), 0, stream>>>(x3, g_ff, b_ff, lnb);
  gemm2(1, lnb, wb_ff1, ff_b1, hbig, NROWS, FF, DM);
  gemmR(0, hbig, wb_ff2, ff_b2, x3, 1.f, x4, NROWS, DM, FF);

  // final LN -> f32 output
  ln_kernel<1, 0><<<dim3(NROWS / 4), dim3(256), 0, stream>>>(x4, g_fin, b_fin, d_out);

  (void)in_sizes; (void)n_in; (void)out_size; (void)ws_size;
}